// Round 20
// baseline (371.143 us; speedup 1.0000x reference)
//
#include <hip/hip_runtime.h>
#include <math.h>

#define B_  4
#define T_  2048
#define C_  1024
#define H_  16
#define HS_ 64
#define BT_ (B_*T_)
#define F_  (4*C_)
#define N3_ (3*C_)

typedef unsigned short ushort_t;
typedef __attribute__((ext_vector_type(4))) unsigned short us4;
typedef __attribute__((ext_vector_type(8))) unsigned short us8;
typedef __attribute__((ext_vector_type(4))) float f32x4;
typedef __attribute__((ext_vector_type(8))) __bf16 bf16x8;

template<bool V> struct bool_c { static constexpr bool value = V; };

__device__ __forceinline__ float bf2f(ushort_t u) {
    union { unsigned int i; float f; } c; c.i = ((unsigned int)u) << 16; return c.f;
}
// Native bf16 convert (RNE) — single v_cvt instruction on gfx950.
__device__ __forceinline__ ushort_t f2bf(float f) {
    union { __bf16 b; ushort_t u; } c; c.b = (__bf16)f; return c.u;
}

// global_load_lds: LDS dest = wave-uniform base + lane*16 (HW); global src per-lane.
#define GLB_(p) ((const __attribute__((address_space(1))) unsigned int*)(size_t)(p))
#define LDS_(p) ((__attribute__((address_space(3))) unsigned int*)(unsigned int)(size_t)(p))
__device__ __forceinline__ void gload16(const void* g, void* l) {
    __builtin_amdgcn_global_load_lds(GLB_(g), LDS_(l), 16, 0, 0);
}

template<int N> __device__ __forceinline__ void vm_wait() {
    if constexpr (N >= 8)      asm volatile("s_waitcnt vmcnt(8)" ::: "memory");
    else if constexpr (N == 6) asm volatile("s_waitcnt vmcnt(6)" ::: "memory");
    else if constexpr (N == 4) asm volatile("s_waitcnt vmcnt(4)" ::: "memory");
    else if constexpr (N == 3) asm volatile("s_waitcnt vmcnt(3)" ::: "memory");
    else if constexpr (N == 2) asm volatile("s_waitcnt vmcnt(2)" ::: "memory");
    else                       asm volatile("s_waitcnt vmcnt(0)" ::: "memory");
}

// ---------- prep: Wq/Wk/Wv [H][C][hs] f32 -> WtB [3C][C] bf16 (row n = p*C + h*64 + s) ----------
__global__ __launch_bounds__(256) void repack_qkv_k(
    const float* __restrict__ Wq, const float* __restrict__ Wk,
    const float* __restrict__ Wv, ushort_t* __restrict__ WtB)
{
    __shared__ float tile[64][65];
    int bid = blockIdx.x;
    int p  = bid >> 8;
    int h  = (bid >> 4) & 15;
    int c0 = (bid & 15) * 64;
    const float* W = (p == 0) ? Wq : ((p == 1) ? Wk : Wv);
    int t = threadIdx.x;
    int cl = t >> 2, seg = (t & 3) * 16;
    const float* src = W + ((size_t)h * C_ + c0 + cl) * HS_ + seg;
#pragma unroll
    for (int i = 0; i < 4; i++) {
        float4 v = *(const float4*)(src + i * 4);
        tile[cl][seg + i*4 + 0] = v.x; tile[cl][seg + i*4 + 1] = v.y;
        tile[cl][seg + i*4 + 2] = v.z; tile[cl][seg + i*4 + 3] = v.w;
    }
    __syncthreads();
    int sl = t >> 2;                 // s within head
    int n = p * C_ + h * HS_ + sl;   // output row
    ushort_t* dst = WtB + (size_t)n * C_ + c0 + seg;
    us8 o0, o1;
#pragma unroll
    for (int e = 0; e < 8; e++) { o0[e] = f2bf(tile[seg + e][sl]); o1[e] = f2bf(tile[seg + 8 + e][sl]); }
    *(us8*)dst = o0; *(us8*)(dst + 8) = o1;
}

// ---------- prep: generic transpose  in f32 [K][N] -> out bf16 [N][K] ----------
__global__ __launch_bounds__(256) void transpose_k(
    const float* __restrict__ in, ushort_t* __restrict__ out, int K, int N)
{
    __shared__ float tile[64][65];
    int n0 = blockIdx.x * 64, k0 = blockIdx.y * 64;
    int t = threadIdx.x;
    int kl = t >> 2, seg = (t & 3) * 16;
    const float* src = in + (size_t)(k0 + kl) * N + n0 + seg;
#pragma unroll
    for (int i = 0; i < 4; i++) {
        float4 v = *(const float4*)(src + i * 4);
        tile[kl][seg + i*4 + 0] = v.x; tile[kl][seg + i*4 + 1] = v.y;
        tile[kl][seg + i*4 + 2] = v.z; tile[kl][seg + i*4 + 3] = v.w;
    }
    __syncthreads();
    int nl = t >> 2;
    ushort_t* dst = out + (size_t)(n0 + nl) * K + k0 + seg;
    us8 o0, o1;
#pragma unroll
    for (int e = 0; e < 8; e++) { o0[e] = f2bf(tile[seg + e][nl]); o1[e] = f2bf(tile[seg + 8 + e][nl]); }
    *(us8*)dst = o0; *(us8*)(dst + 8) = o1;
}

// ---------- prep: V cols of qkv [B*T][3C] -> Vt [B][H][64][T] bf16 ----------
__global__ __launch_bounds__(256) void transv_k(
    const ushort_t* __restrict__ QKV, ushort_t* __restrict__ Vt)
{
    __shared__ ushort_t tl[64][72];
    int bid = blockIdx.x;
    int tt = bid & 31;           // T/64 tiles
    int bh = bid >> 5;
    int b  = bh >> 4;
    int h  = bh & 15;
    int t = threadIdx.x;
    int r = t >> 2, sg = (t & 3) * 16;
    const ushort_t* src = QKV + (size_t)(b * T_ + tt * 64 + r) * N3_ + 2 * C_ + h * HS_ + sg;
    us8 a0 = *(const us8*)src;
    us8 a1 = *(const us8*)(src + 8);
#pragma unroll
    for (int e = 0; e < 8; e++) { tl[r][sg + e] = a0[e]; tl[r][sg + 8 + e] = a1[e]; }
    __syncthreads();
    ushort_t* dst = Vt + ((size_t)(b * H_ + h) * HS_ + r) * T_ + tt * 64 + sg;
    us8 o0, o1;
#pragma unroll
    for (int e = 0; e < 8; e++) { o0[e] = tl[sg + e][r]; o1[e] = tl[sg + 8 + e][r]; }
    *(us8*)dst = o0; *(us8*)(dst + 8) = o1;
}

// ---------- layernorm -> bf16 out. IN_BF16: 0 = fp32 input, 1 = bf16 input ----------
template<int IN_BF16>
__global__ __launch_bounds__(256) void ln_k(
    const void* __restrict__ xv, const float* __restrict__ g,
    const float* __restrict__ b, ushort_t* __restrict__ out)
{
    int row = blockIdx.x;
    int t = threadIdx.x;
    float v[4];
    if (IN_BF16) {
        const ushort_t* xr = (const ushort_t*)xv + (size_t)row * C_;
        us4 u = *(const us4*)(xr + t * 4);
#pragma unroll
        for (int i = 0; i < 4; i++) v[i] = bf2f(u[i]);
    } else {
        const float* xr = (const float*)xv + (size_t)row * C_;
        float4 f = *(const float4*)(xr + t * 4);
        v[0] = f.x; v[1] = f.y; v[2] = f.z; v[3] = f.w;
    }
    float s  = v[0] + v[1] + v[2] + v[3];
    float ss = v[0]*v[0] + v[1]*v[1] + v[2]*v[2] + v[3]*v[3];
#pragma unroll
    for (int off = 32; off > 0; off >>= 1) {
        s  += __shfl_xor(s, off);
        ss += __shfl_xor(ss, off);
    }
    __shared__ float red[8];
    int wv = t >> 6;
    if ((t & 63) == 0) { red[wv*2] = s; red[wv*2+1] = ss; }
    __syncthreads();
    s  = red[0] + red[2] + red[4] + red[6];
    ss = red[1] + red[3] + red[5] + red[7];
    float mu  = s * (1.0f / C_);
    float var = ss * (1.0f / C_) - mu * mu;
    float rs  = rsqrtf(var + 1e-5f);
    float4 gv = *(const float4*)(g + t * 4);
    float4 bv = *(const float4*)(b + t * 4);
    us4 o;
    o[0] = f2bf((v[0] - mu) * rs * gv.x + bv.x);
    o[1] = f2bf((v[1] - mu) * rs * gv.y + bv.y);
    o[2] = f2bf((v[2] - mu) * rs * gv.z + bv.z);
    o[3] = f2bf((v[3] - mu) * rs * gv.w + bv.w);
    *(us4*)(out + (size_t)row * C_ + t * 4) = o;
}

// ---------- 8-phase MFMA bf16 GEMM (T1 swizzle; generic UNIT-derived vmcnt) ----------
// (validated structure: BK=64 two k-half phases, 3-ahead staging, steady
// vmcnt(2*UNIT) with UNIT = A_INSTS + B_INSTS derived, raw s_barrier,
// (row>>1)&3 seg-XOR swizzle for 64B rows, bijective XCD block remap)
template<int BM, int BN, int WM, int WN, int RELU, int BIAS, int RES_MODE, int OUT_BF16>
__global__ __launch_bounds__(WM * WN * 64) void mgemm8_k(
    const ushort_t* __restrict__ A, const ushort_t* __restrict__ Bw,
    const float* __restrict__ bias, const void* __restrict__ res,
    void* __restrict__ out, int M, int N, int K, int lda, int gx)
{
    constexpr int THREADS = WM * WN * 64;
    constexpr int MIa = BM / WM / 16;
    constexpr int MIb = BN / WN / 16;
    constexpr int A_INSTS = (BM * 64) / (16 * THREADS);   // gload insts per thread per A k-half
    constexpr int B_INSTS = (BN * 64) / (16 * THREADS);
    constexpr int UNIT = A_INSTS + B_INSTS;               // VMEM insts per staging unit
    __shared__ ushort_t As[4 * BM * 32];                  // 2buf x 2kh
    __shared__ ushort_t Bs[4 * BN * 32];

    int tid = threadIdx.x;
    int l = tid & 63, w = tid >> 6;
    int wm = w / WN, wn = w % WN;
    int lin = blockIdx.x;
    int nwg = gridDim.x;
    int swz = (lin & 7) * (nwg >> 3) + (lin >> 3);
    int bx = swz % gx, by = swz / gx;
    int m0 = by * BM, n0 = bx * BN;
    const int nt = K >> 6;

    auto stageA = [&](int tile, int kh) {
        ushort_t* dst = As + ((tile & 1) * 2 + kh) * (BM * 32);
#pragma unroll
        for (int inst = 0; inst < A_INSTS; ++inst) {
            int slot = inst * THREADS + tid;
            int row = slot >> 2, q = slot & 3;
            const ushort_t* src = A + (size_t)(m0 + row) * lda + tile * 64 + kh * 32
                                  + ((q ^ ((row >> 1) & 3)) * 8);
            gload16(src, dst + (inst * THREADS + w * 64) * 8);
        }
    };
    auto stageB = [&](int tile, int kh) {
        ushort_t* dst = Bs + ((tile & 1) * 2 + kh) * (BN * 32);
#pragma unroll
        for (int inst = 0; inst < B_INSTS; ++inst) {
            int slot = inst * THREADS + tid;
            int row = slot >> 2, q = slot & 3;
            const ushort_t* src = Bw + (size_t)(n0 + row) * K + tile * 64 + kh * 32
                                  + ((q ^ ((row >> 1) & 3)) * 8);
            gload16(src, dst + (inst * THREADS + w * 64) * 8);
        }
    };

    f32x4 acc[MIa][MIb];
#pragma unroll
    for (int i = 0; i < MIa; i++)
#pragma unroll
        for (int j = 0; j < MIb; j++) acc[i][j] = (f32x4){0.f, 0.f, 0.f, 0.f};

    // prologue: 3 units ahead (t0kh0, t0kh1, t1kh0)
    stageA(0, 0); stageB(0, 0);
    stageA(0, 1); stageB(0, 1);
    stageA(1, 0); stageB(1, 0);

    for (int t = 0; t < nt; ++t) {
        int buf = t & 1;
#pragma unroll
        for (int kh = 0; kh < 2; ++kh) {
            // unit for this phase was issued 3 phases ago; 2 units behind it
            if (t == nt - 1) { if (kh == 0) vm_wait<UNIT>(); else vm_wait<0>(); }
            else vm_wait<2 * UNIT>();
            __builtin_amdgcn_s_barrier();
            __builtin_amdgcn_sched_barrier(0);

            const ushort_t* Ab = As + (buf * 2 + kh) * (BM * 32);
            const ushort_t* Bb = Bs + (buf * 2 + kh) * (BN * 32);
            bf16x8 af[MIa], bf[MIb];
#pragma unroll
            for (int i = 0; i < MIa; ++i) {
                int row = wm * (BM / WM) + i * 16 + (l & 15);
                af[i] = *(const bf16x8*)(Ab + row * 32 + (((l >> 4) ^ ((row >> 1) & 3)) * 8));
            }
#pragma unroll
            for (int j = 0; j < MIb; ++j) {
                int row = wn * (BN / WN) + j * 16 + (l & 15);
                bf[j] = *(const bf16x8*)(Bb + row * 32 + (((l >> 4) ^ ((row >> 1) & 3)) * 8));
            }
            // stage schedule: ph0 -> (t+1) kh1 ; ph1 -> (t+2) kh0
            if (kh == 0) { if (t + 1 < nt) { stageA(t + 1, 1); stageB(t + 1, 1); } }
            else         { if (t + 2 < nt) { stageA(t + 2, 0); stageB(t + 2, 0); } }

            __builtin_amdgcn_s_setprio(1);
#pragma unroll
            for (int i = 0; i < MIa; ++i)
#pragma unroll
                for (int j = 0; j < MIb; ++j)
                    acc[i][j] = __builtin_amdgcn_mfma_f32_16x16x32_bf16(af[i], bf[j], acc[i][j], 0, 0, 0);
            __builtin_amdgcn_s_setprio(0);
            __builtin_amdgcn_sched_barrier(0);
            __builtin_amdgcn_s_barrier();
        }
    }

    int colb = n0 + wn * (BN / WN) + (l & 15);
    int rowb = m0 + wm * (BM / WM) + ((l >> 4) << 2);
#pragma unroll
    for (int j = 0; j < MIb; j++) {
        int col = colb + j * 16;
        float bval = BIAS ? bias[col] : 0.f;
#pragma unroll
        for (int i = 0; i < MIa; i++) {
#pragma unroll
            for (int r = 0; r < 4; r++) {
                int row = rowb + i * 16 + r;
                float v = acc[i][j][r] + bval;
                if (RELU) v = fmaxf(v, 0.f);
                size_t idx = (size_t)row * N + col;
                if (RES_MODE == 1) v += ((const float*)res)[idx];
                else if (RES_MODE == 2) v += bf2f(((const ushort_t*)res)[idx]);
                if (OUT_BF16) ((ushort_t*)out)[idx] = f2bf(v);
                else          ((float*)out)[idx]    = v;
            }
        }
    }
}

// ---------- MFMA flash attention, v10 = v8 (best measured) + exp2 fold ----------
// v8: QK-early pipeline (S(kt+1) MFMA overlaps softmax(kt) VALU), 3-buf K staged
// 2 ahead, 2-buf V, QPs union, per-iter __syncthreads (R19's counted-vmcnt variant
// measured WORSE: L2-resident K/V has little drain-stall left; extra barrier cost).
// exp2 fold: exp(s*0.125) -> exp2(s*(0.125*log2e)) removes one v_mul per element
// (16 VALU ops/thread/iter) from the softmax chain; identical math.
__global__ __launch_bounds__(256) void fattn_k(
    ushort_t* __restrict__ QKV, const ushort_t* __restrict__ Vt)
{
    __shared__ ushort_t QPs[64 * 64];     // Q staging (prologue) / P tile (loop)
    __shared__ ushort_t Ks[3][64 * 64];
    __shared__ ushort_t Vs[2][64 * 64];
    int lin = blockIdx.x;
    int nwg = gridDim.x;                       // 1024, %8 == 0
    int bid = (lin & 7) * (nwg >> 3) + (lin >> 3);   // bijective XCD remap
    int pr = bid & 15;
    int bh = bid >> 4;
    int b  = bh >> 4;
    int h  = bh & 15;
    int tid = threadIdx.x;
    int lid = tid & 63, w = tid >> 6;

    int srow = w * 16 + (lid >> 3);
    int sseg0 = (lid & 7) ^ (srow & 7);
    int sseg1 = (lid & 7) ^ ((srow + 8) & 7);
    const ushort_t* Kg = QKV + (size_t)(b * T_) * N3_ + C_ + h * HS_;
    const ushort_t* Vg = Vt + (size_t)(b * H_ + h) * HS_ * T_;

    int mrow = w * 16 + (lid & 15);
    int fseg = lid >> 4;
    int qlocb = w * 16 + ((lid >> 4) << 2);

    const __bf16 oneb = (__bf16)1.0f;
    bf16x8 ones = {oneb, oneb, oneb, oneb, oneb, oneb, oneb, oneb};
    const float SCL = 0.18033688011112042f;   // 0.125 * log2(e)

    auto stageK = [&](int kt) {
        ushort_t* d = Ks[kt % 3];
        gload16(Kg + (size_t)(kt * 64 + srow) * N3_ + sseg0 * 8,     d + w * 1024);
        gload16(Kg + (size_t)(kt * 64 + srow + 8) * N3_ + sseg1 * 8, d + w * 1024 + 512);
    };
    auto stageV = [&](int kt) {
        ushort_t* d = Vs[kt & 1];
        gload16(Vg + (size_t)srow * T_ + kt * 64 + sseg0 * 8,       d + w * 1024);
        gload16(Vg + (size_t)(srow + 8) * T_ + kt * 64 + sseg1 * 8, d + w * 1024 + 512);
    };

    for (int half = 0; half < 2; ++half) {
        int qt = half ? (31 - pr) : pr;
        const ushort_t* Qg = QKV + (size_t)(b * T_ + qt * 64) * N3_ + h * HS_;

        // prologue: stage Q, K0, V0, K1 (all dests wave-private rows)
        gload16(Qg + (size_t)srow * N3_ + sseg0 * 8,       QPs + w * 1024);
        gload16(Qg + (size_t)(srow + 8) * N3_ + sseg1 * 8, QPs + w * 1024 + 512);
        stageK(0);
        stageV(0);
        if (qt >= 1) stageK(1);
        __syncthreads();   // drains all staging + syncs waves

        // Q fragments loop-invariant -> registers; QPs becomes the P tile.
        bf16x8 aqr[2];
        aqr[0] = *(const bf16x8*)(QPs + mrow * 64 + (((0 + fseg) ^ (mrow & 7)) * 8));
        aqr[1] = *(const bf16x8*)(QPs + mrow * 64 + (((4 + fseg) ^ (mrow & 7)) * 8));

        f32x4 accO[4];
#pragma unroll
        for (int j = 0; j < 4; j++) accO[j] = (f32x4){0.f, 0.f, 0.f, 0.f};
        f32x4 accL = (f32x4){0.f, 0.f, 0.f, 0.f};

        auto qk_into = [&](const ushort_t* Kc, f32x4* s) {
#pragma unroll
            for (int j = 0; j < 4; j++) s[j] = (f32x4){0.f, 0.f, 0.f, 0.f};
            __builtin_amdgcn_s_setprio(1);
#pragma unroll
            for (int ks = 0; ks < 2; ks++) {
#pragma unroll
                for (int j = 0; j < 4; j++) {
                    int krow = j * 16 + (lid & 15);
                    bf16x8 bk = *(const bf16x8*)(Kc + krow * 64 + (((ks * 4 + fseg) ^ (krow & 7)) * 8));
                    s[j] = __builtin_amdgcn_mfma_f32_16x16x32_bf16(aqr[ks], bk, s[j], 0, 0, 0);
                }
            }
            __builtin_amdgcn_s_setprio(0);
        };
        auto smax_pv = [&](auto diag_c, f32x4* s, const ushort_t* Vc) {
            constexpr bool DIAG = decltype(diag_c)::value;
#pragma unroll
            for (int r = 0; r < 4; r++) {
                int qloc = qlocb + r;
#pragma unroll
                for (int j = 0; j < 4; j++) {
                    int col = j * 16 + (lid & 15);
                    float p = exp2f(s[j][r] * SCL);
                    if (DIAG) { if (col > qloc) p = 0.f; }
                    QPs[qloc * 64 + (((col >> 3) ^ (qloc & 7)) * 8) + (col & 7)] = f2bf(p);
                }
            }
            __builtin_amdgcn_s_setprio(1);
#pragma unroll
            for (int ks = 0; ks < 2; ks++) {
                bf16x8 ap = *(const bf16x8*)(QPs + mrow * 64 + (((ks * 4 + fseg) ^ (mrow & 7)) * 8));
                accL = __builtin_amdgcn_mfma_f32_16x16x32_bf16(ap, ones, accL, 0, 0, 0);
#pragma unroll
                for (int j = 0; j < 4; j++) {
                    int drow = j * 16 + (lid & 15);
                    bf16x8 bv = *(const bf16x8*)(Vc + drow * 64 + (((ks * 4 + fseg) ^ (drow & 7)) * 8));
                    accO[j] = __builtin_amdgcn_mfma_f32_16x16x32_bf16(ap, bv, accO[j], 0, 0, 0);
                }
            }
            __builtin_amdgcn_s_setprio(0);
        };

        // sP = S(0)
        f32x4 sP[4], sN[4];
        qk_into(Ks[0], sP);

        for (int kt = 0; kt < qt; ++kt) {
            // early-issue staging: K two ahead, V one ahead
            if (kt + 2 <= qt) stageK(kt + 2);
            stageV(kt + 1);
            // QK(kt+1) — independent of softmax(kt); overlaps its VALU work
            qk_into(Ks[(kt + 1) % 3], sN);
            // softmax(kt) (never diag in-loop) + PV(kt)
            smax_pv(bool_c<false>{}, sP, Vs[kt & 1]);
            __syncthreads();   // staged loads drained; all waves done with K/V[cur]
#pragma unroll
            for (int j = 0; j < 4; j++) sP[j] = sN[j];
        }
        // final tile kt = qt: diag mask
        smax_pv(bool_c<true>{}, sP, Vs[qt & 1]);
        __syncthreads();   // all reads done before next half restages

#pragma unroll
        for (int r = 0; r < 4; r++) {
            float inv = 1.0f / accL[r];
            int qabs = qt * 64 + qlocb + r;
            ushort_t* orow = QKV + (size_t)(b * T_ + qabs) * N3_ + h * HS_;
#pragma unroll
            for (int j = 0; j < 4; j++)
                orow[j * 16 + (lid & 15)] = f2bf(accO[j][r] * inv);
        }
    }
}

extern "C" void kernel_launch(void* const* d_in, const int* in_sizes, int n_in,
                              void* d_out, int out_size, void* d_ws, size_t ws_size,
                              hipStream_t stream)
{
    const float* x   = (const float*)d_in[0];
    const float* g1  = (const float*)d_in[1];
    const float* be1 = (const float*)d_in[2];
    const float* Wq  = (const float*)d_in[3];
    const float* Wk  = (const float*)d_in[4];
    const float* Wv  = (const float*)d_in[5];
    const float* Wo  = (const float*)d_in[6];
    const float* bo  = (const float*)d_in[7];
    const float* g2  = (const float*)d_in[8];
    const float* be2 = (const float*)d_in[9];
    const float* W1  = (const float*)d_in[10];
    const float* b1  = (const float*)d_in[11];
    const float* W2  = (const float*)d_in[12];
    const float* b2  = (const float*)d_in[13];

    // ws (bytes): hB/Vt 16M | big (qkv 48M / ff1 64M, time-disjoint) 64M | WtB 6M |
    // WoB 2M | W1B 8M | W2B 8M = 104 MiB. x2 lives as fp32 in d_out.
    const size_t UB2 = (size_t)BT_ * C_ * 2;
    const size_t WT_B = (size_t)N3_ * C_ * 2;
    const size_t WO_B = (size_t)C_ * C_ * 2;
    const size_t W1_B = (size_t)C_ * F_ * 2;
    const size_t REQ = 5 * UB2 + WT_B + WO_B + 2 * W1_B;
    if (ws_size < REQ) {
        hipMemsetAsync(d_out, 0, (size_t)out_size * 4, stream);
        return;
    }
    char* wsb = (char*)d_ws;
    ushort_t* hB   = (ushort_t*)(wsb);                 // LN out; Vt during attn; h2 after
    ushort_t* qkvB = (ushort_t*)(wsb + UB2);           // big region
    ushort_t* ff1B = qkvB;
    ushort_t* WtB  = (ushort_t*)(wsb + 5 * UB2);
    ushort_t* WoB  = (ushort_t*)(wsb + 5 * UB2 + WT_B);
    ushort_t* W1B  = (ushort_t*)(wsb + 5 * UB2 + WT_B + WO_B);
    ushort_t* W2B  = (ushort_t*)(wsb + 5 * UB2 + WT_B + WO_B + W1_B);
    float* x2F = (float*)d_out;

    // weight prep
    repack_qkv_k<<<3 * 16 * 16, 256, 0, stream>>>(Wq, Wk, Wv, WtB);
    transpose_k<<<dim3(C_ / 64, C_ / 64), 256, 0, stream>>>(Wo, WoB, C_, C_);
    transpose_k<<<dim3(F_ / 64, C_ / 64), 256, 0, stream>>>(W1, W1B, C_, F_);
    transpose_k<<<dim3(C_ / 64, F_ / 64), 256, 0, stream>>>(W2, W2B, F_, C_);

    // h = LN1(x)
    ln_k<0><<<BT_, 256, 0, stream>>>(x, g1, be1, hB);
    // qkv = h @ Wt^T    [8192 x 3072], 128x256 tiles -> grid 768
    mgemm8_k<128,256,2,4,0,0,0,1><<<(N3_ / 256) * (BT_ / 128), 512, 0, stream>>>(
        hB, WtB, nullptr, nullptr, qkvB, BT_, N3_, C_, C_, N3_ / 256);
    // Vt = transpose(V cols) into hB (LN1 output dead)
    transv_k<<<B_ * H_ * (T_ / 64), 256, 0, stream>>>(qkvB, hB);
    // attention (paired q-tiles, XCD-swizzled; O -> Q slots of qkv)
    fattn_k<<<B_ * H_ * 16, 256, 0, stream>>>(qkvB, hB);
    // x2 = x + O @ Wo + bo -> fp32 in d_out   [8192 x 1024], 128x256, grid 256
    mgemm8_k<128,256,2,4,0,1,1,0><<<(C_ / 256) * (BT_ / 128), 512, 0, stream>>>(
        qkvB, WoB, bo, x, x2F, BT_, C_, C_, N3_, C_ / 256);
    // h2 = LN2(x2)
    ln_k<0><<<BT_, 256, 0, stream>>>(x2F, g2, be2, hB);
    // ff1 = relu(h2 @ W1 + b1)   [8192 x 4096], 256x256 tiles, grid 512
    mgemm8_k<256,256,2,4,1,1,0,1><<<(F_ / 256) * (BT_ / 256), 512, 0, stream>>>(
        hB, W1B, b1, nullptr, ff1B, BT_, F_, C_, C_, F_ / 256);
    // out = x2 + ff1 @ W2 + b2   [8192 x 1024], 128x256, grid 256
    mgemm8_k<128,256,2,4,0,1,1,0><<<(C_ / 256) * (BT_ / 128), 512, 0, stream>>>(
        ff1B, W2B, b2, x2F, (float*)d_out, BT_, C_, F_, F_, C_ / 256);
}

// Round 21
// 361.242 us; speedup vs baseline: 1.0274x; 1.0274x over previous
//
#include <hip/hip_runtime.h>
#include <math.h>

#define B_  4
#define T_  2048
#define C_  1024
#define H_  16
#define HS_ 64
#define BT_ (B_*T_)
#define F_  (4*C_)
#define N3_ (3*C_)

typedef unsigned short ushort_t;
typedef __attribute__((ext_vector_type(4))) unsigned short us4;
typedef __attribute__((ext_vector_type(8))) unsigned short us8;
typedef __attribute__((ext_vector_type(4))) float f32x4;
typedef __attribute__((ext_vector_type(8))) __bf16 bf16x8;

template<bool V> struct bool_c { static constexpr bool value = V; };

__device__ __forceinline__ float bf2f(ushort_t u) {
    union { unsigned int i; float f; } c; c.i = ((unsigned int)u) << 16; return c.f;
}
// Native bf16 convert (RNE) — single v_cvt instruction on gfx950.
__device__ __forceinline__ ushort_t f2bf(float f) {
    union { __bf16 b; ushort_t u; } c; c.b = (__bf16)f; return c.u;
}

// global_load_lds: LDS dest = wave-uniform base + lane*16 (HW); global src per-lane.
#define GLB_(p) ((const __attribute__((address_space(1))) unsigned int*)(size_t)(p))
#define LDS_(p) ((__attribute__((address_space(3))) unsigned int*)(unsigned int)(size_t)(p))
__device__ __forceinline__ void gload16(const void* g, void* l) {
    __builtin_amdgcn_global_load_lds(GLB_(g), LDS_(l), 16, 0, 0);
}

template<int N> __device__ __forceinline__ void vm_wait() {
    if constexpr (N >= 8)      asm volatile("s_waitcnt vmcnt(8)" ::: "memory");
    else if constexpr (N == 6) asm volatile("s_waitcnt vmcnt(6)" ::: "memory");
    else if constexpr (N == 4) asm volatile("s_waitcnt vmcnt(4)" ::: "memory");
    else if constexpr (N == 3) asm volatile("s_waitcnt vmcnt(3)" ::: "memory");
    else if constexpr (N == 2) asm volatile("s_waitcnt vmcnt(2)" ::: "memory");
    else                       asm volatile("s_waitcnt vmcnt(0)" ::: "memory");
}

// ---------- prep: Wq/Wk/Wv [H][C][hs] f32 -> WtB [3C][C] bf16 (row n = p*C + h*64 + s) ----------
__global__ __launch_bounds__(256) void repack_qkv_k(
    const float* __restrict__ Wq, const float* __restrict__ Wk,
    const float* __restrict__ Wv, ushort_t* __restrict__ WtB)
{
    __shared__ float tile[64][65];
    int bid = blockIdx.x;
    int p  = bid >> 8;
    int h  = (bid >> 4) & 15;
    int c0 = (bid & 15) * 64;
    const float* W = (p == 0) ? Wq : ((p == 1) ? Wk : Wv);
    int t = threadIdx.x;
    int cl = t >> 2, seg = (t & 3) * 16;
    const float* src = W + ((size_t)h * C_ + c0 + cl) * HS_ + seg;
#pragma unroll
    for (int i = 0; i < 4; i++) {
        float4 v = *(const float4*)(src + i * 4);
        tile[cl][seg + i*4 + 0] = v.x; tile[cl][seg + i*4 + 1] = v.y;
        tile[cl][seg + i*4 + 2] = v.z; tile[cl][seg + i*4 + 3] = v.w;
    }
    __syncthreads();
    int sl = t >> 2;                 // s within head
    int n = p * C_ + h * HS_ + sl;   // output row
    ushort_t* dst = WtB + (size_t)n * C_ + c0 + seg;
    us8 o0, o1;
#pragma unroll
    for (int e = 0; e < 8; e++) { o0[e] = f2bf(tile[seg + e][sl]); o1[e] = f2bf(tile[seg + 8 + e][sl]); }
    *(us8*)dst = o0; *(us8*)(dst + 8) = o1;
}

// ---------- prep: generic transpose  in f32 [K][N] -> out bf16 [N][K] ----------
__global__ __launch_bounds__(256) void transpose_k(
    const float* __restrict__ in, ushort_t* __restrict__ out, int K, int N)
{
    __shared__ float tile[64][65];
    int n0 = blockIdx.x * 64, k0 = blockIdx.y * 64;
    int t = threadIdx.x;
    int kl = t >> 2, seg = (t & 3) * 16;
    const float* src = in + (size_t)(k0 + kl) * N + n0 + seg;
#pragma unroll
    for (int i = 0; i < 4; i++) {
        float4 v = *(const float4*)(src + i * 4);
        tile[kl][seg + i*4 + 0] = v.x; tile[kl][seg + i*4 + 1] = v.y;
        tile[kl][seg + i*4 + 2] = v.z; tile[kl][seg + i*4 + 3] = v.w;
    }
    __syncthreads();
    int nl = t >> 2;
    ushort_t* dst = out + (size_t)(n0 + nl) * K + k0 + seg;
    us8 o0, o1;
#pragma unroll
    for (int e = 0; e < 8; e++) { o0[e] = f2bf(tile[seg + e][nl]); o1[e] = f2bf(tile[seg + 8 + e][nl]); }
    *(us8*)dst = o0; *(us8*)(dst + 8) = o1;
}

// ---------- prep: V cols of qkv [B*T][3C] -> Vt [B][H][64][T] bf16 ----------
__global__ __launch_bounds__(256) void transv_k(
    const ushort_t* __restrict__ QKV, ushort_t* __restrict__ Vt)
{
    __shared__ ushort_t tl[64][72];
    int bid = blockIdx.x;
    int tt = bid & 31;           // T/64 tiles
    int bh = bid >> 5;
    int b  = bh >> 4;
    int h  = bh & 15;
    int t = threadIdx.x;
    int r = t >> 2, sg = (t & 3) * 16;
    const ushort_t* src = QKV + (size_t)(b * T_ + tt * 64 + r) * N3_ + 2 * C_ + h * HS_ + sg;
    us8 a0 = *(const us8*)src;
    us8 a1 = *(const us8*)(src + 8);
#pragma unroll
    for (int e = 0; e < 8; e++) { tl[r][sg + e] = a0[e]; tl[r][sg + 8 + e] = a1[e]; }
    __syncthreads();
    ushort_t* dst = Vt + ((size_t)(b * H_ + h) * HS_ + r) * T_ + tt * 64 + sg;
    us8 o0, o1;
#pragma unroll
    for (int e = 0; e < 8; e++) { o0[e] = tl[sg + e][r]; o1[e] = tl[sg + 8 + e][r]; }
    *(us8*)dst = o0; *(us8*)(dst + 8) = o1;
}

// ---------- layernorm -> bf16 out. IN_BF16: 0 = fp32 input, 1 = bf16 input ----------
template<int IN_BF16>
__global__ __launch_bounds__(256) void ln_k(
    const void* __restrict__ xv, const float* __restrict__ g,
    const float* __restrict__ b, ushort_t* __restrict__ out)
{
    int row = blockIdx.x;
    int t = threadIdx.x;
    float v[4];
    if (IN_BF16) {
        const ushort_t* xr = (const ushort_t*)xv + (size_t)row * C_;
        us4 u = *(const us4*)(xr + t * 4);
#pragma unroll
        for (int i = 0; i < 4; i++) v[i] = bf2f(u[i]);
    } else {
        const float* xr = (const float*)xv + (size_t)row * C_;
        float4 f = *(const float4*)(xr + t * 4);
        v[0] = f.x; v[1] = f.y; v[2] = f.z; v[3] = f.w;
    }
    float s  = v[0] + v[1] + v[2] + v[3];
    float ss = v[0]*v[0] + v[1]*v[1] + v[2]*v[2] + v[3]*v[3];
#pragma unroll
    for (int off = 32; off > 0; off >>= 1) {
        s  += __shfl_xor(s, off);
        ss += __shfl_xor(ss, off);
    }
    __shared__ float red[8];
    int wv = t >> 6;
    if ((t & 63) == 0) { red[wv*2] = s; red[wv*2+1] = ss; }
    __syncthreads();
    s  = red[0] + red[2] + red[4] + red[6];
    ss = red[1] + red[3] + red[5] + red[7];
    float mu  = s * (1.0f / C_);
    float var = ss * (1.0f / C_) - mu * mu;
    float rs  = rsqrtf(var + 1e-5f);
    float4 gv = *(const float4*)(g + t * 4);
    float4 bv = *(const float4*)(b + t * 4);
    us4 o;
    o[0] = f2bf((v[0] - mu) * rs * gv.x + bv.x);
    o[1] = f2bf((v[1] - mu) * rs * gv.y + bv.y);
    o[2] = f2bf((v[2] - mu) * rs * gv.z + bv.z);
    o[3] = f2bf((v[3] - mu) * rs * gv.w + bv.w);
    *(us4*)(out + (size_t)row * C_ + t * 4) = o;
}

// ---------- 8-phase MFMA bf16 GEMM (T1 swizzle; generic UNIT-derived vmcnt) ----------
// (validated structure: BK=64 two k-half phases, 3-ahead staging, steady
// vmcnt(2*UNIT) with UNIT = A_INSTS + B_INSTS derived, raw s_barrier,
// (row>>1)&3 seg-XOR swizzle for 64B rows, bijective XCD block remap)
template<int BM, int BN, int WM, int WN, int RELU, int BIAS, int RES_MODE, int OUT_BF16>
__global__ __launch_bounds__(WM * WN * 64) void mgemm8_k(
    const ushort_t* __restrict__ A, const ushort_t* __restrict__ Bw,
    const float* __restrict__ bias, const void* __restrict__ res,
    void* __restrict__ out, int M, int N, int K, int lda, int gx)
{
    constexpr int THREADS = WM * WN * 64;
    constexpr int MIa = BM / WM / 16;
    constexpr int MIb = BN / WN / 16;
    constexpr int A_INSTS = (BM * 64) / (16 * THREADS);   // gload insts per thread per A k-half
    constexpr int B_INSTS = (BN * 64) / (16 * THREADS);
    constexpr int UNIT = A_INSTS + B_INSTS;               // VMEM insts per staging unit
    __shared__ ushort_t As[4 * BM * 32];                  // 2buf x 2kh
    __shared__ ushort_t Bs[4 * BN * 32];

    int tid = threadIdx.x;
    int l = tid & 63, w = tid >> 6;
    int wm = w / WN, wn = w % WN;
    int lin = blockIdx.x;
    int nwg = gridDim.x;
    int swz = (lin & 7) * (nwg >> 3) + (lin >> 3);
    int bx = swz % gx, by = swz / gx;
    int m0 = by * BM, n0 = bx * BN;
    const int nt = K >> 6;

    auto stageA = [&](int tile, int kh) {
        ushort_t* dst = As + ((tile & 1) * 2 + kh) * (BM * 32);
#pragma unroll
        for (int inst = 0; inst < A_INSTS; ++inst) {
            int slot = inst * THREADS + tid;
            int row = slot >> 2, q = slot & 3;
            const ushort_t* src = A + (size_t)(m0 + row) * lda + tile * 64 + kh * 32
                                  + ((q ^ ((row >> 1) & 3)) * 8);
            gload16(src, dst + (inst * THREADS + w * 64) * 8);
        }
    };
    auto stageB = [&](int tile, int kh) {
        ushort_t* dst = Bs + ((tile & 1) * 2 + kh) * (BN * 32);
#pragma unroll
        for (int inst = 0; inst < B_INSTS; ++inst) {
            int slot = inst * THREADS + tid;
            int row = slot >> 2, q = slot & 3;
            const ushort_t* src = Bw + (size_t)(n0 + row) * K + tile * 64 + kh * 32
                                  + ((q ^ ((row >> 1) & 3)) * 8);
            gload16(src, dst + (inst * THREADS + w * 64) * 8);
        }
    };

    f32x4 acc[MIa][MIb];
#pragma unroll
    for (int i = 0; i < MIa; i++)
#pragma unroll
        for (int j = 0; j < MIb; j++) acc[i][j] = (f32x4){0.f, 0.f, 0.f, 0.f};

    // prologue: 3 units ahead (t0kh0, t0kh1, t1kh0)
    stageA(0, 0); stageB(0, 0);
    stageA(0, 1); stageB(0, 1);
    stageA(1, 0); stageB(1, 0);

    for (int t = 0; t < nt; ++t) {
        int buf = t & 1;
#pragma unroll
        for (int kh = 0; kh < 2; ++kh) {
            // unit for this phase was issued 3 phases ago; 2 units behind it
            if (t == nt - 1) { if (kh == 0) vm_wait<UNIT>(); else vm_wait<0>(); }
            else vm_wait<2 * UNIT>();
            __builtin_amdgcn_s_barrier();
            __builtin_amdgcn_sched_barrier(0);

            const ushort_t* Ab = As + (buf * 2 + kh) * (BM * 32);
            const ushort_t* Bb = Bs + (buf * 2 + kh) * (BN * 32);
            bf16x8 af[MIa], bf[MIb];
#pragma unroll
            for (int i = 0; i < MIa; ++i) {
                int row = wm * (BM / WM) + i * 16 + (l & 15);
                af[i] = *(const bf16x8*)(Ab + row * 32 + (((l >> 4) ^ ((row >> 1) & 3)) * 8));
            }
#pragma unroll
            for (int j = 0; j < MIb; ++j) {
                int row = wn * (BN / WN) + j * 16 + (l & 15);
                bf[j] = *(const bf16x8*)(Bb + row * 32 + (((l >> 4) ^ ((row >> 1) & 3)) * 8));
            }
            // stage schedule: ph0 -> (t+1) kh1 ; ph1 -> (t+2) kh0
            if (kh == 0) { if (t + 1 < nt) { stageA(t + 1, 1); stageB(t + 1, 1); } }
            else         { if (t + 2 < nt) { stageA(t + 2, 0); stageB(t + 2, 0); } }

            __builtin_amdgcn_s_setprio(1);
#pragma unroll
            for (int i = 0; i < MIa; ++i)
#pragma unroll
                for (int j = 0; j < MIb; ++j)
                    acc[i][j] = __builtin_amdgcn_mfma_f32_16x16x32_bf16(af[i], bf[j], acc[i][j], 0, 0, 0);
            __builtin_amdgcn_s_setprio(0);
            __builtin_amdgcn_sched_barrier(0);
            __builtin_amdgcn_s_barrier();
        }
    }

    int colb = n0 + wn * (BN / WN) + (l & 15);
    int rowb = m0 + wm * (BM / WM) + ((l >> 4) << 2);
#pragma unroll
    for (int j = 0; j < MIb; j++) {
        int col = colb + j * 16;
        float bval = BIAS ? bias[col] : 0.f;
#pragma unroll
        for (int i = 0; i < MIa; i++) {
#pragma unroll
            for (int r = 0; r < 4; r++) {
                int row = rowb + i * 16 + r;
                float v = acc[i][j][r] + bval;
                if (RELU) v = fmaxf(v, 0.f);
                size_t idx = (size_t)row * N + col;
                if (RES_MODE == 1) v += ((const float*)res)[idx];
                else if (RES_MODE == 2) v += bf2f(((const ushort_t*)res)[idx]);
                if (OUT_BF16) ((ushort_t*)out)[idx] = f2bf(v);
                else          ((float*)out)[idx]    = v;
            }
        }
    }
}

// ---------- MFMA flash attention, v8 (best measured: 82 us) ----------
// QK-early pipeline: S(kt+1) MFMA overlaps softmax(kt) VALU; K 3-buf staged 2
// ahead, V 2-buf; Qs/Ps union (QPs); __expf (v_exp_f32 — R20's exp2f libm call
// regressed 12 us); diag-specialized mask; per-iter __syncthreads (R19's
// counted-vmcnt variant measured worse: K/V are L2-resident).
__global__ __launch_bounds__(256) void fattn_k(
    ushort_t* __restrict__ QKV, const ushort_t* __restrict__ Vt)
{
    __shared__ ushort_t QPs[64 * 64];     // Q staging (prologue) / P tile (loop)
    __shared__ ushort_t Ks[3][64 * 64];
    __shared__ ushort_t Vs[2][64 * 64];
    int lin = blockIdx.x;
    int nwg = gridDim.x;                       // 1024, %8 == 0
    int bid = (lin & 7) * (nwg >> 3) + (lin >> 3);   // bijective XCD remap
    int pr = bid & 15;
    int bh = bid >> 4;
    int b  = bh >> 4;
    int h  = bh & 15;
    int tid = threadIdx.x;
    int lid = tid & 63, w = tid >> 6;

    int srow = w * 16 + (lid >> 3);
    int sseg0 = (lid & 7) ^ (srow & 7);
    int sseg1 = (lid & 7) ^ ((srow + 8) & 7);
    const ushort_t* Kg = QKV + (size_t)(b * T_) * N3_ + C_ + h * HS_;
    const ushort_t* Vg = Vt + (size_t)(b * H_ + h) * HS_ * T_;

    int mrow = w * 16 + (lid & 15);
    int fseg = lid >> 4;
    int qlocb = w * 16 + ((lid >> 4) << 2);

    const __bf16 oneb = (__bf16)1.0f;
    bf16x8 ones = {oneb, oneb, oneb, oneb, oneb, oneb, oneb, oneb};

    auto stageK = [&](int kt) {
        ushort_t* d = Ks[kt % 3];
        gload16(Kg + (size_t)(kt * 64 + srow) * N3_ + sseg0 * 8,     d + w * 1024);
        gload16(Kg + (size_t)(kt * 64 + srow + 8) * N3_ + sseg1 * 8, d + w * 1024 + 512);
    };
    auto stageV = [&](int kt) {
        ushort_t* d = Vs[kt & 1];
        gload16(Vg + (size_t)srow * T_ + kt * 64 + sseg0 * 8,       d + w * 1024);
        gload16(Vg + (size_t)(srow + 8) * T_ + kt * 64 + sseg1 * 8, d + w * 1024 + 512);
    };

    for (int half = 0; half < 2; ++half) {
        int qt = half ? (31 - pr) : pr;
        const ushort_t* Qg = QKV + (size_t)(b * T_ + qt * 64) * N3_ + h * HS_;

        // prologue: stage Q, K0, V0, K1 (all dests wave-private rows)
        gload16(Qg + (size_t)srow * N3_ + sseg0 * 8,       QPs + w * 1024);
        gload16(Qg + (size_t)(srow + 8) * N3_ + sseg1 * 8, QPs + w * 1024 + 512);
        stageK(0);
        stageV(0);
        if (qt >= 1) stageK(1);
        __syncthreads();   // drains all staging + syncs waves

        // Q fragments loop-invariant -> registers; QPs becomes the P tile.
        bf16x8 aqr[2];
        aqr[0] = *(const bf16x8*)(QPs + mrow * 64 + (((0 + fseg) ^ (mrow & 7)) * 8));
        aqr[1] = *(const bf16x8*)(QPs + mrow * 64 + (((4 + fseg) ^ (mrow & 7)) * 8));

        f32x4 accO[4];
#pragma unroll
        for (int j = 0; j < 4; j++) accO[j] = (f32x4){0.f, 0.f, 0.f, 0.f};
        f32x4 accL = (f32x4){0.f, 0.f, 0.f, 0.f};

        auto qk_into = [&](const ushort_t* Kc, f32x4* s) {
#pragma unroll
            for (int j = 0; j < 4; j++) s[j] = (f32x4){0.f, 0.f, 0.f, 0.f};
            __builtin_amdgcn_s_setprio(1);
#pragma unroll
            for (int ks = 0; ks < 2; ks++) {
#pragma unroll
                for (int j = 0; j < 4; j++) {
                    int krow = j * 16 + (lid & 15);
                    bf16x8 bk = *(const bf16x8*)(Kc + krow * 64 + (((ks * 4 + fseg) ^ (krow & 7)) * 8));
                    s[j] = __builtin_amdgcn_mfma_f32_16x16x32_bf16(aqr[ks], bk, s[j], 0, 0, 0);
                }
            }
            __builtin_amdgcn_s_setprio(0);
        };
        auto smax_pv = [&](auto diag_c, f32x4* s, const ushort_t* Vc) {
            constexpr bool DIAG = decltype(diag_c)::value;
#pragma unroll
            for (int r = 0; r < 4; r++) {
                int qloc = qlocb + r;
#pragma unroll
                for (int j = 0; j < 4; j++) {
                    int col = j * 16 + (lid & 15);
                    float p = __expf(s[j][r] * 0.125f);
                    if (DIAG) { if (col > qloc) p = 0.f; }
                    QPs[qloc * 64 + (((col >> 3) ^ (qloc & 7)) * 8) + (col & 7)] = f2bf(p);
                }
            }
            __builtin_amdgcn_s_setprio(1);
#pragma unroll
            for (int ks = 0; ks < 2; ks++) {
                bf16x8 ap = *(const bf16x8*)(QPs + mrow * 64 + (((ks * 4 + fseg) ^ (mrow & 7)) * 8));
                accL = __builtin_amdgcn_mfma_f32_16x16x32_bf16(ap, ones, accL, 0, 0, 0);
#pragma unroll
                for (int j = 0; j < 4; j++) {
                    int drow = j * 16 + (lid & 15);
                    bf16x8 bv = *(const bf16x8*)(Vc + drow * 64 + (((ks * 4 + fseg) ^ (drow & 7)) * 8));
                    accO[j] = __builtin_amdgcn_mfma_f32_16x16x32_bf16(ap, bv, accO[j], 0, 0, 0);
                }
            }
            __builtin_amdgcn_s_setprio(0);
        };

        // sP = S(0)
        f32x4 sP[4], sN[4];
        qk_into(Ks[0], sP);

        for (int kt = 0; kt < qt; ++kt) {
            // early-issue staging: K two ahead, V one ahead
            if (kt + 2 <= qt) stageK(kt + 2);
            stageV(kt + 1);
            // QK(kt+1) — independent of softmax(kt); overlaps its VALU work
            qk_into(Ks[(kt + 1) % 3], sN);
            // softmax(kt) (never diag in-loop) + PV(kt)
            smax_pv(bool_c<false>{}, sP, Vs[kt & 1]);
            __syncthreads();   // staged loads drained; all waves done with K/V[cur]
#pragma unroll
            for (int j = 0; j < 4; j++) sP[j] = sN[j];
        }
        // final tile kt = qt: diag mask
        smax_pv(bool_c<true>{}, sP, Vs[qt & 1]);
        __syncthreads();   // all reads done before next half restages

#pragma unroll
        for (int r = 0; r < 4; r++) {
            float inv = 1.0f / accL[r];
            int qabs = qt * 64 + qlocb + r;
            ushort_t* orow = QKV + (size_t)(b * T_ + qabs) * N3_ + h * HS_;
#pragma unroll
            for (int j = 0; j < 4; j++)
                orow[j * 16 + (lid & 15)] = f2bf(accO[j][r] * inv);
        }
    }
}

extern "C" void kernel_launch(void* const* d_in, const int* in_sizes, int n_in,
                              void* d_out, int out_size, void* d_ws, size_t ws_size,
                              hipStream_t stream)
{
    const float* x   = (const float*)d_in[0];
    const float* g1  = (const float*)d_in[1];
    const float* be1 = (const float*)d_in[2];
    const float* Wq  = (const float*)d_in[3];
    const float* Wk  = (const float*)d_in[4];
    const float* Wv  = (const float*)d_in[5];
    const float* Wo  = (const float*)d_in[6];
    const float* bo  = (const float*)d_in[7];
    const float* g2  = (const float*)d_in[8];
    const float* be2 = (const float*)d_in[9];
    const float* W1  = (const float*)d_in[10];
    const float* b1  = (const float*)d_in[11];
    const float* W2  = (const float*)d_in[12];
    const float* b2  = (const float*)d_in[13];

    // ws (bytes): hB/Vt 16M | big (qkv 48M / ff1 64M, time-disjoint) 64M | WtB 6M |
    // WoB 2M | W1B 8M | W2B 8M = 104 MiB. x2 lives as fp32 in d_out.
    const size_t UB2 = (size_t)BT_ * C_ * 2;
    const size_t WT_B = (size_t)N3_ * C_ * 2;
    const size_t WO_B = (size_t)C_ * C_ * 2;
    const size_t W1_B = (size_t)C_ * F_ * 2;
    const size_t REQ = 5 * UB2 + WT_B + WO_B + 2 * W1_B;
    if (ws_size < REQ) {
        hipMemsetAsync(d_out, 0, (size_t)out_size * 4, stream);
        return;
    }
    char* wsb = (char*)d_ws;
    ushort_t* hB   = (ushort_t*)(wsb);                 // LN out; Vt during attn; h2 after
    ushort_t* qkvB = (ushort_t*)(wsb + UB2);           // big region
    ushort_t* ff1B = qkvB;
    ushort_t* WtB  = (ushort_t*)(wsb + 5 * UB2);
    ushort_t* WoB  = (ushort_t*)(wsb + 5 * UB2 + WT_B);
    ushort_t* W1B  = (ushort_t*)(wsb + 5 * UB2 + WT_B + WO_B);
    ushort_t* W2B  = (ushort_t*)(wsb + 5 * UB2 + WT_B + WO_B + W1_B);
    float* x2F = (float*)d_out;

    // weight prep
    repack_qkv_k<<<3 * 16 * 16, 256, 0, stream>>>(Wq, Wk, Wv, WtB);
    transpose_k<<<dim3(C_ / 64, C_ / 64), 256, 0, stream>>>(Wo, WoB, C_, C_);
    transpose_k<<<dim3(F_ / 64, C_ / 64), 256, 0, stream>>>(W1, W1B, C_, F_);
    transpose_k<<<dim3(C_ / 64, F_ / 64), 256, 0, stream>>>(W2, W2B, F_, C_);

    // h = LN1(x)
    ln_k<0><<<BT_, 256, 0, stream>>>(x, g1, be1, hB);
    // qkv = h @ Wt^T    [8192 x 3072], 128x256 tiles -> grid 768
    mgemm8_k<128,256,2,4,0,0,0,1><<<(N3_ / 256) * (BT_ / 128), 512, 0, stream>>>(
        hB, WtB, nullptr, nullptr, qkvB, BT_, N3_, C_, C_, N3_ / 256);
    // Vt = transpose(V cols) into hB (LN1 output dead)
    transv_k<<<B_ * H_ * (T_ / 64), 256, 0, stream>>>(qkvB, hB);
    // attention (paired q-tiles, XCD-swizzled; O -> Q slots of qkv)
    fattn_k<<<B_ * H_ * 16, 256, 0, stream>>>(qkvB, hB);
    // x2 = x + O @ Wo + bo -> fp32 in d_out   [8192 x 1024], 128x256, grid 256
    mgemm8_k<128,256,2,4,0,1,1,0><<<(C_ / 256) * (BT_ / 128), 512, 0, stream>>>(
        qkvB, WoB, bo, x, x2F, BT_, C_, C_, N3_, C_ / 256);
    // h2 = LN2(x2)
    ln_k<0><<<BT_, 256, 0, stream>>>(x2F, g2, be2, hB);
    // ff1 = relu(h2 @ W1 + b1)   [8192 x 4096], 256x256 tiles, grid 512
    mgemm8_k<256,256,2,4,1,1,0,1><<<(F_ / 256) * (BT_ / 256), 512, 0, stream>>>(
        hB, W1B, b1, nullptr, ff1B, BT_, F_, C_, C_, F_ / 256);
    // out = x2 + ff1 @ W2 + b2   [8192 x 1024], 128x256, grid 256
    mgemm8_k<128,256,2,4,0,1,1,0><<<(C_ / 256) * (BT_ / 128), 512, 0, stream>>>(
        ff1B, W2B, b2, x2F, (float*)d_out, BT_, C_, F_, F_, C_ / 256);
}

// Round 22
// 352.622 us; speedup vs baseline: 1.0525x; 1.0244x over previous
//
#include <hip/hip_runtime.h>
#include <math.h>

#define B_  4
#define T_  2048
#define C_  1024
#define H_  16
#define HS_ 64
#define BT_ (B_*T_)
#define F_  (4*C_)
#define N3_ (3*C_)

typedef unsigned short ushort_t;
typedef __attribute__((ext_vector_type(4))) unsigned short us4;
typedef __attribute__((ext_vector_type(8))) unsigned short us8;
typedef __attribute__((ext_vector_type(4))) float f32x4;
typedef __attribute__((ext_vector_type(8))) __bf16 bf16x8;

template<bool V> struct bool_c { static constexpr bool value = V; };

__device__ __forceinline__ float bf2f(ushort_t u) {
    union { unsigned int i; float f; } c; c.i = ((unsigned int)u) << 16; return c.f;
}
// Native bf16 convert (RNE) — single v_cvt instruction on gfx950.
__device__ __forceinline__ ushort_t f2bf(float f) {
    union { __bf16 b; ushort_t u; } c; c.b = (__bf16)f; return c.u;
}

// global_load_lds: LDS dest = wave-uniform base + lane*16 (HW); global src per-lane.
#define GLB_(p) ((const __attribute__((address_space(1))) unsigned int*)(size_t)(p))
#define LDS_(p) ((__attribute__((address_space(3))) unsigned int*)(unsigned int)(size_t)(p))
__device__ __forceinline__ void gload16(const void* g, void* l) {
    __builtin_amdgcn_global_load_lds(GLB_(g), LDS_(l), 16, 0, 0);
}

template<int N> __device__ __forceinline__ void vm_wait() {
    if constexpr (N >= 8)      asm volatile("s_waitcnt vmcnt(8)" ::: "memory");
    else if constexpr (N == 6) asm volatile("s_waitcnt vmcnt(6)" ::: "memory");
    else if constexpr (N == 4) asm volatile("s_waitcnt vmcnt(4)" ::: "memory");
    else if constexpr (N == 3) asm volatile("s_waitcnt vmcnt(3)" ::: "memory");
    else if constexpr (N == 2) asm volatile("s_waitcnt vmcnt(2)" ::: "memory");
    else                       asm volatile("s_waitcnt vmcnt(0)" ::: "memory");
}

// ---------- prep: Wq/Wk/Wv [H][C][hs] f32 -> WtB [3C][C] bf16 (row n = p*C + h*64 + s) ----------
__global__ __launch_bounds__(256) void repack_qkv_k(
    const float* __restrict__ Wq, const float* __restrict__ Wk,
    const float* __restrict__ Wv, ushort_t* __restrict__ WtB)
{
    __shared__ float tile[64][65];
    int bid = blockIdx.x;
    int p  = bid >> 8;
    int h  = (bid >> 4) & 15;
    int c0 = (bid & 15) * 64;
    const float* W = (p == 0) ? Wq : ((p == 1) ? Wk : Wv);
    int t = threadIdx.x;
    int cl = t >> 2, seg = (t & 3) * 16;
    const float* src = W + ((size_t)h * C_ + c0 + cl) * HS_ + seg;
#pragma unroll
    for (int i = 0; i < 4; i++) {
        float4 v = *(const float4*)(src + i * 4);
        tile[cl][seg + i*4 + 0] = v.x; tile[cl][seg + i*4 + 1] = v.y;
        tile[cl][seg + i*4 + 2] = v.z; tile[cl][seg + i*4 + 3] = v.w;
    }
    __syncthreads();
    int sl = t >> 2;                 // s within head
    int n = p * C_ + h * HS_ + sl;   // output row
    ushort_t* dst = WtB + (size_t)n * C_ + c0 + seg;
    us8 o0, o1;
#pragma unroll
    for (int e = 0; e < 8; e++) { o0[e] = f2bf(tile[seg + e][sl]); o1[e] = f2bf(tile[seg + 8 + e][sl]); }
    *(us8*)dst = o0; *(us8*)(dst + 8) = o1;
}

// ---------- prep: generic transpose  in f32 [K][N] -> out bf16 [N][K] ----------
__global__ __launch_bounds__(256) void transpose_k(
    const float* __restrict__ in, ushort_t* __restrict__ out, int K, int N)
{
    __shared__ float tile[64][65];
    int n0 = blockIdx.x * 64, k0 = blockIdx.y * 64;
    int t = threadIdx.x;
    int kl = t >> 2, seg = (t & 3) * 16;
    const float* src = in + (size_t)(k0 + kl) * N + n0 + seg;
#pragma unroll
    for (int i = 0; i < 4; i++) {
        float4 v = *(const float4*)(src + i * 4);
        tile[kl][seg + i*4 + 0] = v.x; tile[kl][seg + i*4 + 1] = v.y;
        tile[kl][seg + i*4 + 2] = v.z; tile[kl][seg + i*4 + 3] = v.w;
    }
    __syncthreads();
    int nl = t >> 2;
    ushort_t* dst = out + (size_t)(n0 + nl) * K + k0 + seg;
    us8 o0, o1;
#pragma unroll
    for (int e = 0; e < 8; e++) { o0[e] = f2bf(tile[seg + e][nl]); o1[e] = f2bf(tile[seg + 8 + e][nl]); }
    *(us8*)dst = o0; *(us8*)(dst + 8) = o1;
}

// ---------- prep: V cols of qkv [B*T][3C] -> Vt [B][H][64][T] bf16 ----------
__global__ __launch_bounds__(256) void transv_k(
    const ushort_t* __restrict__ QKV, ushort_t* __restrict__ Vt)
{
    __shared__ ushort_t tl[64][72];
    int bid = blockIdx.x;
    int tt = bid & 31;           // T/64 tiles
    int bh = bid >> 5;
    int b  = bh >> 4;
    int h  = bh & 15;
    int t = threadIdx.x;
    int r = t >> 2, sg = (t & 3) * 16;
    const ushort_t* src = QKV + (size_t)(b * T_ + tt * 64 + r) * N3_ + 2 * C_ + h * HS_ + sg;
    us8 a0 = *(const us8*)src;
    us8 a1 = *(const us8*)(src + 8);
#pragma unroll
    for (int e = 0; e < 8; e++) { tl[r][sg + e] = a0[e]; tl[r][sg + 8 + e] = a1[e]; }
    __syncthreads();
    ushort_t* dst = Vt + ((size_t)(b * H_ + h) * HS_ + r) * T_ + tt * 64 + sg;
    us8 o0, o1;
#pragma unroll
    for (int e = 0; e < 8; e++) { o0[e] = tl[sg + e][r]; o1[e] = tl[sg + 8 + e][r]; }
    *(us8*)dst = o0; *(us8*)(dst + 8) = o1;
}

// ---------- layernorm -> bf16 out. IN_BF16: 0 = fp32 input, 1 = bf16 input ----------
template<int IN_BF16>
__global__ __launch_bounds__(256) void ln_k(
    const void* __restrict__ xv, const float* __restrict__ g,
    const float* __restrict__ b, ushort_t* __restrict__ out)
{
    int row = blockIdx.x;
    int t = threadIdx.x;
    float v[4];
    if (IN_BF16) {
        const ushort_t* xr = (const ushort_t*)xv + (size_t)row * C_;
        us4 u = *(const us4*)(xr + t * 4);
#pragma unroll
        for (int i = 0; i < 4; i++) v[i] = bf2f(u[i]);
    } else {
        const float* xr = (const float*)xv + (size_t)row * C_;
        float4 f = *(const float4*)(xr + t * 4);
        v[0] = f.x; v[1] = f.y; v[2] = f.z; v[3] = f.w;
    }
    float s  = v[0] + v[1] + v[2] + v[3];
    float ss = v[0]*v[0] + v[1]*v[1] + v[2]*v[2] + v[3]*v[3];
#pragma unroll
    for (int off = 32; off > 0; off >>= 1) {
        s  += __shfl_xor(s, off);
        ss += __shfl_xor(ss, off);
    }
    __shared__ float red[8];
    int wv = t >> 6;
    if ((t & 63) == 0) { red[wv*2] = s; red[wv*2+1] = ss; }
    __syncthreads();
    s  = red[0] + red[2] + red[4] + red[6];
    ss = red[1] + red[3] + red[5] + red[7];
    float mu  = s * (1.0f / C_);
    float var = ss * (1.0f / C_) - mu * mu;
    float rs  = rsqrtf(var + 1e-5f);
    float4 gv = *(const float4*)(g + t * 4);
    float4 bv = *(const float4*)(b + t * 4);
    us4 o;
    o[0] = f2bf((v[0] - mu) * rs * gv.x + bv.x);
    o[1] = f2bf((v[1] - mu) * rs * gv.y + bv.y);
    o[2] = f2bf((v[2] - mu) * rs * gv.z + bv.z);
    o[3] = f2bf((v[3] - mu) * rs * gv.w + bv.w);
    *(us4*)(out + (size_t)row * C_ + t * 4) = o;
}

// ---------- 8-phase MFMA bf16 GEMM (T1 swizzle; UNIT-derived vmcnt) ----------
// Validated R21 structure. NEW (R22): for OUT_BF16 (RES_MODE==0) the epilogue
// stages each 16x64 wave fragment through wave-private LDS (aliasing As — legal:
// last K-loop s_barrier certifies all As reads done; DS ops are in-order per
// wave, no new barriers) and emits fully-coalesced us8 row stores, replacing
// 64 scalar 2B stores/thread (R21 W1: WRITE_SIZE 125MB vs 64MB ideal).
template<int BM, int BN, int WM, int WN, int RELU, int BIAS, int RES_MODE, int OUT_BF16>
__global__ __launch_bounds__(WM * WN * 64) void mgemm8_k(
    const ushort_t* __restrict__ A, const ushort_t* __restrict__ Bw,
    const float* __restrict__ bias, const void* __restrict__ res,
    void* __restrict__ out, int M, int N, int K, int lda, int gx)
{
    constexpr int THREADS = WM * WN * 64;
    constexpr int MIa = BM / WM / 16;
    constexpr int MIb = BN / WN / 16;
    constexpr int A_INSTS = (BM * 64) / (16 * THREADS);   // gload insts per thread per A k-half
    constexpr int B_INSTS = (BN * 64) / (16 * THREADS);
    constexpr int UNIT = A_INSTS + B_INSTS;               // VMEM insts per staging unit
    __shared__ ushort_t As[4 * BM * 32];                  // 2buf x 2kh
    __shared__ ushort_t Bs[4 * BN * 32];

    int tid = threadIdx.x;
    int l = tid & 63, w = tid >> 6;
    int wm = w / WN, wn = w % WN;
    int lin = blockIdx.x;
    int nwg = gridDim.x;
    int swz = (lin & 7) * (nwg >> 3) + (lin >> 3);
    int bx = swz % gx, by = swz / gx;
    int m0 = by * BM, n0 = bx * BN;
    const int nt = K >> 6;

    auto stageA = [&](int tile, int kh) {
        ushort_t* dst = As + ((tile & 1) * 2 + kh) * (BM * 32);
#pragma unroll
        for (int inst = 0; inst < A_INSTS; ++inst) {
            int slot = inst * THREADS + tid;
            int row = slot >> 2, q = slot & 3;
            const ushort_t* src = A + (size_t)(m0 + row) * lda + tile * 64 + kh * 32
                                  + ((q ^ ((row >> 1) & 3)) * 8);
            gload16(src, dst + (inst * THREADS + w * 64) * 8);
        }
    };
    auto stageB = [&](int tile, int kh) {
        ushort_t* dst = Bs + ((tile & 1) * 2 + kh) * (BN * 32);
#pragma unroll
        for (int inst = 0; inst < B_INSTS; ++inst) {
            int slot = inst * THREADS + tid;
            int row = slot >> 2, q = slot & 3;
            const ushort_t* src = Bw + (size_t)(n0 + row) * K + tile * 64 + kh * 32
                                  + ((q ^ ((row >> 1) & 3)) * 8);
            gload16(src, dst + (inst * THREADS + w * 64) * 8);
        }
    };

    f32x4 acc[MIa][MIb];
#pragma unroll
    for (int i = 0; i < MIa; i++)
#pragma unroll
        for (int j = 0; j < MIb; j++) acc[i][j] = (f32x4){0.f, 0.f, 0.f, 0.f};

    // prologue: 3 units ahead (t0kh0, t0kh1, t1kh0)
    stageA(0, 0); stageB(0, 0);
    stageA(0, 1); stageB(0, 1);
    stageA(1, 0); stageB(1, 0);

    for (int t = 0; t < nt; ++t) {
        int buf = t & 1;
#pragma unroll
        for (int kh = 0; kh < 2; ++kh) {
            // unit for this phase was issued 3 phases ago; 2 units behind it
            if (t == nt - 1) { if (kh == 0) vm_wait<UNIT>(); else vm_wait<0>(); }
            else vm_wait<2 * UNIT>();
            __builtin_amdgcn_s_barrier();
            __builtin_amdgcn_sched_barrier(0);

            const ushort_t* Ab = As + (buf * 2 + kh) * (BM * 32);
            const ushort_t* Bb = Bs + (buf * 2 + kh) * (BN * 32);
            bf16x8 af[MIa], bf[MIb];
#pragma unroll
            for (int i = 0; i < MIa; ++i) {
                int row = wm * (BM / WM) + i * 16 + (l & 15);
                af[i] = *(const bf16x8*)(Ab + row * 32 + (((l >> 4) ^ ((row >> 1) & 3)) * 8));
            }
#pragma unroll
            for (int j = 0; j < MIb; ++j) {
                int row = wn * (BN / WN) + j * 16 + (l & 15);
                bf[j] = *(const bf16x8*)(Bb + row * 32 + (((l >> 4) ^ ((row >> 1) & 3)) * 8));
            }
            // stage schedule: ph0 -> (t+1) kh1 ; ph1 -> (t+2) kh0
            if (kh == 0) { if (t + 1 < nt) { stageA(t + 1, 1); stageB(t + 1, 1); } }
            else         { if (t + 2 < nt) { stageA(t + 2, 0); stageB(t + 2, 0); } }

            __builtin_amdgcn_s_setprio(1);
#pragma unroll
            for (int i = 0; i < MIa; ++i)
#pragma unroll
                for (int j = 0; j < MIb; ++j)
                    acc[i][j] = __builtin_amdgcn_mfma_f32_16x16x32_bf16(af[i], bf[j], acc[i][j], 0, 0, 0);
            __builtin_amdgcn_s_setprio(0);
            __builtin_amdgcn_sched_barrier(0);
            __builtin_amdgcn_s_barrier();
        }
    }

    if (OUT_BF16 && RES_MODE == 0) {
        // LDS-staged vectorized epilogue (wave-private 16x64 scratch in As)
        ushort_t* scratch = As + w * 1024;          // 2KB/wave, 16KB total (fits all configs)
#pragma unroll
        for (int i = 0; i < MIa; i++) {
#pragma unroll
            for (int j = 0; j < MIb; j++) {
                int colo = wn * 64 + j * 16 + (l & 15);       // block-local col
                float bval = BIAS ? bias[n0 + colo] : 0.f;
#pragma unroll
                for (int r = 0; r < 4; r++) {
                    float v = acc[i][j][r] + bval;
                    if (RELU) v = fmaxf(v, 0.f);
                    scratch[(((l >> 4) << 2) + r) * 64 + j * 16 + (l & 15)] = f2bf(v);
                }
            }
            // in-order DS per wave: reads below see the writes above (lgkmcnt-tracked)
#pragma unroll
            for (int rr = 0; rr < 2; rr++) {
                int lrow = rr * 8 + (l >> 3);
                us8 vv = *(const us8*)(scratch + lrow * 64 + (l & 7) * 8);
                int grow = m0 + wm * (BM / WM) + i * 16 + lrow;
                *(us8*)((ushort_t*)out + (size_t)grow * N + n0 + wn * 64 + (l & 7) * 8) = vv;
            }
        }
    } else {
        int colb = n0 + wn * (BN / WN) + (l & 15);
        int rowb = m0 + wm * (BM / WM) + ((l >> 4) << 2);
#pragma unroll
        for (int j = 0; j < MIb; j++) {
            int col = colb + j * 16;
            float bval = BIAS ? bias[col] : 0.f;
#pragma unroll
            for (int i = 0; i < MIa; i++) {
#pragma unroll
                for (int r = 0; r < 4; r++) {
                    int row = rowb + i * 16 + r;
                    float v = acc[i][j][r] + bval;
                    if (RELU) v = fmaxf(v, 0.f);
                    size_t idx = (size_t)row * N + col;
                    if (RES_MODE == 1) v += ((const float*)res)[idx];
                    else if (RES_MODE == 2) v += bf2f(((const ushort_t*)res)[idx]);
                    if (OUT_BF16) ((ushort_t*)out)[idx] = f2bf(v);
                    else          ((float*)out)[idx]    = v;
                }
            }
        }
    }
}

// ---------- MFMA flash attention, v8 (best measured: 82 us) ----------
// QK-early pipeline: S(kt+1) MFMA overlaps softmax(kt) VALU; K 3-buf staged 2
// ahead, V 2-buf; Qs/Ps union (QPs); __expf (v_exp_f32); diag-specialized mask.
__global__ __launch_bounds__(256) void fattn_k(
    ushort_t* __restrict__ QKV, const ushort_t* __restrict__ Vt)
{
    __shared__ ushort_t QPs[64 * 64];     // Q staging (prologue) / P tile (loop)
    __shared__ ushort_t Ks[3][64 * 64];
    __shared__ ushort_t Vs[2][64 * 64];
    int lin = blockIdx.x;
    int nwg = gridDim.x;                       // 1024, %8 == 0
    int bid = (lin & 7) * (nwg >> 3) + (lin >> 3);   // bijective XCD remap
    int pr = bid & 15;
    int bh = bid >> 4;
    int b  = bh >> 4;
    int h  = bh & 15;
    int tid = threadIdx.x;
    int lid = tid & 63, w = tid >> 6;

    int srow = w * 16 + (lid >> 3);
    int sseg0 = (lid & 7) ^ (srow & 7);
    int sseg1 = (lid & 7) ^ ((srow + 8) & 7);
    const ushort_t* Kg = QKV + (size_t)(b * T_) * N3_ + C_ + h * HS_;
    const ushort_t* Vg = Vt + (size_t)(b * H_ + h) * HS_ * T_;

    int mrow = w * 16 + (lid & 15);
    int fseg = lid >> 4;
    int qlocb = w * 16 + ((lid >> 4) << 2);

    const __bf16 oneb = (__bf16)1.0f;
    bf16x8 ones = {oneb, oneb, oneb, oneb, oneb, oneb, oneb, oneb};

    auto stageK = [&](int kt) {
        ushort_t* d = Ks[kt % 3];
        gload16(Kg + (size_t)(kt * 64 + srow) * N3_ + sseg0 * 8,     d + w * 1024);
        gload16(Kg + (size_t)(kt * 64 + srow + 8) * N3_ + sseg1 * 8, d + w * 1024 + 512);
    };
    auto stageV = [&](int kt) {
        ushort_t* d = Vs[kt & 1];
        gload16(Vg + (size_t)srow * T_ + kt * 64 + sseg0 * 8,       d + w * 1024);
        gload16(Vg + (size_t)(srow + 8) * T_ + kt * 64 + sseg1 * 8, d + w * 1024 + 512);
    };

    for (int half = 0; half < 2; ++half) {
        int qt = half ? (31 - pr) : pr;
        const ushort_t* Qg = QKV + (size_t)(b * T_ + qt * 64) * N3_ + h * HS_;

        // prologue: stage Q, K0, V0, K1 (all dests wave-private rows)
        gload16(Qg + (size_t)srow * N3_ + sseg0 * 8,       QPs + w * 1024);
        gload16(Qg + (size_t)(srow + 8) * N3_ + sseg1 * 8, QPs + w * 1024 + 512);
        stageK(0);
        stageV(0);
        if (qt >= 1) stageK(1);
        __syncthreads();   // drains all staging + syncs waves

        // Q fragments loop-invariant -> registers; QPs becomes the P tile.
        bf16x8 aqr[2];
        aqr[0] = *(const bf16x8*)(QPs + mrow * 64 + (((0 + fseg) ^ (mrow & 7)) * 8));
        aqr[1] = *(const bf16x8*)(QPs + mrow * 64 + (((4 + fseg) ^ (mrow & 7)) * 8));

        f32x4 accO[4];
#pragma unroll
        for (int j = 0; j < 4; j++) accO[j] = (f32x4){0.f, 0.f, 0.f, 0.f};
        f32x4 accL = (f32x4){0.f, 0.f, 0.f, 0.f};

        auto qk_into = [&](const ushort_t* Kc, f32x4* s) {
#pragma unroll
            for (int j = 0; j < 4; j++) s[j] = (f32x4){0.f, 0.f, 0.f, 0.f};
            __builtin_amdgcn_s_setprio(1);
#pragma unroll
            for (int ks = 0; ks < 2; ks++) {
#pragma unroll
                for (int j = 0; j < 4; j++) {
                    int krow = j * 16 + (lid & 15);
                    bf16x8 bk = *(const bf16x8*)(Kc + krow * 64 + (((ks * 4 + fseg) ^ (krow & 7)) * 8));
                    s[j] = __builtin_amdgcn_mfma_f32_16x16x32_bf16(aqr[ks], bk, s[j], 0, 0, 0);
                }
            }
            __builtin_amdgcn_s_setprio(0);
        };
        auto smax_pv = [&](auto diag_c, f32x4* s, const ushort_t* Vc) {
            constexpr bool DIAG = decltype(diag_c)::value;
#pragma unroll
            for (int r = 0; r < 4; r++) {
                int qloc = qlocb + r;
#pragma unroll
                for (int j = 0; j < 4; j++) {
                    int col = j * 16 + (lid & 15);
                    float p = __expf(s[j][r] * 0.125f);
                    if (DIAG) { if (col > qloc) p = 0.f; }
                    QPs[qloc * 64 + (((col >> 3) ^ (qloc & 7)) * 8) + (col & 7)] = f2bf(p);
                }
            }
            __builtin_amdgcn_s_setprio(1);
#pragma unroll
            for (int ks = 0; ks < 2; ks++) {
                bf16x8 ap = *(const bf16x8*)(QPs + mrow * 64 + (((ks * 4 + fseg) ^ (mrow & 7)) * 8));
                accL = __builtin_amdgcn_mfma_f32_16x16x32_bf16(ap, ones, accL, 0, 0, 0);
#pragma unroll
                for (int j = 0; j < 4; j++) {
                    int drow = j * 16 + (lid & 15);
                    bf16x8 bv = *(const bf16x8*)(Vc + drow * 64 + (((ks * 4 + fseg) ^ (drow & 7)) * 8));
                    accO[j] = __builtin_amdgcn_mfma_f32_16x16x32_bf16(ap, bv, accO[j], 0, 0, 0);
                }
            }
            __builtin_amdgcn_s_setprio(0);
        };

        // sP = S(0)
        f32x4 sP[4], sN[4];
        qk_into(Ks[0], sP);

        for (int kt = 0; kt < qt; ++kt) {
            // early-issue staging: K two ahead, V one ahead
            if (kt + 2 <= qt) stageK(kt + 2);
            stageV(kt + 1);
            // QK(kt+1) — independent of softmax(kt); overlaps its VALU work
            qk_into(Ks[(kt + 1) % 3], sN);
            // softmax(kt) (never diag in-loop) + PV(kt)
            smax_pv(bool_c<false>{}, sP, Vs[kt & 1]);
            __syncthreads();   // staged loads drained; all waves done with K/V[cur]
#pragma unroll
            for (int j = 0; j < 4; j++) sP[j] = sN[j];
        }
        // final tile kt = qt: diag mask
        smax_pv(bool_c<true>{}, sP, Vs[qt & 1]);
        __syncthreads();   // all reads done before next half restages

#pragma unroll
        for (int r = 0; r < 4; r++) {
            float inv = 1.0f / accL[r];
            int qabs = qt * 64 + qlocb + r;
            ushort_t* orow = QKV + (size_t)(b * T_ + qabs) * N3_ + h * HS_;
#pragma unroll
            for (int j = 0; j < 4; j++)
                orow[j * 16 + (lid & 15)] = f2bf(accO[j][r] * inv);
        }
    }
}

extern "C" void kernel_launch(void* const* d_in, const int* in_sizes, int n_in,
                              void* d_out, int out_size, void* d_ws, size_t ws_size,
                              hipStream_t stream)
{
    const float* x   = (const float*)d_in[0];
    const float* g1  = (const float*)d_in[1];
    const float* be1 = (const float*)d_in[2];
    const float* Wq  = (const float*)d_in[3];
    const float* Wk  = (const float*)d_in[4];
    const float* Wv  = (const float*)d_in[5];
    const float* Wo  = (const float*)d_in[6];
    const float* bo  = (const float*)d_in[7];
    const float* g2  = (const float*)d_in[8];
    const float* be2 = (const float*)d_in[9];
    const float* W1  = (const float*)d_in[10];
    const float* b1  = (const float*)d_in[11];
    const float* W2  = (const float*)d_in[12];
    const float* b2  = (const float*)d_in[13];

    // ws (bytes): hB/Vt 16M | big (qkv 48M / ff1 64M, time-disjoint) 64M | WtB 6M |
    // WoB 2M | W1B 8M | W2B 8M = 104 MiB. x2 lives as fp32 in d_out.
    const size_t UB2 = (size_t)BT_ * C_ * 2;
    const size_t WT_B = (size_t)N3_ * C_ * 2;
    const size_t WO_B = (size_t)C_ * C_ * 2;
    const size_t W1_B = (size_t)C_ * F_ * 2;
    const size_t REQ = 5 * UB2 + WT_B + WO_B + 2 * W1_B;
    if (ws_size < REQ) {
        hipMemsetAsync(d_out, 0, (size_t)out_size * 4, stream);
        return;
    }
    char* wsb = (char*)d_ws;
    ushort_t* hB   = (ushort_t*)(wsb);                 // LN out; Vt during attn; h2 after
    ushort_t* qkvB = (ushort_t*)(wsb + UB2);           // big region
    ushort_t* ff1B = qkvB;
    ushort_t* WtB  = (ushort_t*)(wsb + 5 * UB2);
    ushort_t* WoB  = (ushort_t*)(wsb + 5 * UB2 + WT_B);
    ushort_t* W1B  = (ushort_t*)(wsb + 5 * UB2 + WT_B + WO_B);
    ushort_t* W2B  = (ushort_t*)(wsb + 5 * UB2 + WT_B + WO_B + W1_B);
    float* x2F = (float*)d_out;

    // weight prep
    repack_qkv_k<<<3 * 16 * 16, 256, 0, stream>>>(Wq, Wk, Wv, WtB);
    transpose_k<<<dim3(C_ / 64, C_ / 64), 256, 0, stream>>>(Wo, WoB, C_, C_);
    transpose_k<<<dim3(F_ / 64, C_ / 64), 256, 0, stream>>>(W1, W1B, C_, F_);
    transpose_k<<<dim3(C_ / 64, F_ / 64), 256, 0, stream>>>(W2, W2B, F_, C_);

    // h = LN1(x)
    ln_k<0><<<BT_, 256, 0, stream>>>(x, g1, be1, hB);
    // qkv = h @ Wt^T    [8192 x 3072], 128x256 tiles -> grid 768
    mgemm8_k<128,256,2,4,0,0,0,1><<<(N3_ / 256) * (BT_ / 128), 512, 0, stream>>>(
        hB, WtB, nullptr, nullptr, qkvB, BT_, N3_, C_, C_, N3_ / 256);
    // Vt = transpose(V cols) into hB (LN1 output dead)
    transv_k<<<B_ * H_ * (T_ / 64), 256, 0, stream>>>(qkvB, hB);
    // attention (paired q-tiles, XCD-swizzled; O -> Q slots of qkv)
    fattn_k<<<B_ * H_ * 16, 256, 0, stream>>>(qkvB, hB);
    // x2 = x + O @ Wo + bo -> fp32 in d_out   [8192 x 1024], 128x256, grid 256
    mgemm8_k<128,256,2,4,0,1,1,0><<<(C_ / 256) * (BT_ / 128), 512, 0, stream>>>(
        qkvB, WoB, bo, x, x2F, BT_, C_, C_, N3_, C_ / 256);
    // h2 = LN2(x2)
    ln_k<0><<<BT_, 256, 0, stream>>>(x2F, g2, be2, hB);
    // ff1 = relu(h2 @ W1 + b1)   [8192 x 4096], 256x256 tiles, grid 512
    mgemm8_k<256,256,2,4,1,1,0,1><<<(F_ / 256) * (BT_ / 256), 512, 0, stream>>>(
        hB, W1B, b1, nullptr, ff1B, BT_, F_, C_, C_, F_ / 256);
    // out = x2 + ff1 @ W2 + b2   [8192 x 1024], 128x256, grid 256
    mgemm8_k<128,256,2,4,0,1,1,0><<<(C_ / 256) * (BT_ / 128), 512, 0, stream>>>(
        ff1B, W2B, b2, x2F, (float*)d_out, BT_, C_, F_, F_, C_ / 256);
}

// Round 23
// 348.761 us; speedup vs baseline: 1.0642x; 1.0111x over previous
//
#include <hip/hip_runtime.h>
#include <math.h>

#define B_  4
#define T_  2048
#define C_  1024
#define H_  16
#define HS_ 64
#define BT_ (B_*T_)
#define F_  (4*C_)
#define N3_ (3*C_)

typedef unsigned short ushort_t;
typedef __attribute__((ext_vector_type(4))) unsigned short us4;
typedef __attribute__((ext_vector_type(8))) unsigned short us8;
typedef __attribute__((ext_vector_type(4))) float f32x4;
typedef __attribute__((ext_vector_type(8))) __bf16 bf16x8;

template<bool V> struct bool_c { static constexpr bool value = V; };

__device__ __forceinline__ float bf2f(ushort_t u) {
    union { unsigned int i; float f; } c; c.i = ((unsigned int)u) << 16; return c.f;
}
// Native bf16 convert (RNE) — single v_cvt instruction on gfx950.
__device__ __forceinline__ ushort_t f2bf(float f) {
    union { __bf16 b; ushort_t u; } c; c.b = (__bf16)f; return c.u;
}

// global_load_lds: LDS dest = wave-uniform base + lane*16 (HW); global src per-lane.
#define GLB_(p) ((const __attribute__((address_space(1))) unsigned int*)(size_t)(p))
#define LDS_(p) ((__attribute__((address_space(3))) unsigned int*)(unsigned int)(size_t)(p))
__device__ __forceinline__ void gload16(const void* g, void* l) {
    __builtin_amdgcn_global_load_lds(GLB_(g), LDS_(l), 16, 0, 0);
}

template<int N> __device__ __forceinline__ void vm_wait() {
    if constexpr (N >= 8)      asm volatile("s_waitcnt vmcnt(8)" ::: "memory");
    else if constexpr (N == 6) asm volatile("s_waitcnt vmcnt(6)" ::: "memory");
    else if constexpr (N == 4) asm volatile("s_waitcnt vmcnt(4)" ::: "memory");
    else if constexpr (N == 3) asm volatile("s_waitcnt vmcnt(3)" ::: "memory");
    else if constexpr (N == 2) asm volatile("s_waitcnt vmcnt(2)" ::: "memory");
    else                       asm volatile("s_waitcnt vmcnt(0)" ::: "memory");
}

// ---------- prep: Wq/Wk/Wv [H][C][hs] f32 -> WtB [3C][C] bf16 (row n = p*C + h*64 + s) ----------
__global__ __launch_bounds__(256) void repack_qkv_k(
    const float* __restrict__ Wq, const float* __restrict__ Wk,
    const float* __restrict__ Wv, ushort_t* __restrict__ WtB)
{
    __shared__ float tile[64][65];
    int bid = blockIdx.x;
    int p  = bid >> 8;
    int h  = (bid >> 4) & 15;
    int c0 = (bid & 15) * 64;
    const float* W = (p == 0) ? Wq : ((p == 1) ? Wk : Wv);
    int t = threadIdx.x;
    int cl = t >> 2, seg = (t & 3) * 16;
    const float* src = W + ((size_t)h * C_ + c0 + cl) * HS_ + seg;
#pragma unroll
    for (int i = 0; i < 4; i++) {
        float4 v = *(const float4*)(src + i * 4);
        tile[cl][seg + i*4 + 0] = v.x; tile[cl][seg + i*4 + 1] = v.y;
        tile[cl][seg + i*4 + 2] = v.z; tile[cl][seg + i*4 + 3] = v.w;
    }
    __syncthreads();
    int sl = t >> 2;                 // s within head
    int n = p * C_ + h * HS_ + sl;   // output row
    ushort_t* dst = WtB + (size_t)n * C_ + c0 + seg;
    us8 o0, o1;
#pragma unroll
    for (int e = 0; e < 8; e++) { o0[e] = f2bf(tile[seg + e][sl]); o1[e] = f2bf(tile[seg + 8 + e][sl]); }
    *(us8*)dst = o0; *(us8*)(dst + 8) = o1;
}

// ---------- prep: generic transpose  in f32 [K][N] -> out bf16 [N][K] ----------
__global__ __launch_bounds__(256) void transpose_k(
    const float* __restrict__ in, ushort_t* __restrict__ out, int K, int N)
{
    __shared__ float tile[64][65];
    int n0 = blockIdx.x * 64, k0 = blockIdx.y * 64;
    int t = threadIdx.x;
    int kl = t >> 2, seg = (t & 3) * 16;
    const float* src = in + (size_t)(k0 + kl) * N + n0 + seg;
#pragma unroll
    for (int i = 0; i < 4; i++) {
        float4 v = *(const float4*)(src + i * 4);
        tile[kl][seg + i*4 + 0] = v.x; tile[kl][seg + i*4 + 1] = v.y;
        tile[kl][seg + i*4 + 2] = v.z; tile[kl][seg + i*4 + 3] = v.w;
    }
    __syncthreads();
    int nl = t >> 2;
    ushort_t* dst = out + (size_t)(n0 + nl) * K + k0 + seg;
    us8 o0, o1;
#pragma unroll
    for (int e = 0; e < 8; e++) { o0[e] = f2bf(tile[seg + e][nl]); o1[e] = f2bf(tile[seg + 8 + e][nl]); }
    *(us8*)dst = o0; *(us8*)(dst + 8) = o1;
}

// ---------- prep: V cols of qkv [B*T][3C] -> Vt [B][H][64][T] bf16 ----------
__global__ __launch_bounds__(256) void transv_k(
    const ushort_t* __restrict__ QKV, ushort_t* __restrict__ Vt)
{
    __shared__ ushort_t tl[64][72];
    int bid = blockIdx.x;
    int tt = bid & 31;           // T/64 tiles
    int bh = bid >> 5;
    int b  = bh >> 4;
    int h  = bh & 15;
    int t = threadIdx.x;
    int r = t >> 2, sg = (t & 3) * 16;
    const ushort_t* src = QKV + (size_t)(b * T_ + tt * 64 + r) * N3_ + 2 * C_ + h * HS_ + sg;
    us8 a0 = *(const us8*)src;
    us8 a1 = *(const us8*)(src + 8);
#pragma unroll
    for (int e = 0; e < 8; e++) { tl[r][sg + e] = a0[e]; tl[r][sg + 8 + e] = a1[e]; }
    __syncthreads();
    ushort_t* dst = Vt + ((size_t)(b * H_ + h) * HS_ + r) * T_ + tt * 64 + sg;
    us8 o0, o1;
#pragma unroll
    for (int e = 0; e < 8; e++) { o0[e] = tl[sg + e][r]; o1[e] = tl[sg + 8 + e][r]; }
    *(us8*)dst = o0; *(us8*)(dst + 8) = o1;
}

// ---------- layernorm -> bf16 out. IN_BF16: 0 = fp32 input, 1 = bf16 input ----------
template<int IN_BF16>
__global__ __launch_bounds__(256) void ln_k(
    const void* __restrict__ xv, const float* __restrict__ g,
    const float* __restrict__ b, ushort_t* __restrict__ out)
{
    int row = blockIdx.x;
    int t = threadIdx.x;
    float v[4];
    if (IN_BF16) {
        const ushort_t* xr = (const ushort_t*)xv + (size_t)row * C_;
        us4 u = *(const us4*)(xr + t * 4);
#pragma unroll
        for (int i = 0; i < 4; i++) v[i] = bf2f(u[i]);
    } else {
        const float* xr = (const float*)xv + (size_t)row * C_;
        float4 f = *(const float4*)(xr + t * 4);
        v[0] = f.x; v[1] = f.y; v[2] = f.z; v[3] = f.w;
    }
    float s  = v[0] + v[1] + v[2] + v[3];
    float ss = v[0]*v[0] + v[1]*v[1] + v[2]*v[2] + v[3]*v[3];
#pragma unroll
    for (int off = 32; off > 0; off >>= 1) {
        s  += __shfl_xor(s, off);
        ss += __shfl_xor(ss, off);
    }
    __shared__ float red[8];
    int wv = t >> 6;
    if ((t & 63) == 0) { red[wv*2] = s; red[wv*2+1] = ss; }
    __syncthreads();
    s  = red[0] + red[2] + red[4] + red[6];
    ss = red[1] + red[3] + red[5] + red[7];
    float mu  = s * (1.0f / C_);
    float var = ss * (1.0f / C_) - mu * mu;
    float rs  = rsqrtf(var + 1e-5f);
    float4 gv = *(const float4*)(g + t * 4);
    float4 bv = *(const float4*)(b + t * 4);
    us4 o;
    o[0] = f2bf((v[0] - mu) * rs * gv.x + bv.x);
    o[1] = f2bf((v[1] - mu) * rs * gv.y + bv.y);
    o[2] = f2bf((v[2] - mu) * rs * gv.z + bv.z);
    o[3] = f2bf((v[3] - mu) * rs * gv.w + bv.w);
    *(us4*)(out + (size_t)row * C_ + t * 4) = o;
}

// ---------- 8-phase MFMA bf16 GEMM (T1 swizzle; UNIT-derived vmcnt) ----------
// Validated R22 structure. NEW (R23): fp32+residual epilogue (Wo/W2) also staged
// through wave-private LDS (4KB/wave fp32 scratch aliasing As — same legality as
// the R22 bf16 path) -> fully-coalesced float4 residual-load + store rounds,
// replacing 64 scalar 4B loads + 64 scalar 4B stores per thread.
template<int BM, int BN, int WM, int WN, int RELU, int BIAS, int RES_MODE, int OUT_BF16>
__global__ __launch_bounds__(WM * WN * 64) void mgemm8_k(
    const ushort_t* __restrict__ A, const ushort_t* __restrict__ Bw,
    const float* __restrict__ bias, const void* __restrict__ res,
    void* __restrict__ out, int M, int N, int K, int lda, int gx)
{
    constexpr int THREADS = WM * WN * 64;
    constexpr int MIa = BM / WM / 16;
    constexpr int MIb = BN / WN / 16;
    constexpr int A_INSTS = (BM * 64) / (16 * THREADS);   // gload insts per thread per A k-half
    constexpr int B_INSTS = (BN * 64) / (16 * THREADS);
    constexpr int UNIT = A_INSTS + B_INSTS;               // VMEM insts per staging unit
    __shared__ ushort_t As[4 * BM * 32];                  // 2buf x 2kh
    __shared__ ushort_t Bs[4 * BN * 32];

    int tid = threadIdx.x;
    int l = tid & 63, w = tid >> 6;
    int wm = w / WN, wn = w % WN;
    int lin = blockIdx.x;
    int nwg = gridDim.x;
    int swz = (lin & 7) * (nwg >> 3) + (lin >> 3);
    int bx = swz % gx, by = swz / gx;
    int m0 = by * BM, n0 = bx * BN;
    const int nt = K >> 6;

    auto stageA = [&](int tile, int kh) {
        ushort_t* dst = As + ((tile & 1) * 2 + kh) * (BM * 32);
#pragma unroll
        for (int inst = 0; inst < A_INSTS; ++inst) {
            int slot = inst * THREADS + tid;
            int row = slot >> 2, q = slot & 3;
            const ushort_t* src = A + (size_t)(m0 + row) * lda + tile * 64 + kh * 32
                                  + ((q ^ ((row >> 1) & 3)) * 8);
            gload16(src, dst + (inst * THREADS + w * 64) * 8);
        }
    };
    auto stageB = [&](int tile, int kh) {
        ushort_t* dst = Bs + ((tile & 1) * 2 + kh) * (BN * 32);
#pragma unroll
        for (int inst = 0; inst < B_INSTS; ++inst) {
            int slot = inst * THREADS + tid;
            int row = slot >> 2, q = slot & 3;
            const ushort_t* src = Bw + (size_t)(n0 + row) * K + tile * 64 + kh * 32
                                  + ((q ^ ((row >> 1) & 3)) * 8);
            gload16(src, dst + (inst * THREADS + w * 64) * 8);
        }
    };

    f32x4 acc[MIa][MIb];
#pragma unroll
    for (int i = 0; i < MIa; i++)
#pragma unroll
        for (int j = 0; j < MIb; j++) acc[i][j] = (f32x4){0.f, 0.f, 0.f, 0.f};

    // prologue: 3 units ahead (t0kh0, t0kh1, t1kh0)
    stageA(0, 0); stageB(0, 0);
    stageA(0, 1); stageB(0, 1);
    stageA(1, 0); stageB(1, 0);

    for (int t = 0; t < nt; ++t) {
        int buf = t & 1;
#pragma unroll
        for (int kh = 0; kh < 2; ++kh) {
            // unit for this phase was issued 3 phases ago; 2 units behind it
            if (t == nt - 1) { if (kh == 0) vm_wait<UNIT>(); else vm_wait<0>(); }
            else vm_wait<2 * UNIT>();
            __builtin_amdgcn_s_barrier();
            __builtin_amdgcn_sched_barrier(0);

            const ushort_t* Ab = As + (buf * 2 + kh) * (BM * 32);
            const ushort_t* Bb = Bs + (buf * 2 + kh) * (BN * 32);
            bf16x8 af[MIa], bf[MIb];
#pragma unroll
            for (int i = 0; i < MIa; ++i) {
                int row = wm * (BM / WM) + i * 16 + (l & 15);
                af[i] = *(const bf16x8*)(Ab + row * 32 + (((l >> 4) ^ ((row >> 1) & 3)) * 8));
            }
#pragma unroll
            for (int j = 0; j < MIb; ++j) {
                int row = wn * (BN / WN) + j * 16 + (l & 15);
                bf[j] = *(const bf16x8*)(Bb + row * 32 + (((l >> 4) ^ ((row >> 1) & 3)) * 8));
            }
            // stage schedule: ph0 -> (t+1) kh1 ; ph1 -> (t+2) kh0
            if (kh == 0) { if (t + 1 < nt) { stageA(t + 1, 1); stageB(t + 1, 1); } }
            else         { if (t + 2 < nt) { stageA(t + 2, 0); stageB(t + 2, 0); } }

            __builtin_amdgcn_s_setprio(1);
#pragma unroll
            for (int i = 0; i < MIa; ++i)
#pragma unroll
                for (int j = 0; j < MIb; ++j)
                    acc[i][j] = __builtin_amdgcn_mfma_f32_16x16x32_bf16(af[i], bf[j], acc[i][j], 0, 0, 0);
            __builtin_amdgcn_s_setprio(0);
            __builtin_amdgcn_sched_barrier(0);
            __builtin_amdgcn_s_barrier();
        }
    }

    if (OUT_BF16 && RES_MODE == 0) {
        // LDS-staged vectorized epilogue (wave-private 16x64 bf16 scratch in As)
        ushort_t* scratch = As + w * 1024;          // 2KB/wave
#pragma unroll
        for (int i = 0; i < MIa; i++) {
#pragma unroll
            for (int j = 0; j < MIb; j++) {
                int colo = wn * 64 + j * 16 + (l & 15);       // block-local col
                float bval = BIAS ? bias[n0 + colo] : 0.f;
#pragma unroll
                for (int r = 0; r < 4; r++) {
                    float v = acc[i][j][r] + bval;
                    if (RELU) v = fmaxf(v, 0.f);
                    scratch[(((l >> 4) << 2) + r) * 64 + j * 16 + (l & 15)] = f2bf(v);
                }
            }
            // in-order DS per wave: reads below see the writes above
#pragma unroll
            for (int rr = 0; rr < 2; rr++) {
                int lrow = rr * 8 + (l >> 3);
                us8 vv = *(const us8*)(scratch + lrow * 64 + (l & 7) * 8);
                int grow = m0 + wm * (BM / WM) + i * 16 + lrow;
                *(us8*)((ushort_t*)out + (size_t)grow * N + n0 + wn * 64 + (l & 7) * 8) = vv;
            }
        }
    } else if (!OUT_BF16 && RES_MODE == 1) {
        // fp32 LDS-staged epilogue with coalesced float4 residual+store (Wo/W2)
        float* scratch = (float*)As + w * 1024;     // 4KB/wave (8 waves = 32KB = As)
#pragma unroll
        for (int i = 0; i < MIa; i++) {
#pragma unroll
            for (int j = 0; j < MIb; j++) {
                int colo = wn * 64 + j * 16 + (l & 15);
                float bval = BIAS ? bias[n0 + colo] : 0.f;
#pragma unroll
                for (int r = 0; r < 4; r++) {
                    float v = acc[i][j][r] + bval;
                    if (RELU) v = fmaxf(v, 0.f);
                    scratch[(((l >> 4) << 2) + r) * 64 + j * 16 + (l & 15)] = v;
                }
            }
            // 4 rounds: lanes 0-15 cover one full 256B row -> coalesced float4
#pragma unroll
            for (int rr = 0; rr < 4; rr++) {
                int lrow = rr * 4 + (l >> 4);
                f32x4 v4 = *(const f32x4*)(scratch + lrow * 64 + (l & 15) * 4);
                int grow = m0 + wm * (BM / WM) + i * 16 + lrow;
                size_t base = (size_t)grow * N + n0 + wn * 64 + (l & 15) * 4;
                f32x4 r4 = *(const f32x4*)((const float*)res + base);
                v4 += r4;
                *(f32x4*)((float*)out + base) = v4;
            }
        }
    } else {
        int colb = n0 + wn * (BN / WN) + (l & 15);
        int rowb = m0 + wm * (BM / WM) + ((l >> 4) << 2);
#pragma unroll
        for (int j = 0; j < MIb; j++) {
            int col = colb + j * 16;
            float bval = BIAS ? bias[col] : 0.f;
#pragma unroll
            for (int i = 0; i < MIa; i++) {
#pragma unroll
                for (int r = 0; r < 4; r++) {
                    int row = rowb + i * 16 + r;
                    float v = acc[i][j][r] + bval;
                    if (RELU) v = fmaxf(v, 0.f);
                    size_t idx = (size_t)row * N + col;
                    if (RES_MODE == 1) v += ((const float*)res)[idx];
                    else if (RES_MODE == 2) v += bf2f(((const ushort_t*)res)[idx]);
                    if (OUT_BF16) ((ushort_t*)out)[idx] = f2bf(v);
                    else          ((float*)out)[idx]    = v;
                }
            }
        }
    }
}

// ---------- MFMA flash attention, v8 (best measured: 82 us) ----------
// QK-early pipeline: S(kt+1) MFMA overlaps softmax(kt) VALU; K 3-buf staged 2
// ahead, V 2-buf; Qs/Ps union (QPs); __expf (v_exp_f32); diag-specialized mask.
__global__ __launch_bounds__(256) void fattn_k(
    ushort_t* __restrict__ QKV, const ushort_t* __restrict__ Vt)
{
    __shared__ ushort_t QPs[64 * 64];     // Q staging (prologue) / P tile (loop)
    __shared__ ushort_t Ks[3][64 * 64];
    __shared__ ushort_t Vs[2][64 * 64];
    int lin = blockIdx.x;
    int nwg = gridDim.x;                       // 1024, %8 == 0
    int bid = (lin & 7) * (nwg >> 3) + (lin >> 3);   // bijective XCD remap
    int pr = bid & 15;
    int bh = bid >> 4;
    int b  = bh >> 4;
    int h  = bh & 15;
    int tid = threadIdx.x;
    int lid = tid & 63, w = tid >> 6;

    int srow = w * 16 + (lid >> 3);
    int sseg0 = (lid & 7) ^ (srow & 7);
    int sseg1 = (lid & 7) ^ ((srow + 8) & 7);
    const ushort_t* Kg = QKV + (size_t)(b * T_) * N3_ + C_ + h * HS_;
    const ushort_t* Vg = Vt + (size_t)(b * H_ + h) * HS_ * T_;

    int mrow = w * 16 + (lid & 15);
    int fseg = lid >> 4;
    int qlocb = w * 16 + ((lid >> 4) << 2);

    const __bf16 oneb = (__bf16)1.0f;
    bf16x8 ones = {oneb, oneb, oneb, oneb, oneb, oneb, oneb, oneb};

    auto stageK = [&](int kt) {
        ushort_t* d = Ks[kt % 3];
        gload16(Kg + (size_t)(kt * 64 + srow) * N3_ + sseg0 * 8,     d + w * 1024);
        gload16(Kg + (size_t)(kt * 64 + srow + 8) * N3_ + sseg1 * 8, d + w * 1024 + 512);
    };
    auto stageV = [&](int kt) {
        ushort_t* d = Vs[kt & 1];
        gload16(Vg + (size_t)srow * T_ + kt * 64 + sseg0 * 8,       d + w * 1024);
        gload16(Vg + (size_t)(srow + 8) * T_ + kt * 64 + sseg1 * 8, d + w * 1024 + 512);
    };

    for (int half = 0; half < 2; ++half) {
        int qt = half ? (31 - pr) : pr;
        const ushort_t* Qg = QKV + (size_t)(b * T_ + qt * 64) * N3_ + h * HS_;

        // prologue: stage Q, K0, V0, K1 (all dests wave-private rows)
        gload16(Qg + (size_t)srow * N3_ + sseg0 * 8,       QPs + w * 1024);
        gload16(Qg + (size_t)(srow + 8) * N3_ + sseg1 * 8, QPs + w * 1024 + 512);
        stageK(0);
        stageV(0);
        if (qt >= 1) stageK(1);
        __syncthreads();   // drains all staging + syncs waves

        // Q fragments loop-invariant -> registers; QPs becomes the P tile.
        bf16x8 aqr[2];
        aqr[0] = *(const bf16x8*)(QPs + mrow * 64 + (((0 + fseg) ^ (mrow & 7)) * 8));
        aqr[1] = *(const bf16x8*)(QPs + mrow * 64 + (((4 + fseg) ^ (mrow & 7)) * 8));

        f32x4 accO[4];
#pragma unroll
        for (int j = 0; j < 4; j++) accO[j] = (f32x4){0.f, 0.f, 0.f, 0.f};
        f32x4 accL = (f32x4){0.f, 0.f, 0.f, 0.f};

        auto qk_into = [&](const ushort_t* Kc, f32x4* s) {
#pragma unroll
            for (int j = 0; j < 4; j++) s[j] = (f32x4){0.f, 0.f, 0.f, 0.f};
            __builtin_amdgcn_s_setprio(1);
#pragma unroll
            for (int ks = 0; ks < 2; ks++) {
#pragma unroll
                for (int j = 0; j < 4; j++) {
                    int krow = j * 16 + (lid & 15);
                    bf16x8 bk = *(const bf16x8*)(Kc + krow * 64 + (((ks * 4 + fseg) ^ (krow & 7)) * 8));
                    s[j] = __builtin_amdgcn_mfma_f32_16x16x32_bf16(aqr[ks], bk, s[j], 0, 0, 0);
                }
            }
            __builtin_amdgcn_s_setprio(0);
        };
        auto smax_pv = [&](auto diag_c, f32x4* s, const ushort_t* Vc) {
            constexpr bool DIAG = decltype(diag_c)::value;
#pragma unroll
            for (int r = 0; r < 4; r++) {
                int qloc = qlocb + r;
#pragma unroll
                for (int j = 0; j < 4; j++) {
                    int col = j * 16 + (lid & 15);
                    float p = __expf(s[j][r] * 0.125f);
                    if (DIAG) { if (col > qloc) p = 0.f; }
                    QPs[qloc * 64 + (((col >> 3) ^ (qloc & 7)) * 8) + (col & 7)] = f2bf(p);
                }
            }
            __builtin_amdgcn_s_setprio(1);
#pragma unroll
            for (int ks = 0; ks < 2; ks++) {
                bf16x8 ap = *(const bf16x8*)(QPs + mrow * 64 + (((ks * 4 + fseg) ^ (mrow & 7)) * 8));
                accL = __builtin_amdgcn_mfma_f32_16x16x32_bf16(ap, ones, accL, 0, 0, 0);
#pragma unroll
                for (int j = 0; j < 4; j++) {
                    int drow = j * 16 + (lid & 15);
                    bf16x8 bv = *(const bf16x8*)(Vc + drow * 64 + (((ks * 4 + fseg) ^ (drow & 7)) * 8));
                    accO[j] = __builtin_amdgcn_mfma_f32_16x16x32_bf16(ap, bv, accO[j], 0, 0, 0);
                }
            }
            __builtin_amdgcn_s_setprio(0);
        };

        // sP = S(0)
        f32x4 sP[4], sN[4];
        qk_into(Ks[0], sP);

        for (int kt = 0; kt < qt; ++kt) {
            // early-issue staging: K two ahead, V one ahead
            if (kt + 2 <= qt) stageK(kt + 2);
            stageV(kt + 1);
            // QK(kt+1) — independent of softmax(kt); overlaps its VALU work
            qk_into(Ks[(kt + 1) % 3], sN);
            // softmax(kt) (never diag in-loop) + PV(kt)
            smax_pv(bool_c<false>{}, sP, Vs[kt & 1]);
            __syncthreads();   // staged loads drained; all waves done with K/V[cur]
#pragma unroll
            for (int j = 0; j < 4; j++) sP[j] = sN[j];
        }
        // final tile kt = qt: diag mask
        smax_pv(bool_c<true>{}, sP, Vs[qt & 1]);
        __syncthreads();   // all reads done before next half restages

#pragma unroll
        for (int r = 0; r < 4; r++) {
            float inv = 1.0f / accL[r];
            int qabs = qt * 64 + qlocb + r;
            ushort_t* orow = QKV + (size_t)(b * T_ + qabs) * N3_ + h * HS_;
#pragma unroll
            for (int j = 0; j < 4; j++)
                orow[j * 16 + (lid & 15)] = f2bf(accO[j][r] * inv);
        }
    }
}

extern "C" void kernel_launch(void* const* d_in, const int* in_sizes, int n_in,
                              void* d_out, int out_size, void* d_ws, size_t ws_size,
                              hipStream_t stream)
{
    const float* x   = (const float*)d_in[0];
    const float* g1  = (const float*)d_in[1];
    const float* be1 = (const float*)d_in[2];
    const float* Wq  = (const float*)d_in[3];
    const float* Wk  = (const float*)d_in[4];
    const float* Wv  = (const float*)d_in[5];
    const float* Wo  = (const float*)d_in[6];
    const float* bo  = (const float*)d_in[7];
    const float* g2  = (const float*)d_in[8];
    const float* be2 = (const float*)d_in[9];
    const float* W1  = (const float*)d_in[10];
    const float* b1  = (const float*)d_in[11];
    const float* W2  = (const float*)d_in[12];
    const float* b2  = (const float*)d_in[13];

    // ws (bytes): hB/Vt 16M | big (qkv 48M / ff1 64M, time-disjoint) 64M | WtB 6M |
    // WoB 2M | W1B 8M | W2B 8M = 104 MiB. x2 lives as fp32 in d_out.
    const size_t UB2 = (size_t)BT_ * C_ * 2;
    const size_t WT_B = (size_t)N3_ * C_ * 2;
    const size_t WO_B = (size_t)C_ * C_ * 2;
    const size_t W1_B = (size_t)C_ * F_ * 2;
    const size_t REQ = 5 * UB2 + WT_B + WO_B + 2 * W1_B;
    if (ws_size < REQ) {
        hipMemsetAsync(d_out, 0, (size_t)out_size * 4, stream);
        return;
    }
    char* wsb = (char*)d_ws;
    ushort_t* hB   = (ushort_t*)(wsb);                 // LN out; Vt during attn; h2 after
    ushort_t* qkvB = (ushort_t*)(wsb + UB2);           // big region
    ushort_t* ff1B = qkvB;
    ushort_t* WtB  = (ushort_t*)(wsb + 5 * UB2);
    ushort_t* WoB  = (ushort_t*)(wsb + 5 * UB2 + WT_B);
    ushort_t* W1B  = (ushort_t*)(wsb + 5 * UB2 + WT_B + WO_B);
    ushort_t* W2B  = (ushort_t*)(wsb + 5 * UB2 + WT_B + WO_B + W1_B);
    float* x2F = (float*)d_out;

    // weight prep
    repack_qkv_k<<<3 * 16 * 16, 256, 0, stream>>>(Wq, Wk, Wv, WtB);
    transpose_k<<<dim3(C_ / 64, C_ / 64), 256, 0, stream>>>(Wo, WoB, C_, C_);
    transpose_k<<<dim3(F_ / 64, C_ / 64), 256, 0, stream>>>(W1, W1B, C_, F_);
    transpose_k<<<dim3(C_ / 64, F_ / 64), 256, 0, stream>>>(W2, W2B, F_, C_);

    // h = LN1(x)
    ln_k<0><<<BT_, 256, 0, stream>>>(x, g1, be1, hB);
    // qkv = h @ Wt^T    [8192 x 3072], 128x256 tiles -> grid 768
    mgemm8_k<128,256,2,4,0,0,0,1><<<(N3_ / 256) * (BT_ / 128), 512, 0, stream>>>(
        hB, WtB, nullptr, nullptr, qkvB, BT_, N3_, C_, C_, N3_ / 256);
    // Vt = transpose(V cols) into hB (LN1 output dead)
    transv_k<<<B_ * H_ * (T_ / 64), 256, 0, stream>>>(qkvB, hB);
    // attention (paired q-tiles, XCD-swizzled; O -> Q slots of qkv)
    fattn_k<<<B_ * H_ * 16, 256, 0, stream>>>(qkvB, hB);
    // x2 = x + O @ Wo + bo -> fp32 in d_out   [8192 x 1024], 128x256, grid 256
    mgemm8_k<128,256,2,4,0,1,1,0><<<(C_ / 256) * (BT_ / 128), 512, 0, stream>>>(
        qkvB, WoB, bo, x, x2F, BT_, C_, C_, N3_, C_ / 256);
    // h2 = LN2(x2)
    ln_k<0><<<BT_, 256, 0, stream>>>(x2F, g2, be2, hB);
    // ff1 = relu(h2 @ W1 + b1)   [8192 x 4096], 256x256 tiles, grid 512
    mgemm8_k<256,256,2,4,1,1,0,1><<<(F_ / 256) * (BT_ / 256), 512, 0, stream>>>(
        hB, W1B, b1, nullptr, ff1B, BT_, F_, C_, C_, F_ / 256);
    // out = x2 + ff1 @ W2 + b2   [8192 x 1024], 128x256, grid 256
    mgemm8_k<128,256,2,4,0,1,1,0><<<(C_ / 256) * (BT_ / 128), 512, 0, stream>>>(
        ff1B, W2B, b2, x2F, (float*)d_out, BT_, C_, F_, F_, C_ / 256);
}

// Round 24
// 340.611 us; speedup vs baseline: 1.0896x; 1.0239x over previous
//
#include <hip/hip_runtime.h>
#include <math.h>

#define B_  4
#define T_  2048
#define C_  1024
#define H_  16
#define HS_ 64
#define BT_ (B_*T_)
#define F_  (4*C_)
#define N3_ (3*C_)

typedef unsigned short ushort_t;
typedef __attribute__((ext_vector_type(4))) unsigned short us4;
typedef __attribute__((ext_vector_type(8))) unsigned short us8;
typedef __attribute__((ext_vector_type(4))) float f32x4;
typedef __attribute__((ext_vector_type(8))) __bf16 bf16x8;

template<bool V> struct bool_c { static constexpr bool value = V; };

__device__ __forceinline__ float bf2f(ushort_t u) {
    union { unsigned int i; float f; } c; c.i = ((unsigned int)u) << 16; return c.f;
}
// Native bf16 convert (RNE) — single v_cvt instruction on gfx950.
__device__ __forceinline__ ushort_t f2bf(float f) {
    union { __bf16 b; ushort_t u; } c; c.b = (__bf16)f; return c.u;
}

// global_load_lds: LDS dest = wave-uniform base + lane*16 (HW); global src per-lane.
#define GLB_(p) ((const __attribute__((address_space(1))) unsigned int*)(size_t)(p))
#define LDS_(p) ((__attribute__((address_space(3))) unsigned int*)(unsigned int)(size_t)(p))
__device__ __forceinline__ void gload16(const void* g, void* l) {
    __builtin_amdgcn_global_load_lds(GLB_(g), LDS_(l), 16, 0, 0);
}

template<int N> __device__ __forceinline__ void vm_wait() {
    if constexpr (N >= 8)      asm volatile("s_waitcnt vmcnt(8)" ::: "memory");
    else if constexpr (N == 6) asm volatile("s_waitcnt vmcnt(6)" ::: "memory");
    else if constexpr (N == 4) asm volatile("s_waitcnt vmcnt(4)" ::: "memory");
    else if constexpr (N == 3) asm volatile("s_waitcnt vmcnt(3)" ::: "memory");
    else if constexpr (N == 2) asm volatile("s_waitcnt vmcnt(2)" ::: "memory");
    else                       asm volatile("s_waitcnt vmcnt(0)" ::: "memory");
}

// ---------- device bodies for the fused prologue (verbatim logic from R23) ----------
// repack: Wq/Wk/Wv [H][C][hs] f32 -> WtB [3C][C] bf16 (row n = p*C + h*64 + s)
__device__ __forceinline__ void repack_body(
    float (*tile)[65], const float* __restrict__ Wq, const float* __restrict__ Wk,
    const float* __restrict__ Wv, ushort_t* __restrict__ WtB, int bid)
{
    int p  = bid >> 8;
    int h  = (bid >> 4) & 15;
    int c0 = (bid & 15) * 64;
    const float* W = (p == 0) ? Wq : ((p == 1) ? Wk : Wv);
    int t = threadIdx.x;
    int cl = t >> 2, seg = (t & 3) * 16;
    const float* src = W + ((size_t)h * C_ + c0 + cl) * HS_ + seg;
#pragma unroll
    for (int i = 0; i < 4; i++) {
        float4 v = *(const float4*)(src + i * 4);
        tile[cl][seg + i*4 + 0] = v.x; tile[cl][seg + i*4 + 1] = v.y;
        tile[cl][seg + i*4 + 2] = v.z; tile[cl][seg + i*4 + 3] = v.w;
    }
    __syncthreads();
    int sl = t >> 2;
    int n = p * C_ + h * HS_ + sl;
    ushort_t* dst = WtB + (size_t)n * C_ + c0 + seg;
    us8 o0, o1;
#pragma unroll
    for (int e = 0; e < 8; e++) { o0[e] = f2bf(tile[seg + e][sl]); o1[e] = f2bf(tile[seg + 8 + e][sl]); }
    *(us8*)dst = o0; *(us8*)(dst + 8) = o1;
}

// transpose: in f32 [K][N] -> out bf16 [N][K]
__device__ __forceinline__ void transpose_body(
    float (*tile)[65], const float* __restrict__ in, ushort_t* __restrict__ out,
    int K, int N, int bx, int by)
{
    int n0 = bx * 64, k0 = by * 64;
    int t = threadIdx.x;
    int kl = t >> 2, seg = (t & 3) * 16;
    const float* src = in + (size_t)(k0 + kl) * N + n0 + seg;
#pragma unroll
    for (int i = 0; i < 4; i++) {
        float4 v = *(const float4*)(src + i * 4);
        tile[kl][seg + i*4 + 0] = v.x; tile[kl][seg + i*4 + 1] = v.y;
        tile[kl][seg + i*4 + 2] = v.z; tile[kl][seg + i*4 + 3] = v.w;
    }
    __syncthreads();
    int nl = t >> 2;
    ushort_t* dst = out + (size_t)(n0 + nl) * K + k0 + seg;
    us8 o0, o1;
#pragma unroll
    for (int e = 0; e < 8; e++) { o0[e] = f2bf(tile[seg + e][nl]); o1[e] = f2bf(tile[seg + 8 + e][nl]); }
    *(us8*)dst = o0; *(us8*)(dst + 8) = o1;
}

// layernorm (fp32 in, bf16 out)
__device__ __forceinline__ void ln_body(
    float* red, const float* __restrict__ xr0, const float* __restrict__ g,
    const float* __restrict__ b, ushort_t* __restrict__ out, int row)
{
    int t = threadIdx.x;
    const float* xr = xr0 + (size_t)row * C_;
    float4 f = *(const float4*)(xr + t * 4);
    float v[4] = {f.x, f.y, f.z, f.w};
    float s  = v[0] + v[1] + v[2] + v[3];
    float ss = v[0]*v[0] + v[1]*v[1] + v[2]*v[2] + v[3]*v[3];
#pragma unroll
    for (int off = 32; off > 0; off >>= 1) {
        s  += __shfl_xor(s, off);
        ss += __shfl_xor(ss, off);
    }
    int wv = t >> 6;
    if ((t & 63) == 0) { red[wv*2] = s; red[wv*2+1] = ss; }
    __syncthreads();
    s  = red[0] + red[2] + red[4] + red[6];
    ss = red[1] + red[3] + red[5] + red[7];
    float mu  = s * (1.0f / C_);
    float var = ss * (1.0f / C_) - mu * mu;
    float rs  = rsqrtf(var + 1e-5f);
    float4 gv = *(const float4*)(g + t * 4);
    float4 bv = *(const float4*)(b + t * 4);
    us4 o;
    o[0] = f2bf((v[0] - mu) * rs * gv.x + bv.x);
    o[1] = f2bf((v[1] - mu) * rs * gv.y + bv.y);
    o[2] = f2bf((v[2] - mu) * rs * gv.z + bv.z);
    o[3] = f2bf((v[3] - mu) * rs * gv.w + bv.w);
    *(us4*)(out + (size_t)row * C_ + t * 4) = o;
}

// ---------- fused prologue: LN1 (8192) + repack (768) + T(Wo) 256 + T(W1) 1024 + T(W2) 1024 ----------
__global__ __launch_bounds__(256) void prep_ln1_k(
    const float* __restrict__ x, const float* __restrict__ g1, const float* __restrict__ be1,
    ushort_t* __restrict__ hB,
    const float* __restrict__ Wq, const float* __restrict__ Wk, const float* __restrict__ Wv,
    ushort_t* __restrict__ WtB,
    const float* __restrict__ Wo, ushort_t* __restrict__ WoB,
    const float* __restrict__ W1, ushort_t* __restrict__ W1B,
    const float* __restrict__ W2, ushort_t* __restrict__ W2B)
{
    __shared__ float tile[64][65];
    __shared__ float red[8];
    int bid = blockIdx.x;
    if (bid < BT_) { ln_body(red, x, g1, be1, hB, bid); return; }
    bid -= BT_;
    if (bid < 768) { repack_body(tile, Wq, Wk, Wv, WtB, bid); return; }
    bid -= 768;
    if (bid < 256) { transpose_body(tile, Wo, WoB, C_, C_, bid & 15, bid >> 4); return; }
    bid -= 256;
    if (bid < 1024) { transpose_body(tile, W1, W1B, C_, F_, bid & 63, bid >> 6); return; }
    bid -= 1024;
    transpose_body(tile, W2, W2B, F_, C_, bid & 15, bid >> 4);
}

// ---------- standalone LN (fp32 in, bf16 out) for LN2 ----------
__global__ __launch_bounds__(256) void ln_k(
    const float* __restrict__ xv, const float* __restrict__ g,
    const float* __restrict__ b, ushort_t* __restrict__ out)
{
    __shared__ float red[8];
    ln_body(red, xv, g, b, out, blockIdx.x);
}

// ---------- prep: V cols of qkv [B*T][3C] -> Vt [B][H][64][T] bf16 ----------
__global__ __launch_bounds__(256) void transv_k(
    const ushort_t* __restrict__ QKV, ushort_t* __restrict__ Vt)
{
    __shared__ ushort_t tl[64][72];
    int bid = blockIdx.x;
    int tt = bid & 31;           // T/64 tiles
    int bh = bid >> 5;
    int b  = bh >> 4;
    int h  = bh & 15;
    int t = threadIdx.x;
    int r = t >> 2, sg = (t & 3) * 16;
    const ushort_t* src = QKV + (size_t)(b * T_ + tt * 64 + r) * N3_ + 2 * C_ + h * HS_ + sg;
    us8 a0 = *(const us8*)src;
    us8 a1 = *(const us8*)(src + 8);
#pragma unroll
    for (int e = 0; e < 8; e++) { tl[r][sg + e] = a0[e]; tl[r][sg + 8 + e] = a1[e]; }
    __syncthreads();
    ushort_t* dst = Vt + ((size_t)(b * H_ + h) * HS_ + r) * T_ + tt * 64 + sg;
    us8 o0, o1;
#pragma unroll
    for (int e = 0; e < 8; e++) { o0[e] = tl[sg + e][r]; o1[e] = tl[sg + 8 + e][r]; }
    *(us8*)dst = o0; *(us8*)(dst + 8) = o1;
}

// ---------- 8-phase MFMA bf16 GEMM (validated R23: T1 swizzle, UNIT vmcnt,
// LDS-staged coalesced epilogues for bf16 and fp32+residual outputs) ----------
template<int BM, int BN, int WM, int WN, int RELU, int BIAS, int RES_MODE, int OUT_BF16>
__global__ __launch_bounds__(WM * WN * 64) void mgemm8_k(
    const ushort_t* __restrict__ A, const ushort_t* __restrict__ Bw,
    const float* __restrict__ bias, const void* __restrict__ res,
    void* __restrict__ out, int M, int N, int K, int lda, int gx)
{
    constexpr int THREADS = WM * WN * 64;
    constexpr int MIa = BM / WM / 16;
    constexpr int MIb = BN / WN / 16;
    constexpr int A_INSTS = (BM * 64) / (16 * THREADS);   // gload insts per thread per A k-half
    constexpr int B_INSTS = (BN * 64) / (16 * THREADS);
    constexpr int UNIT = A_INSTS + B_INSTS;               // VMEM insts per staging unit
    __shared__ ushort_t As[4 * BM * 32];                  // 2buf x 2kh
    __shared__ ushort_t Bs[4 * BN * 32];

    int tid = threadIdx.x;
    int l = tid & 63, w = tid >> 6;
    int wm = w / WN, wn = w % WN;
    int lin = blockIdx.x;
    int nwg = gridDim.x;
    int swz = (lin & 7) * (nwg >> 3) + (lin >> 3);
    int bx = swz % gx, by = swz / gx;
    int m0 = by * BM, n0 = bx * BN;
    const int nt = K >> 6;

    auto stageA = [&](int tile, int kh) {
        ushort_t* dst = As + ((tile & 1) * 2 + kh) * (BM * 32);
#pragma unroll
        for (int inst = 0; inst < A_INSTS; ++inst) {
            int slot = inst * THREADS + tid;
            int row = slot >> 2, q = slot & 3;
            const ushort_t* src = A + (size_t)(m0 + row) * lda + tile * 64 + kh * 32
                                  + ((q ^ ((row >> 1) & 3)) * 8);
            gload16(src, dst + (inst * THREADS + w * 64) * 8);
        }
    };
    auto stageB = [&](int tile, int kh) {
        ushort_t* dst = Bs + ((tile & 1) * 2 + kh) * (BN * 32);
#pragma unroll
        for (int inst = 0; inst < B_INSTS; ++inst) {
            int slot = inst * THREADS + tid;
            int row = slot >> 2, q = slot & 3;
            const ushort_t* src = Bw + (size_t)(n0 + row) * K + tile * 64 + kh * 32
                                  + ((q ^ ((row >> 1) & 3)) * 8);
            gload16(src, dst + (inst * THREADS + w * 64) * 8);
        }
    };

    f32x4 acc[MIa][MIb];
#pragma unroll
    for (int i = 0; i < MIa; i++)
#pragma unroll
        for (int j = 0; j < MIb; j++) acc[i][j] = (f32x4){0.f, 0.f, 0.f, 0.f};

    // prologue: 3 units ahead (t0kh0, t0kh1, t1kh0)
    stageA(0, 0); stageB(0, 0);
    stageA(0, 1); stageB(0, 1);
    stageA(1, 0); stageB(1, 0);

    for (int t = 0; t < nt; ++t) {
        int buf = t & 1;
#pragma unroll
        for (int kh = 0; kh < 2; ++kh) {
            // unit for this phase was issued 3 phases ago; 2 units behind it
            if (t == nt - 1) { if (kh == 0) vm_wait<UNIT>(); else vm_wait<0>(); }
            else vm_wait<2 * UNIT>();
            __builtin_amdgcn_s_barrier();
            __builtin_amdgcn_sched_barrier(0);

            const ushort_t* Ab = As + (buf * 2 + kh) * (BM * 32);
            const ushort_t* Bb = Bs + (buf * 2 + kh) * (BN * 32);
            bf16x8 af[MIa], bf[MIb];
#pragma unroll
            for (int i = 0; i < MIa; ++i) {
                int row = wm * (BM / WM) + i * 16 + (l & 15);
                af[i] = *(const bf16x8*)(Ab + row * 32 + (((l >> 4) ^ ((row >> 1) & 3)) * 8));
            }
#pragma unroll
            for (int j = 0; j < MIb; ++j) {
                int row = wn * (BN / WN) + j * 16 + (l & 15);
                bf[j] = *(const bf16x8*)(Bb + row * 32 + (((l >> 4) ^ ((row >> 1) & 3)) * 8));
            }
            // stage schedule: ph0 -> (t+1) kh1 ; ph1 -> (t+2) kh0
            if (kh == 0) { if (t + 1 < nt) { stageA(t + 1, 1); stageB(t + 1, 1); } }
            else         { if (t + 2 < nt) { stageA(t + 2, 0); stageB(t + 2, 0); } }

            __builtin_amdgcn_s_setprio(1);
#pragma unroll
            for (int i = 0; i < MIa; ++i)
#pragma unroll
                for (int j = 0; j < MIb; ++j)
                    acc[i][j] = __builtin_amdgcn_mfma_f32_16x16x32_bf16(af[i], bf[j], acc[i][j], 0, 0, 0);
            __builtin_amdgcn_s_setprio(0);
            __builtin_amdgcn_sched_barrier(0);
            __builtin_amdgcn_s_barrier();
        }
    }

    if (OUT_BF16 && RES_MODE == 0) {
        // LDS-staged vectorized epilogue (wave-private 16x64 bf16 scratch in As)
        ushort_t* scratch = As + w * 1024;          // 2KB/wave
#pragma unroll
        for (int i = 0; i < MIa; i++) {
#pragma unroll
            for (int j = 0; j < MIb; j++) {
                int colo = wn * 64 + j * 16 + (l & 15);       // block-local col
                float bval = BIAS ? bias[n0 + colo] : 0.f;
#pragma unroll
                for (int r = 0; r < 4; r++) {
                    float v = acc[i][j][r] + bval;
                    if (RELU) v = fmaxf(v, 0.f);
                    scratch[(((l >> 4) << 2) + r) * 64 + j * 16 + (l & 15)] = f2bf(v);
                }
            }
            // in-order DS per wave: reads below see the writes above
#pragma unroll
            for (int rr = 0; rr < 2; rr++) {
                int lrow = rr * 8 + (l >> 3);
                us8 vv = *(const us8*)(scratch + lrow * 64 + (l & 7) * 8);
                int grow = m0 + wm * (BM / WM) + i * 16 + lrow;
                *(us8*)((ushort_t*)out + (size_t)grow * N + n0 + wn * 64 + (l & 7) * 8) = vv;
            }
        }
    } else if (!OUT_BF16 && RES_MODE == 1) {
        // fp32 LDS-staged epilogue with coalesced float4 residual+store (Wo/W2)
        float* scratch = (float*)As + w * 1024;     // 4KB/wave (8 waves = 32KB = As)
#pragma unroll
        for (int i = 0; i < MIa; i++) {
#pragma unroll
            for (int j = 0; j < MIb; j++) {
                int colo = wn * 64 + j * 16 + (l & 15);
                float bval = BIAS ? bias[n0 + colo] : 0.f;
#pragma unroll
                for (int r = 0; r < 4; r++) {
                    float v = acc[i][j][r] + bval;
                    if (RELU) v = fmaxf(v, 0.f);
                    scratch[(((l >> 4) << 2) + r) * 64 + j * 16 + (l & 15)] = v;
                }
            }
            // 4 rounds: lanes 0-15 cover one full 256B row -> coalesced float4
#pragma unroll
            for (int rr = 0; rr < 4; rr++) {
                int lrow = rr * 4 + (l >> 4);
                f32x4 v4 = *(const f32x4*)(scratch + lrow * 64 + (l & 15) * 4);
                int grow = m0 + wm * (BM / WM) + i * 16 + lrow;
                size_t base = (size_t)grow * N + n0 + wn * 64 + (l & 15) * 4;
                f32x4 r4 = *(const f32x4*)((const float*)res + base);
                v4 += r4;
                *(f32x4*)((float*)out + base) = v4;
            }
        }
    } else {
        int colb = n0 + wn * (BN / WN) + (l & 15);
        int rowb = m0 + wm * (BM / WM) + ((l >> 4) << 2);
#pragma unroll
        for (int j = 0; j < MIb; j++) {
            int col = colb + j * 16;
            float bval = BIAS ? bias[col] : 0.f;
#pragma unroll
            for (int i = 0; i < MIa; i++) {
#pragma unroll
                for (int r = 0; r < 4; r++) {
                    int row = rowb + i * 16 + r;
                    float v = acc[i][j][r] + bval;
                    if (RELU) v = fmaxf(v, 0.f);
                    size_t idx = (size_t)row * N + col;
                    if (RES_MODE == 1) v += ((const float*)res)[idx];
                    else if (RES_MODE == 2) v += bf2f(((const ushort_t*)res)[idx]);
                    if (OUT_BF16) ((ushort_t*)out)[idx] = f2bf(v);
                    else          ((float*)out)[idx]    = v;
                }
            }
        }
    }
}

// ---------- MFMA flash attention, v8 (best measured: 82 us) ----------
// QK-early pipeline: S(kt+1) MFMA overlaps softmax(kt) VALU; K 3-buf staged 2
// ahead, V 2-buf; Qs/Ps union (QPs); __expf (v_exp_f32); diag-specialized mask.
__global__ __launch_bounds__(256) void fattn_k(
    ushort_t* __restrict__ QKV, const ushort_t* __restrict__ Vt)
{
    __shared__ ushort_t QPs[64 * 64];     // Q staging (prologue) / P tile (loop)
    __shared__ ushort_t Ks[3][64 * 64];
    __shared__ ushort_t Vs[2][64 * 64];
    int lin = blockIdx.x;
    int nwg = gridDim.x;                       // 1024, %8 == 0
    int bid = (lin & 7) * (nwg >> 3) + (lin >> 3);   // bijective XCD remap
    int pr = bid & 15;
    int bh = bid >> 4;
    int b  = bh >> 4;
    int h  = bh & 15;
    int tid = threadIdx.x;
    int lid = tid & 63, w = tid >> 6;

    int srow = w * 16 + (lid >> 3);
    int sseg0 = (lid & 7) ^ (srow & 7);
    int sseg1 = (lid & 7) ^ ((srow + 8) & 7);
    const ushort_t* Kg = QKV + (size_t)(b * T_) * N3_ + C_ + h * HS_;
    const ushort_t* Vg = Vt + (size_t)(b * H_ + h) * HS_ * T_;

    int mrow = w * 16 + (lid & 15);
    int fseg = lid >> 4;
    int qlocb = w * 16 + ((lid >> 4) << 2);

    const __bf16 oneb = (__bf16)1.0f;
    bf16x8 ones = {oneb, oneb, oneb, oneb, oneb, oneb, oneb, oneb};

    auto stageK = [&](int kt) {
        ushort_t* d = Ks[kt % 3];
        gload16(Kg + (size_t)(kt * 64 + srow) * N3_ + sseg0 * 8,     d + w * 1024);
        gload16(Kg + (size_t)(kt * 64 + srow + 8) * N3_ + sseg1 * 8, d + w * 1024 + 512);
    };
    auto stageV = [&](int kt) {
        ushort_t* d = Vs[kt & 1];
        gload16(Vg + (size_t)srow * T_ + kt * 64 + sseg0 * 8,       d + w * 1024);
        gload16(Vg + (size_t)(srow + 8) * T_ + kt * 64 + sseg1 * 8, d + w * 1024 + 512);
    };

    for (int half = 0; half < 2; ++half) {
        int qt = half ? (31 - pr) : pr;
        const ushort_t* Qg = QKV + (size_t)(b * T_ + qt * 64) * N3_ + h * HS_;

        // prologue: stage Q, K0, V0, K1 (all dests wave-private rows)
        gload16(Qg + (size_t)srow * N3_ + sseg0 * 8,       QPs + w * 1024);
        gload16(Qg + (size_t)(srow + 8) * N3_ + sseg1 * 8, QPs + w * 1024 + 512);
        stageK(0);
        stageV(0);
        if (qt >= 1) stageK(1);
        __syncthreads();   // drains all staging + syncs waves

        // Q fragments loop-invariant -> registers; QPs becomes the P tile.
        bf16x8 aqr[2];
        aqr[0] = *(const bf16x8*)(QPs + mrow * 64 + (((0 + fseg) ^ (mrow & 7)) * 8));
        aqr[1] = *(const bf16x8*)(QPs + mrow * 64 + (((4 + fseg) ^ (mrow & 7)) * 8));

        f32x4 accO[4];
#pragma unroll
        for (int j = 0; j < 4; j++) accO[j] = (f32x4){0.f, 0.f, 0.f, 0.f};
        f32x4 accL = (f32x4){0.f, 0.f, 0.f, 0.f};

        auto qk_into = [&](const ushort_t* Kc, f32x4* s) {
#pragma unroll
            for (int j = 0; j < 4; j++) s[j] = (f32x4){0.f, 0.f, 0.f, 0.f};
            __builtin_amdgcn_s_setprio(1);
#pragma unroll
            for (int ks = 0; ks < 2; ks++) {
#pragma unroll
                for (int j = 0; j < 4; j++) {
                    int krow = j * 16 + (lid & 15);
                    bf16x8 bk = *(const bf16x8*)(Kc + krow * 64 + (((ks * 4 + fseg) ^ (krow & 7)) * 8));
                    s[j] = __builtin_amdgcn_mfma_f32_16x16x32_bf16(aqr[ks], bk, s[j], 0, 0, 0);
                }
            }
            __builtin_amdgcn_s_setprio(0);
        };
        auto smax_pv = [&](auto diag_c, f32x4* s, const ushort_t* Vc) {
            constexpr bool DIAG = decltype(diag_c)::value;
#pragma unroll
            for (int r = 0; r < 4; r++) {
                int qloc = qlocb + r;
#pragma unroll
                for (int j = 0; j < 4; j++) {
                    int col = j * 16 + (lid & 15);
                    float p = __expf(s[j][r] * 0.125f);
                    if (DIAG) { if (col > qloc) p = 0.f; }
                    QPs[qloc * 64 + (((col >> 3) ^ (qloc & 7)) * 8) + (col & 7)] = f2bf(p);
                }
            }
            __builtin_amdgcn_s_setprio(1);
#pragma unroll
            for (int ks = 0; ks < 2; ks++) {
                bf16x8 ap = *(const bf16x8*)(QPs + mrow * 64 + (((ks * 4 + fseg) ^ (mrow & 7)) * 8));
                accL = __builtin_amdgcn_mfma_f32_16x16x32_bf16(ap, ones, accL, 0, 0, 0);
#pragma unroll
                for (int j = 0; j < 4; j++) {
                    int drow = j * 16 + (lid & 15);
                    bf16x8 bv = *(const bf16x8*)(Vc + drow * 64 + (((ks * 4 + fseg) ^ (drow & 7)) * 8));
                    accO[j] = __builtin_amdgcn_mfma_f32_16x16x32_bf16(ap, bv, accO[j], 0, 0, 0);
                }
            }
            __builtin_amdgcn_s_setprio(0);
        };

        // sP = S(0)
        f32x4 sP[4], sN[4];
        qk_into(Ks[0], sP);

        for (int kt = 0; kt < qt; ++kt) {
            // early-issue staging: K two ahead, V one ahead
            if (kt + 2 <= qt) stageK(kt + 2);
            stageV(kt + 1);
            // QK(kt+1) — independent of softmax(kt); overlaps its VALU work
            qk_into(Ks[(kt + 1) % 3], sN);
            // softmax(kt) (never diag in-loop) + PV(kt)
            smax_pv(bool_c<false>{}, sP, Vs[kt & 1]);
            __syncthreads();   // staged loads drained; all waves done with K/V[cur]
#pragma unroll
            for (int j = 0; j < 4; j++) sP[j] = sN[j];
        }
        // final tile kt = qt: diag mask
        smax_pv(bool_c<true>{}, sP, Vs[qt & 1]);
        __syncthreads();   // all reads done before next half restages

#pragma unroll
        for (int r = 0; r < 4; r++) {
            float inv = 1.0f / accL[r];
            int qabs = qt * 64 + qlocb + r;
            ushort_t* orow = QKV + (size_t)(b * T_ + qabs) * N3_ + h * HS_;
#pragma unroll
            for (int j = 0; j < 4; j++)
                orow[j * 16 + (lid & 15)] = f2bf(accO[j][r] * inv);
        }
    }
}

extern "C" void kernel_launch(void* const* d_in, const int* in_sizes, int n_in,
                              void* d_out, int out_size, void* d_ws, size_t ws_size,
                              hipStream_t stream)
{
    const float* x   = (const float*)d_in[0];
    const float* g1  = (const float*)d_in[1];
    const float* be1 = (const float*)d_in[2];
    const float* Wq  = (const float*)d_in[3];
    const float* Wk  = (const float*)d_in[4];
    const float* Wv  = (const float*)d_in[5];
    const float* Wo  = (const float*)d_in[6];
    const float* bo  = (const float*)d_in[7];
    const float* g2  = (const float*)d_in[8];
    const float* be2 = (const float*)d_in[9];
    const float* W1  = (const float*)d_in[10];
    const float* b1  = (const float*)d_in[11];
    const float* W2  = (const float*)d_in[12];
    const float* b2  = (const float*)d_in[13];

    // ws (bytes): hB/Vt 16M | big (qkv 48M / ff1 64M, time-disjoint) 64M | WtB 6M |
    // WoB 2M | W1B 8M | W2B 8M = 104 MiB. x2 lives as fp32 in d_out.
    const size_t UB2 = (size_t)BT_ * C_ * 2;
    const size_t WT_B = (size_t)N3_ * C_ * 2;
    const size_t WO_B = (size_t)C_ * C_ * 2;
    const size_t W1_B = (size_t)C_ * F_ * 2;
    const size_t REQ = 5 * UB2 + WT_B + WO_B + 2 * W1_B;
    if (ws_size < REQ) {
        hipMemsetAsync(d_out, 0, (size_t)out_size * 4, stream);
        return;
    }
    char* wsb = (char*)d_ws;
    ushort_t* hB   = (ushort_t*)(wsb);                 // LN out; Vt during attn; h2 after
    ushort_t* qkvB = (ushort_t*)(wsb + UB2);           // big region
    ushort_t* ff1B = qkvB;
    ushort_t* WtB  = (ushort_t*)(wsb + 5 * UB2);
    ushort_t* WoB  = (ushort_t*)(wsb + 5 * UB2 + WT_B);
    ushort_t* W1B  = (ushort_t*)(wsb + 5 * UB2 + WT_B + WO_B);
    ushort_t* W2B  = (ushort_t*)(wsb + 5 * UB2 + WT_B + WO_B + W1_B);
    float* x2F = (float*)d_out;

    // fused prologue: LN1 + QKV-weight repack + 3 weight transposes (independent)
    prep_ln1_k<<<BT_ + 768 + 256 + 1024 + 1024, 256, 0, stream>>>(
        x, g1, be1, hB, Wq, Wk, Wv, WtB, Wo, WoB, W1, W1B, W2, W2B);
    // qkv = h @ Wt^T    [8192 x 3072], 128x256 tiles -> grid 768
    mgemm8_k<128,256,2,4,0,0,0,1><<<(N3_ / 256) * (BT_ / 128), 512, 0, stream>>>(
        hB, WtB, nullptr, nullptr, qkvB, BT_, N3_, C_, C_, N3_ / 256);
    // Vt = transpose(V cols) into hB (LN1 output dead)
    transv_k<<<B_ * H_ * (T_ / 64), 256, 0, stream>>>(qkvB, hB);
    // attention (paired q-tiles, XCD-swizzled; O -> Q slots of qkv)
    fattn_k<<<B_ * H_ * 16, 256, 0, stream>>>(qkvB, hB);
    // x2 = x + O @ Wo + bo -> fp32 in d_out   [8192 x 1024], 128x256, grid 256
    mgemm8_k<128,256,2,4,0,1,1,0><<<(C_ / 256) * (BT_ / 128), 512, 0, stream>>>(
        qkvB, WoB, bo, x, x2F, BT_, C_, C_, N3_, C_ / 256);
    // h2 = LN2(x2)
    ln_k<<<BT_, 256, 0, stream>>>(x2F, g2, be2, hB);
    // ff1 = relu(h2 @ W1 + b1)   [8192 x 4096], 256x256 tiles, grid 512
    mgemm8_k<256,256,2,4,1,1,0,1><<<(F_ / 256) * (BT_ / 256), 512, 0, stream>>>(
        hB, W1B, b1, nullptr, ff1B, BT_, F_, C_, C_, F_ / 256);
    // out = x2 + ff1 @ W2 + b2   [8192 x 1024], 128x256, grid 256
    mgemm8_k<128,256,2,4,0,1,1,0><<<(C_ / 256) * (BT_ / 128), 512, 0, stream>>>(
        ff1B, W2B, b2, x2F, (float*)d_out, BT_, C_, F_, F_, C_ / 256);
}

// Round 25
// 333.437 us; speedup vs baseline: 1.1131x; 1.0215x over previous
//
#include <hip/hip_runtime.h>
#include <math.h>

#define B_  4
#define T_  2048
#define C_  1024
#define H_  16
#define HS_ 64
#define BT_ (B_*T_)
#define F_  (4*C_)
#define N3_ (3*C_)

typedef unsigned short ushort_t;
typedef __attribute__((ext_vector_type(4))) unsigned short us4;
typedef __attribute__((ext_vector_type(8))) unsigned short us8;
typedef __attribute__((ext_vector_type(4))) float f32x4;
typedef __attribute__((ext_vector_type(8))) __bf16 bf16x8;

template<bool V> struct bool_c { static constexpr bool value = V; };

__device__ __forceinline__ float bf2f(ushort_t u) {
    union { unsigned int i; float f; } c; c.i = ((unsigned int)u) << 16; return c.f;
}
// Native bf16 convert (RNE) — single v_cvt instruction on gfx950.
__device__ __forceinline__ ushort_t f2bf(float f) {
    union { __bf16 b; ushort_t u; } c; c.b = (__bf16)f; return c.u;
}

// global_load_lds: LDS dest = wave-uniform base + lane*16 (HW); global src per-lane.
#define GLB_(p) ((const __attribute__((address_space(1))) unsigned int*)(size_t)(p))
#define LDS_(p) ((__attribute__((address_space(3))) unsigned int*)(unsigned int)(size_t)(p))
__device__ __forceinline__ void gload16(const void* g, void* l) {
    __builtin_amdgcn_global_load_lds(GLB_(g), LDS_(l), 16, 0, 0);
}

template<int N> __device__ __forceinline__ void vm_wait() {
    if constexpr (N >= 8)      asm volatile("s_waitcnt vmcnt(8)" ::: "memory");
    else if constexpr (N == 6) asm volatile("s_waitcnt vmcnt(6)" ::: "memory");
    else if constexpr (N == 4) asm volatile("s_waitcnt vmcnt(4)" ::: "memory");
    else if constexpr (N == 3) asm volatile("s_waitcnt vmcnt(3)" ::: "memory");
    else if constexpr (N == 2) asm volatile("s_waitcnt vmcnt(2)" ::: "memory");
    else                       asm volatile("s_waitcnt vmcnt(0)" ::: "memory");
}

// ---------- device bodies for the fused prologue (validated R24) ----------
__device__ __forceinline__ void repack_body(
    float (*tile)[65], const float* __restrict__ Wq, const float* __restrict__ Wk,
    const float* __restrict__ Wv, ushort_t* __restrict__ WtB, int bid)
{
    int p  = bid >> 8;
    int h  = (bid >> 4) & 15;
    int c0 = (bid & 15) * 64;
    const float* W = (p == 0) ? Wq : ((p == 1) ? Wk : Wv);
    int t = threadIdx.x;
    int cl = t >> 2, seg = (t & 3) * 16;
    const float* src = W + ((size_t)h * C_ + c0 + cl) * HS_ + seg;
#pragma unroll
    for (int i = 0; i < 4; i++) {
        float4 v = *(const float4*)(src + i * 4);
        tile[cl][seg + i*4 + 0] = v.x; tile[cl][seg + i*4 + 1] = v.y;
        tile[cl][seg + i*4 + 2] = v.z; tile[cl][seg + i*4 + 3] = v.w;
    }
    __syncthreads();
    int sl = t >> 2;
    int n = p * C_ + h * HS_ + sl;
    ushort_t* dst = WtB + (size_t)n * C_ + c0 + seg;
    us8 o0, o1;
#pragma unroll
    for (int e = 0; e < 8; e++) { o0[e] = f2bf(tile[seg + e][sl]); o1[e] = f2bf(tile[seg + 8 + e][sl]); }
    *(us8*)dst = o0; *(us8*)(dst + 8) = o1;
}

__device__ __forceinline__ void transpose_body(
    float (*tile)[65], const float* __restrict__ in, ushort_t* __restrict__ out,
    int K, int N, int bx, int by)
{
    int n0 = bx * 64, k0 = by * 64;
    int t = threadIdx.x;
    int kl = t >> 2, seg = (t & 3) * 16;
    const float* src = in + (size_t)(k0 + kl) * N + n0 + seg;
#pragma unroll
    for (int i = 0; i < 4; i++) {
        float4 v = *(const float4*)(src + i * 4);
        tile[kl][seg + i*4 + 0] = v.x; tile[kl][seg + i*4 + 1] = v.y;
        tile[kl][seg + i*4 + 2] = v.z; tile[kl][seg + i*4 + 3] = v.w;
    }
    __syncthreads();
    int nl = t >> 2;
    ushort_t* dst = out + (size_t)(n0 + nl) * K + k0 + seg;
    us8 o0, o1;
#pragma unroll
    for (int e = 0; e < 8; e++) { o0[e] = f2bf(tile[seg + e][nl]); o1[e] = f2bf(tile[seg + 8 + e][nl]); }
    *(us8*)dst = o0; *(us8*)(dst + 8) = o1;
}

__device__ __forceinline__ void ln_body(
    float* red, const float* __restrict__ xr0, const float* __restrict__ g,
    const float* __restrict__ b, ushort_t* __restrict__ out, int row)
{
    int t = threadIdx.x;
    const float* xr = xr0 + (size_t)row * C_;
    float4 f = *(const float4*)(xr + t * 4);
    float v[4] = {f.x, f.y, f.z, f.w};
    float s  = v[0] + v[1] + v[2] + v[3];
    float ss = v[0]*v[0] + v[1]*v[1] + v[2]*v[2] + v[3]*v[3];
#pragma unroll
    for (int off = 32; off > 0; off >>= 1) {
        s  += __shfl_xor(s, off);
        ss += __shfl_xor(ss, off);
    }
    int wv = t >> 6;
    if ((t & 63) == 0) { red[wv*2] = s; red[wv*2+1] = ss; }
    __syncthreads();
    s  = red[0] + red[2] + red[4] + red[6];
    ss = red[1] + red[3] + red[5] + red[7];
    float mu  = s * (1.0f / C_);
    float var = ss * (1.0f / C_) - mu * mu;
    float rs  = rsqrtf(var + 1e-5f);
    float4 gv = *(const float4*)(g + t * 4);
    float4 bv = *(const float4*)(b + t * 4);
    us4 o;
    o[0] = f2bf((v[0] - mu) * rs * gv.x + bv.x);
    o[1] = f2bf((v[1] - mu) * rs * gv.y + bv.y);
    o[2] = f2bf((v[2] - mu) * rs * gv.z + bv.z);
    o[3] = f2bf((v[3] - mu) * rs * gv.w + bv.w);
    *(us4*)(out + (size_t)row * C_ + t * 4) = o;
}

// ---------- fused prologue: LN1 (8192) + repack (768) + T(Wo) 256 + T(W1) 1024 + T(W2) 1024 ----------
__global__ __launch_bounds__(256) void prep_ln1_k(
    const float* __restrict__ x, const float* __restrict__ g1, const float* __restrict__ be1,
    ushort_t* __restrict__ hB,
    const float* __restrict__ Wq, const float* __restrict__ Wk, const float* __restrict__ Wv,
    ushort_t* __restrict__ WtB,
    const float* __restrict__ Wo, ushort_t* __restrict__ WoB,
    const float* __restrict__ W1, ushort_t* __restrict__ W1B,
    const float* __restrict__ W2, ushort_t* __restrict__ W2B)
{
    __shared__ float tile[64][65];
    __shared__ float red[8];
    int bid = blockIdx.x;
    if (bid < BT_) { ln_body(red, x, g1, be1, hB, bid); return; }
    bid -= BT_;
    if (bid < 768) { repack_body(tile, Wq, Wk, Wv, WtB, bid); return; }
    bid -= 768;
    if (bid < 256) { transpose_body(tile, Wo, WoB, C_, C_, bid & 15, bid >> 4); return; }
    bid -= 256;
    if (bid < 1024) { transpose_body(tile, W1, W1B, C_, F_, bid & 63, bid >> 6); return; }
    bid -= 1024;
    transpose_body(tile, W2, W2B, F_, C_, bid & 15, bid >> 4);
}

// ---------- standalone LN (fp32 in, bf16 out) for LN2 ----------
__global__ __launch_bounds__(256) void ln_k(
    const float* __restrict__ xv, const float* __restrict__ g,
    const float* __restrict__ b, ushort_t* __restrict__ out)
{
    __shared__ float red[8];
    ln_body(red, xv, g, b, out, blockIdx.x);
}

// ---------- 8-phase MFMA bf16 GEMM (validated R24 + fused V-transpose epilogue) ----------
// NEW (R25): for the qkv GEMM (vt != nullptr), V-region blocks (bx >= 8, cols
// 2048..3072; each wave's 64-col slice = one head) write their output DIRECTLY
// TRANSPOSED to Vt[(b*H+h)*64+d][t] via a wave-private [d][t] LDS scratch
// (stride 24 ushorts = 48B, 16B-aligned rows), skipping qkvB entirely.
// Replaces the separate transv_k dispatch (16MB re-read + 16MB re-write).
template<int BM, int BN, int WM, int WN, int RELU, int BIAS, int RES_MODE, int OUT_BF16>
__global__ __launch_bounds__(WM * WN * 64) void mgemm8_k(
    const ushort_t* __restrict__ A, const ushort_t* __restrict__ Bw,
    const float* __restrict__ bias, const void* __restrict__ res,
    void* __restrict__ out, int M, int N, int K, int lda, int gx,
    ushort_t* __restrict__ vt)
{
    constexpr int THREADS = WM * WN * 64;
    constexpr int MIa = BM / WM / 16;
    constexpr int MIb = BN / WN / 16;
    constexpr int A_INSTS = (BM * 64) / (16 * THREADS);   // gload insts per thread per A k-half
    constexpr int B_INSTS = (BN * 64) / (16 * THREADS);
    constexpr int UNIT = A_INSTS + B_INSTS;               // VMEM insts per staging unit
    __shared__ ushort_t As[4 * BM * 32];                  // 2buf x 2kh
    __shared__ ushort_t Bs[4 * BN * 32];

    int tid = threadIdx.x;
    int l = tid & 63, w = tid >> 6;
    int wm = w / WN, wn = w % WN;
    int lin = blockIdx.x;
    int nwg = gridDim.x;
    int swz = (lin & 7) * (nwg >> 3) + (lin >> 3);
    int bx = swz % gx, by = swz / gx;
    int m0 = by * BM, n0 = bx * BN;
    const int nt = K >> 6;

    auto stageA = [&](int tile, int kh) {
        ushort_t* dst = As + ((tile & 1) * 2 + kh) * (BM * 32);
#pragma unroll
        for (int inst = 0; inst < A_INSTS; ++inst) {
            int slot = inst * THREADS + tid;
            int row = slot >> 2, q = slot & 3;
            const ushort_t* src = A + (size_t)(m0 + row) * lda + tile * 64 + kh * 32
                                  + ((q ^ ((row >> 1) & 3)) * 8);
            gload16(src, dst + (inst * THREADS + w * 64) * 8);
        }
    };
    auto stageB = [&](int tile, int kh) {
        ushort_t* dst = Bs + ((tile & 1) * 2 + kh) * (BN * 32);
#pragma unroll
        for (int inst = 0; inst < B_INSTS; ++inst) {
            int slot = inst * THREADS + tid;
            int row = slot >> 2, q = slot & 3;
            const ushort_t* src = Bw + (size_t)(n0 + row) * K + tile * 64 + kh * 32
                                  + ((q ^ ((row >> 1) & 3)) * 8);
            gload16(src, dst + (inst * THREADS + w * 64) * 8);
        }
    };

    f32x4 acc[MIa][MIb];
#pragma unroll
    for (int i = 0; i < MIa; i++)
#pragma unroll
        for (int j = 0; j < MIb; j++) acc[i][j] = (f32x4){0.f, 0.f, 0.f, 0.f};

    // prologue: 3 units ahead (t0kh0, t0kh1, t1kh0)
    stageA(0, 0); stageB(0, 0);
    stageA(0, 1); stageB(0, 1);
    stageA(1, 0); stageB(1, 0);

    for (int t = 0; t < nt; ++t) {
        int buf = t & 1;
#pragma unroll
        for (int kh = 0; kh < 2; ++kh) {
            // unit for this phase was issued 3 phases ago; 2 units behind it
            if (t == nt - 1) { if (kh == 0) vm_wait<UNIT>(); else vm_wait<0>(); }
            else vm_wait<2 * UNIT>();
            __builtin_amdgcn_s_barrier();
            __builtin_amdgcn_sched_barrier(0);

            const ushort_t* Ab = As + (buf * 2 + kh) * (BM * 32);
            const ushort_t* Bb = Bs + (buf * 2 + kh) * (BN * 32);
            bf16x8 af[MIa], bf[MIb];
#pragma unroll
            for (int i = 0; i < MIa; ++i) {
                int row = wm * (BM / WM) + i * 16 + (l & 15);
                af[i] = *(const bf16x8*)(Ab + row * 32 + (((l >> 4) ^ ((row >> 1) & 3)) * 8));
            }
#pragma unroll
            for (int j = 0; j < MIb; ++j) {
                int row = wn * (BN / WN) + j * 16 + (l & 15);
                bf[j] = *(const bf16x8*)(Bb + row * 32 + (((l >> 4) ^ ((row >> 1) & 3)) * 8));
            }
            // stage schedule: ph0 -> (t+1) kh1 ; ph1 -> (t+2) kh0
            if (kh == 0) { if (t + 1 < nt) { stageA(t + 1, 1); stageB(t + 1, 1); } }
            else         { if (t + 2 < nt) { stageA(t + 2, 0); stageB(t + 2, 0); } }

            __builtin_amdgcn_s_setprio(1);
#pragma unroll
            for (int i = 0; i < MIa; ++i)
#pragma unroll
                for (int j = 0; j < MIb; ++j)
                    acc[i][j] = __builtin_amdgcn_mfma_f32_16x16x32_bf16(af[i], bf[j], acc[i][j], 0, 0, 0);
            __builtin_amdgcn_s_setprio(0);
            __builtin_amdgcn_sched_barrier(0);
            __builtin_amdgcn_s_barrier();
        }
    }

    if (OUT_BF16 && RES_MODE == 0 && vt != nullptr && bx >= 8) {
        // qkv V-region: write transposed directly to Vt[(b*H+h)*64+d][t]
        ushort_t* st = As + w * 1536;               // 64 rows x 24-ushort stride (48B)
        int h = (n0 + wn * 64 - 2048) >> 6;
#pragma unroll
        for (int i = 0; i < MIa; i++) {
#pragma unroll
            for (int j = 0; j < MIb; j++) {
#pragma unroll
                for (int r = 0; r < 4; r++) {
                    int d   = j * 16 + (l & 15);
                    int tl2 = ((l >> 4) << 2) + r;
                    st[d * 24 + tl2] = f2bf(acc[i][j][r]);
                }
            }
            // in-order DS per wave: reads see writes above. lane = d.
            int grow = m0 + wm * (BM / WM) + i * 16;
            int bb = grow / T_;
            int t0 = grow % T_;
            us8 v0 = *(const us8*)(st + l * 24);
            us8 v1 = *(const us8*)(st + l * 24 + 8);
            ushort_t* dstp = vt + ((size_t)(bb * H_ + h) * HS_ + l) * T_ + t0;
            *(us8*)dstp       = v0;
            *(us8*)(dstp + 8) = v1;
        }
    } else if (OUT_BF16 && RES_MODE == 0) {
        // LDS-staged vectorized epilogue (wave-private 16x64 bf16 scratch in As)
        ushort_t* scratch = As + w * 1024;          // 2KB/wave
#pragma unroll
        for (int i = 0; i < MIa; i++) {
#pragma unroll
            for (int j = 0; j < MIb; j++) {
                int colo = wn * 64 + j * 16 + (l & 15);       // block-local col
                float bval = BIAS ? bias[n0 + colo] : 0.f;
#pragma unroll
                for (int r = 0; r < 4; r++) {
                    float v = acc[i][j][r] + bval;
                    if (RELU) v = fmaxf(v, 0.f);
                    scratch[(((l >> 4) << 2) + r) * 64 + j * 16 + (l & 15)] = f2bf(v);
                }
            }
            // in-order DS per wave: reads below see the writes above
#pragma unroll
            for (int rr = 0; rr < 2; rr++) {
                int lrow = rr * 8 + (l >> 3);
                us8 vv = *(const us8*)(scratch + lrow * 64 + (l & 7) * 8);
                int grow = m0 + wm * (BM / WM) + i * 16 + lrow;
                *(us8*)((ushort_t*)out + (size_t)grow * N + n0 + wn * 64 + (l & 7) * 8) = vv;
            }
        }
    } else if (!OUT_BF16 && RES_MODE == 1) {
        // fp32 LDS-staged epilogue with coalesced float4 residual+store (Wo/W2)
        float* scratch = (float*)As + w * 1024;     // 4KB/wave (8 waves = 32KB = As)
#pragma unroll
        for (int i = 0; i < MIa; i++) {
#pragma unroll
            for (int j = 0; j < MIb; j++) {
                int colo = wn * 64 + j * 16 + (l & 15);
                float bval = BIAS ? bias[n0 + colo] : 0.f;
#pragma unroll
                for (int r = 0; r < 4; r++) {
                    float v = acc[i][j][r] + bval;
                    if (RELU) v = fmaxf(v, 0.f);
                    scratch[(((l >> 4) << 2) + r) * 64 + j * 16 + (l & 15)] = v;
                }
            }
            // 4 rounds: lanes 0-15 cover one full 256B row -> coalesced float4
#pragma unroll
            for (int rr = 0; rr < 4; rr++) {
                int lrow = rr * 4 + (l >> 4);
                f32x4 v4 = *(const f32x4*)(scratch + lrow * 64 + (l & 15) * 4);
                int grow = m0 + wm * (BM / WM) + i * 16 + lrow;
                size_t base = (size_t)grow * N + n0 + wn * 64 + (l & 15) * 4;
                f32x4 r4 = *(const f32x4*)((const float*)res + base);
                v4 += r4;
                *(f32x4*)((float*)out + base) = v4;
            }
        }
    } else {
        int colb = n0 + wn * (BN / WN) + (l & 15);
        int rowb = m0 + wm * (BM / WM) + ((l >> 4) << 2);
#pragma unroll
        for (int j = 0; j < MIb; j++) {
            int col = colb + j * 16;
            float bval = BIAS ? bias[col] : 0.f;
#pragma unroll
            for (int i = 0; i < MIa; i++) {
#pragma unroll
                for (int r = 0; r < 4; r++) {
                    int row = rowb + i * 16 + r;
                    float v = acc[i][j][r] + bval;
                    if (RELU) v = fmaxf(v, 0.f);
                    size_t idx = (size_t)row * N + col;
                    if (RES_MODE == 1) v += ((const float*)res)[idx];
                    else if (RES_MODE == 2) v += bf2f(((const ushort_t*)res)[idx]);
                    if (OUT_BF16) ((ushort_t*)out)[idx] = f2bf(v);
                    else          ((float*)out)[idx]    = v;
                }
            }
        }
    }
}

// ---------- MFMA flash attention, v8 (best measured: 82 us) ----------
// QK-early pipeline: S(kt+1) MFMA overlaps softmax(kt) VALU; K 3-buf staged 2
// ahead, V 2-buf; Qs/Ps union (QPs); __expf (v_exp_f32); diag-specialized mask.
__global__ __launch_bounds__(256) void fattn_k(
    ushort_t* __restrict__ QKV, const ushort_t* __restrict__ Vt)
{
    __shared__ ushort_t QPs[64 * 64];     // Q staging (prologue) / P tile (loop)
    __shared__ ushort_t Ks[3][64 * 64];
    __shared__ ushort_t Vs[2][64 * 64];
    int lin = blockIdx.x;
    int nwg = gridDim.x;                       // 1024, %8 == 0
    int bid = (lin & 7) * (nwg >> 3) + (lin >> 3);   // bijective XCD remap
    int pr = bid & 15;
    int bh = bid >> 4;
    int b  = bh >> 4;
    int h  = bh & 15;
    int tid = threadIdx.x;
    int lid = tid & 63, w = tid >> 6;

    int srow = w * 16 + (lid >> 3);
    int sseg0 = (lid & 7) ^ (srow & 7);
    int sseg1 = (lid & 7) ^ ((srow + 8) & 7);
    const ushort_t* Kg = QKV + (size_t)(b * T_) * N3_ + C_ + h * HS_;
    const ushort_t* Vg = Vt + (size_t)(b * H_ + h) * HS_ * T_;

    int mrow = w * 16 + (lid & 15);
    int fseg = lid >> 4;
    int qlocb = w * 16 + ((lid >> 4) << 2);

    const __bf16 oneb = (__bf16)1.0f;
    bf16x8 ones = {oneb, oneb, oneb, oneb, oneb, oneb, oneb, oneb};

    auto stageK = [&](int kt) {
        ushort_t* d = Ks[kt % 3];
        gload16(Kg + (size_t)(kt * 64 + srow) * N3_ + sseg0 * 8,     d + w * 1024);
        gload16(Kg + (size_t)(kt * 64 + srow + 8) * N3_ + sseg1 * 8, d + w * 1024 + 512);
    };
    auto stageV = [&](int kt) {
        ushort_t* d = Vs[kt & 1];
        gload16(Vg + (size_t)srow * T_ + kt * 64 + sseg0 * 8,       d + w * 1024);
        gload16(Vg + (size_t)(srow + 8) * T_ + kt * 64 + sseg1 * 8, d + w * 1024 + 512);
    };

    for (int half = 0; half < 2; ++half) {
        int qt = half ? (31 - pr) : pr;
        const ushort_t* Qg = QKV + (size_t)(b * T_ + qt * 64) * N3_ + h * HS_;

        // prologue: stage Q, K0, V0, K1 (all dests wave-private rows)
        gload16(Qg + (size_t)srow * N3_ + sseg0 * 8,       QPs + w * 1024);
        gload16(Qg + (size_t)(srow + 8) * N3_ + sseg1 * 8, QPs + w * 1024 + 512);
        stageK(0);
        stageV(0);
        if (qt >= 1) stageK(1);
        __syncthreads();   // drains all staging + syncs waves

        // Q fragments loop-invariant -> registers; QPs becomes the P tile.
        bf16x8 aqr[2];
        aqr[0] = *(const bf16x8*)(QPs + mrow * 64 + (((0 + fseg) ^ (mrow & 7)) * 8));
        aqr[1] = *(const bf16x8*)(QPs + mrow * 64 + (((4 + fseg) ^ (mrow & 7)) * 8));

        f32x4 accO[4];
#pragma unroll
        for (int j = 0; j < 4; j++) accO[j] = (f32x4){0.f, 0.f, 0.f, 0.f};
        f32x4 accL = (f32x4){0.f, 0.f, 0.f, 0.f};

        auto qk_into = [&](const ushort_t* Kc, f32x4* s) {
#pragma unroll
            for (int j = 0; j < 4; j++) s[j] = (f32x4){0.f, 0.f, 0.f, 0.f};
            __builtin_amdgcn_s_setprio(1);
#pragma unroll
            for (int ks = 0; ks < 2; ks++) {
#pragma unroll
                for (int j = 0; j < 4; j++) {
                    int krow = j * 16 + (lid & 15);
                    bf16x8 bk = *(const bf16x8*)(Kc + krow * 64 + (((ks * 4 + fseg) ^ (krow & 7)) * 8));
                    s[j] = __builtin_amdgcn_mfma_f32_16x16x32_bf16(aqr[ks], bk, s[j], 0, 0, 0);
                }
            }
            __builtin_amdgcn_s_setprio(0);
        };
        auto smax_pv = [&](auto diag_c, f32x4* s, const ushort_t* Vc) {
            constexpr bool DIAG = decltype(diag_c)::value;
#pragma unroll
            for (int r = 0; r < 4; r++) {
                int qloc = qlocb + r;
#pragma unroll
                for (int j = 0; j < 4; j++) {
                    int col = j * 16 + (lid & 15);
                    float p = __expf(s[j][r] * 0.125f);
                    if (DIAG) { if (col > qloc) p = 0.f; }
                    QPs[qloc * 64 + (((col >> 3) ^ (qloc & 7)) * 8) + (col & 7)] = f2bf(p);
                }
            }
            __builtin_amdgcn_s_setprio(1);
#pragma unroll
            for (int ks = 0; ks < 2; ks++) {
                bf16x8 ap = *(const bf16x8*)(QPs + mrow * 64 + (((ks * 4 + fseg) ^ (mrow & 7)) * 8));
                accL = __builtin_amdgcn_mfma_f32_16x16x32_bf16(ap, ones, accL, 0, 0, 0);
#pragma unroll
                for (int j = 0; j < 4; j++) {
                    int drow = j * 16 + (lid & 15);
                    bf16x8 bv = *(const bf16x8*)(Vc + drow * 64 + (((ks * 4 + fseg) ^ (drow & 7)) * 8));
                    accO[j] = __builtin_amdgcn_mfma_f32_16x16x32_bf16(ap, bv, accO[j], 0, 0, 0);
                }
            }
            __builtin_amdgcn_s_setprio(0);
        };

        // sP = S(0)
        f32x4 sP[4], sN[4];
        qk_into(Ks[0], sP);

        for (int kt = 0; kt < qt; ++kt) {
            // early-issue staging: K two ahead, V one ahead
            if (kt + 2 <= qt) stageK(kt + 2);
            stageV(kt + 1);
            // QK(kt+1) — independent of softmax(kt); overlaps its VALU work
            qk_into(Ks[(kt + 1) % 3], sN);
            // softmax(kt) (never diag in-loop) + PV(kt)
            smax_pv(bool_c<false>{}, sP, Vs[kt & 1]);
            __syncthreads();   // staged loads drained; all waves done with K/V[cur]
#pragma unroll
            for (int j = 0; j < 4; j++) sP[j] = sN[j];
        }
        // final tile kt = qt: diag mask
        smax_pv(bool_c<true>{}, sP, Vs[qt & 1]);
        __syncthreads();   // all reads done before next half restages

#pragma unroll
        for (int r = 0; r < 4; r++) {
            float inv = 1.0f / accL[r];
            int qabs = qt * 64 + qlocb + r;
            ushort_t* orow = QKV + (size_t)(b * T_ + qabs) * N3_ + h * HS_;
#pragma unroll
            for (int j = 0; j < 4; j++)
                orow[j * 16 + (lid & 15)] = f2bf(accO[j][r] * inv);
        }
    }
}

extern "C" void kernel_launch(void* const* d_in, const int* in_sizes, int n_in,
                              void* d_out, int out_size, void* d_ws, size_t ws_size,
                              hipStream_t stream)
{
    const float* x   = (const float*)d_in[0];
    const float* g1  = (const float*)d_in[1];
    const float* be1 = (const float*)d_in[2];
    const float* Wq  = (const float*)d_in[3];
    const float* Wk  = (const float*)d_in[4];
    const float* Wv  = (const float*)d_in[5];
    const float* Wo  = (const float*)d_in[6];
    const float* bo  = (const float*)d_in[7];
    const float* g2  = (const float*)d_in[8];
    const float* be2 = (const float*)d_in[9];
    const float* W1  = (const float*)d_in[10];
    const float* b1  = (const float*)d_in[11];
    const float* W2  = (const float*)d_in[12];
    const float* b2  = (const float*)d_in[13];

    // ws (bytes): hB 16M | big region 64M (qkv 48M + Vt tail 16M during attn;
    // ff1 64M later, time-disjoint) | WtB 6M | WoB 2M | W1B 8M | W2B 8M = 104 MiB.
    // x2 lives as fp32 in d_out. Vt = wsb+4*UB2 (big-region tail: free during
    // qkv GEMM + attention; overwritten by ff1 only after fattn consumed it).
    const size_t UB2 = (size_t)BT_ * C_ * 2;
    const size_t WT_B = (size_t)N3_ * C_ * 2;
    const size_t WO_B = (size_t)C_ * C_ * 2;
    const size_t W1_B = (size_t)C_ * F_ * 2;
    const size_t REQ = 5 * UB2 + WT_B + WO_B + 2 * W1_B;
    if (ws_size < REQ) {
        hipMemsetAsync(d_out, 0, (size_t)out_size * 4, stream);
        return;
    }
    char* wsb = (char*)d_ws;
    ushort_t* hB   = (ushort_t*)(wsb);                 // LN1 out; h2 after LN2
    ushort_t* qkvB = (ushort_t*)(wsb + UB2);           // big region
    ushort_t* ff1B = qkvB;
    ushort_t* VtB  = (ushort_t*)(wsb + 4 * UB2);       // big-region tail
    ushort_t* WtB  = (ushort_t*)(wsb + 5 * UB2);
    ushort_t* WoB  = (ushort_t*)(wsb + 5 * UB2 + WT_B);
    ushort_t* W1B  = (ushort_t*)(wsb + 5 * UB2 + WT_B + WO_B);
    ushort_t* W2B  = (ushort_t*)(wsb + 5 * UB2 + WT_B + WO_B + W1_B);
    float* x2F = (float*)d_out;

    // fused prologue: LN1 + QKV-weight repack + 3 weight transposes (independent)
    prep_ln1_k<<<BT_ + 768 + 256 + 1024 + 1024, 256, 0, stream>>>(
        x, g1, be1, hB, Wq, Wk, Wv, WtB, Wo, WoB, W1, W1B, W2, W2B);
    // qkv = h @ Wt^T  [8192 x 3072]; V-region blocks write transposed into VtB
    mgemm8_k<128,256,2,4,0,0,0,1><<<(N3_ / 256) * (BT_ / 128), 512, 0, stream>>>(
        hB, WtB, nullptr, nullptr, qkvB, BT_, N3_, C_, C_, N3_ / 256, VtB);
    // attention (paired q-tiles, XCD-swizzled; O -> Q slots of qkv)
    fattn_k<<<B_ * H_ * 16, 256, 0, stream>>>(qkvB, VtB);
    // x2 = x + O @ Wo + bo -> fp32 in d_out   [8192 x 1024], 128x256, grid 256
    mgemm8_k<128,256,2,4,0,1,1,0><<<(C_ / 256) * (BT_ / 128), 512, 0, stream>>>(
        qkvB, WoB, bo, x, x2F, BT_, C_, C_, N3_, C_ / 256, nullptr);
    // h2 = LN2(x2)
    ln_k<<<BT_, 256, 0, stream>>>(x2F, g2, be2, hB);
    // ff1 = relu(h2 @ W1 + b1)   [8192 x 4096], 256x256 tiles, grid 512
    mgemm8_k<256,256,2,4,1,1,0,1><<<(F_ / 256) * (BT_ / 256), 512, 0, stream>>>(
        hB, W1B, b1, nullptr, ff1B, BT_, F_, C_, C_, F_ / 256, nullptr);
    // out = x2 + ff1 @ W2 + b2   [8192 x 1024], 128x256, grid 256
    mgemm8_k<128,256,2,4,0,1,1,0><<<(C_ / 256) * (BT_ / 128), 512, 0, stream>>>(
        ff1B, W2B, b2, x2F, (float*)d_out, BT_, C_, F_, F_, C_ / 256, nullptr);
}

// Round 26
// 332.312 us; speedup vs baseline: 1.1169x; 1.0034x over previous
//
#include <hip/hip_runtime.h>
#include <math.h>

#define B_  4
#define T_  2048
#define C_  1024
#define H_  16
#define HS_ 64
#define BT_ (B_*T_)
#define F_  (4*C_)
#define N3_ (3*C_)

typedef unsigned short ushort_t;
typedef __attribute__((ext_vector_type(4))) unsigned short us4;
typedef __attribute__((ext_vector_type(8))) unsigned short us8;
typedef __attribute__((ext_vector_type(4))) float f32x4;
typedef __attribute__((ext_vector_type(8))) __bf16 bf16x8;

template<bool V> struct bool_c { static constexpr bool value = V; };

__device__ __forceinline__ float bf2f(ushort_t u) {
    union { unsigned int i; float f; } c; c.i = ((unsigned int)u) << 16; return c.f;
}
// Native bf16 convert (RNE) — single v_cvt instruction on gfx950.
__device__ __forceinline__ ushort_t f2bf(float f) {
    union { __bf16 b; ushort_t u; } c; c.b = (__bf16)f; return c.u;
}

// global_load_lds: LDS dest = wave-uniform base + lane*16 (HW); global src per-lane.
#define GLB_(p) ((const __attribute__((address_space(1))) unsigned int*)(size_t)(p))
#define LDS_(p) ((__attribute__((address_space(3))) unsigned int*)(unsigned int)(size_t)(p))
__device__ __forceinline__ void gload16(const void* g, void* l) {
    __builtin_amdgcn_global_load_lds(GLB_(g), LDS_(l), 16, 0, 0);
}

template<int N> __device__ __forceinline__ void vm_wait() {
    if constexpr (N >= 8)      asm volatile("s_waitcnt vmcnt(8)" ::: "memory");
    else if constexpr (N == 6) asm volatile("s_waitcnt vmcnt(6)" ::: "memory");
    else if constexpr (N == 4) asm volatile("s_waitcnt vmcnt(4)" ::: "memory");
    else if constexpr (N == 3) asm volatile("s_waitcnt vmcnt(3)" ::: "memory");
    else if constexpr (N == 2) asm volatile("s_waitcnt vmcnt(2)" ::: "memory");
    else                       asm volatile("s_waitcnt vmcnt(0)" ::: "memory");
}

// ---------- device bodies for the fused prologue (validated R25) ----------
__device__ __forceinline__ void repack_body(
    float (*tile)[65], const float* __restrict__ Wq, const float* __restrict__ Wk,
    const float* __restrict__ Wv, ushort_t* __restrict__ WtB, int bid)
{
    int p  = bid >> 8;
    int h  = (bid >> 4) & 15;
    int c0 = (bid & 15) * 64;
    const float* W = (p == 0) ? Wq : ((p == 1) ? Wk : Wv);
    int t = threadIdx.x;
    int cl = t >> 2, seg = (t & 3) * 16;
    const float* src = W + ((size_t)h * C_ + c0 + cl) * HS_ + seg;
#pragma unroll
    for (int i = 0; i < 4; i++) {
        float4 v = *(const float4*)(src + i * 4);
        tile[cl][seg + i*4 + 0] = v.x; tile[cl][seg + i*4 + 1] = v.y;
        tile[cl][seg + i*4 + 2] = v.z; tile[cl][seg + i*4 + 3] = v.w;
    }
    __syncthreads();
    int sl = t >> 2;
    int n = p * C_ + h * HS_ + sl;
    ushort_t* dst = WtB + (size_t)n * C_ + c0 + seg;
    us8 o0, o1;
#pragma unroll
    for (int e = 0; e < 8; e++) { o0[e] = f2bf(tile[seg + e][sl]); o1[e] = f2bf(tile[seg + 8 + e][sl]); }
    *(us8*)dst = o0; *(us8*)(dst + 8) = o1;
}

__device__ __forceinline__ void transpose_body(
    float (*tile)[65], const float* __restrict__ in, ushort_t* __restrict__ out,
    int K, int N, int bx, int by)
{
    int n0 = bx * 64, k0 = by * 64;
    int t = threadIdx.x;
    int kl = t >> 2, seg = (t & 3) * 16;
    const float* src = in + (size_t)(k0 + kl) * N + n0 + seg;
#pragma unroll
    for (int i = 0; i < 4; i++) {
        float4 v = *(const float4*)(src + i * 4);
        tile[kl][seg + i*4 + 0] = v.x; tile[kl][seg + i*4 + 1] = v.y;
        tile[kl][seg + i*4 + 2] = v.z; tile[kl][seg + i*4 + 3] = v.w;
    }
    __syncthreads();
    int nl = t >> 2;
    ushort_t* dst = out + (size_t)(n0 + nl) * K + k0 + seg;
    us8 o0, o1;
#pragma unroll
    for (int e = 0; e < 8; e++) { o0[e] = f2bf(tile[seg + e][nl]); o1[e] = f2bf(tile[seg + 8 + e][nl]); }
    *(us8*)dst = o0; *(us8*)(dst + 8) = o1;
}

// 2-row layernorm: 256 thr = waves 0-1 own row 2*rp, waves 2-3 own row 2*rp+1.
// 128 lanes/row x float8 (32B/lane). red[8]: wave wv writes {s,ss} at {2wv,2wv+1};
// row half combines its two waves: s = red[4h]+red[4h+2], ss = red[4h+1]+red[4h+3].
__device__ __forceinline__ void ln2row_body(
    float* red, const float* __restrict__ x, const float* __restrict__ g,
    const float* __restrict__ b, ushort_t* __restrict__ out, int rp)
{
    int t = threadIdx.x;
    int half = t >> 7;
    int tl = t & 127;
    int row = rp * 2 + half;
    const float* xr = x + (size_t)row * C_ + tl * 8;
    float4 f0 = *(const float4*)xr;
    float4 f1 = *(const float4*)(xr + 4);
    float v[8] = {f0.x, f0.y, f0.z, f0.w, f1.x, f1.y, f1.z, f1.w};
    float s = 0.f, ss = 0.f;
#pragma unroll
    for (int i = 0; i < 8; i++) { s += v[i]; ss += v[i] * v[i]; }
#pragma unroll
    for (int off = 32; off > 0; off >>= 1) {
        s  += __shfl_xor(s, off);
        ss += __shfl_xor(ss, off);
    }
    int wv = t >> 6;
    if ((t & 63) == 0) { red[wv*2] = s; red[wv*2+1] = ss; }
    __syncthreads();
    s  = red[half*4 + 0] + red[half*4 + 2];
    ss = red[half*4 + 1] + red[half*4 + 3];
    float mu  = s * (1.0f / C_);
    float var = ss * (1.0f / C_) - mu * mu;
    float rs  = rsqrtf(var + 1e-5f);
    float4 g0 = *(const float4*)(g + tl * 8);
    float4 g1 = *(const float4*)(g + tl * 8 + 4);
    float4 b0 = *(const float4*)(b + tl * 8);
    float4 b1 = *(const float4*)(b + tl * 8 + 4);
    float gv[8] = {g0.x, g0.y, g0.z, g0.w, g1.x, g1.y, g1.z, g1.w};
    float bv[8] = {b0.x, b0.y, b0.z, b0.w, b1.x, b1.y, b1.z, b1.w};
    us8 o;
#pragma unroll
    for (int e = 0; e < 8; e++) o[e] = f2bf((v[e] - mu) * rs * gv[e] + bv[e]);
    *(us8*)(out + (size_t)row * C_ + tl * 8) = o;
}

// ---------- fused prologue: LN1 (4096 x 2-row) + repack (768) + T(Wo) 256 + T(W1) 1024 + T(W2) 1024 ----------
__global__ __launch_bounds__(256) void prep_ln1_k(
    const float* __restrict__ x, const float* __restrict__ g1, const float* __restrict__ be1,
    ushort_t* __restrict__ hB,
    const float* __restrict__ Wq, const float* __restrict__ Wk, const float* __restrict__ Wv,
    ushort_t* __restrict__ WtB,
    const float* __restrict__ Wo, ushort_t* __restrict__ WoB,
    const float* __restrict__ W1, ushort_t* __restrict__ W1B,
    const float* __restrict__ W2, ushort_t* __restrict__ W2B)
{
    __shared__ float tile[64][65];
    __shared__ float red[8];
    int bid = blockIdx.x;
    if (bid < BT_ / 2) { ln2row_body(red, x, g1, be1, hB, bid); return; }
    bid -= BT_ / 2;
    if (bid < 768) { repack_body(tile, Wq, Wk, Wv, WtB, bid); return; }
    bid -= 768;
    if (bid < 256) { transpose_body(tile, Wo, WoB, C_, C_, bid & 15, bid >> 4); return; }
    bid -= 256;
    if (bid < 1024) { transpose_body(tile, W1, W1B, C_, F_, bid & 63, bid >> 6); return; }
    bid -= 1024;
    transpose_body(tile, W2, W2B, F_, C_, bid & 15, bid >> 4);
}

// ---------- standalone 2-row LN (fp32 in, bf16 out) for LN2 ----------
__global__ __launch_bounds__(256) void ln_k(
    const float* __restrict__ xv, const float* __restrict__ g,
    const float* __restrict__ b, ushort_t* __restrict__ out)
{
    __shared__ float red[8];
    ln2row_body(red, xv, g, b, out, blockIdx.x);
}

// ---------- 8-phase MFMA bf16 GEMM (validated R25: T1 swizzle, UNIT vmcnt,
// LDS-staged coalesced epilogues, fused V-transpose for the qkv GEMM) ----------
template<int BM, int BN, int WM, int WN, int RELU, int BIAS, int RES_MODE, int OUT_BF16>
__global__ __launch_bounds__(WM * WN * 64) void mgemm8_k(
    const ushort_t* __restrict__ A, const ushort_t* __restrict__ Bw,
    const float* __restrict__ bias, const void* __restrict__ res,
    void* __restrict__ out, int M, int N, int K, int lda, int gx,
    ushort_t* __restrict__ vt)
{
    constexpr int THREADS = WM * WN * 64;
    constexpr int MIa = BM / WM / 16;
    constexpr int MIb = BN / WN / 16;
    constexpr int A_INSTS = (BM * 64) / (16 * THREADS);   // gload insts per thread per A k-half
    constexpr int B_INSTS = (BN * 64) / (16 * THREADS);
    constexpr int UNIT = A_INSTS + B_INSTS;               // VMEM insts per staging unit
    __shared__ ushort_t As[4 * BM * 32];                  // 2buf x 2kh
    __shared__ ushort_t Bs[4 * BN * 32];

    int tid = threadIdx.x;
    int l = tid & 63, w = tid >> 6;
    int wm = w / WN, wn = w % WN;
    int lin = blockIdx.x;
    int nwg = gridDim.x;
    int swz = (lin & 7) * (nwg >> 3) + (lin >> 3);
    int bx = swz % gx, by = swz / gx;
    int m0 = by * BM, n0 = bx * BN;
    const int nt = K >> 6;

    auto stageA = [&](int tile, int kh) {
        ushort_t* dst = As + ((tile & 1) * 2 + kh) * (BM * 32);
#pragma unroll
        for (int inst = 0; inst < A_INSTS; ++inst) {
            int slot = inst * THREADS + tid;
            int row = slot >> 2, q = slot & 3;
            const ushort_t* src = A + (size_t)(m0 + row) * lda + tile * 64 + kh * 32
                                  + ((q ^ ((row >> 1) & 3)) * 8);
            gload16(src, dst + (inst * THREADS + w * 64) * 8);
        }
    };
    auto stageB = [&](int tile, int kh) {
        ushort_t* dst = Bs + ((tile & 1) * 2 + kh) * (BN * 32);
#pragma unroll
        for (int inst = 0; inst < B_INSTS; ++inst) {
            int slot = inst * THREADS + tid;
            int row = slot >> 2, q = slot & 3;
            const ushort_t* src = Bw + (size_t)(n0 + row) * K + tile * 64 + kh * 32
                                  + ((q ^ ((row >> 1) & 3)) * 8);
            gload16(src, dst + (inst * THREADS + w * 64) * 8);
        }
    };

    f32x4 acc[MIa][MIb];
#pragma unroll
    for (int i = 0; i < MIa; i++)
#pragma unroll
        for (int j = 0; j < MIb; j++) acc[i][j] = (f32x4){0.f, 0.f, 0.f, 0.f};

    // prologue: 3 units ahead (t0kh0, t0kh1, t1kh0)
    stageA(0, 0); stageB(0, 0);
    stageA(0, 1); stageB(0, 1);
    stageA(1, 0); stageB(1, 0);

    for (int t = 0; t < nt; ++t) {
        int buf = t & 1;
#pragma unroll
        for (int kh = 0; kh < 2; ++kh) {
            // unit for this phase was issued 3 phases ago; 2 units behind it
            if (t == nt - 1) { if (kh == 0) vm_wait<UNIT>(); else vm_wait<0>(); }
            else vm_wait<2 * UNIT>();
            __builtin_amdgcn_s_barrier();
            __builtin_amdgcn_sched_barrier(0);

            const ushort_t* Ab = As + (buf * 2 + kh) * (BM * 32);
            const ushort_t* Bb = Bs + (buf * 2 + kh) * (BN * 32);
            bf16x8 af[MIa], bf[MIb];
#pragma unroll
            for (int i = 0; i < MIa; ++i) {
                int row = wm * (BM / WM) + i * 16 + (l & 15);
                af[i] = *(const bf16x8*)(Ab + row * 32 + (((l >> 4) ^ ((row >> 1) & 3)) * 8));
            }
#pragma unroll
            for (int j = 0; j < MIb; ++j) {
                int row = wn * (BN / WN) + j * 16 + (l & 15);
                bf[j] = *(const bf16x8*)(Bb + row * 32 + (((l >> 4) ^ ((row >> 1) & 3)) * 8));
            }
            // stage schedule: ph0 -> (t+1) kh1 ; ph1 -> (t+2) kh0
            if (kh == 0) { if (t + 1 < nt) { stageA(t + 1, 1); stageB(t + 1, 1); } }
            else         { if (t + 2 < nt) { stageA(t + 2, 0); stageB(t + 2, 0); } }

            __builtin_amdgcn_s_setprio(1);
#pragma unroll
            for (int i = 0; i < MIa; ++i)
#pragma unroll
                for (int j = 0; j < MIb; ++j)
                    acc[i][j] = __builtin_amdgcn_mfma_f32_16x16x32_bf16(af[i], bf[j], acc[i][j], 0, 0, 0);
            __builtin_amdgcn_s_setprio(0);
            __builtin_amdgcn_sched_barrier(0);
            __builtin_amdgcn_s_barrier();
        }
    }

    if (OUT_BF16 && RES_MODE == 0 && vt != nullptr && bx >= 8) {
        // qkv V-region: write transposed directly to Vt[(b*H+h)*64+d][t]
        ushort_t* st = As + w * 1536;               // 64 rows x 24-ushort stride (48B)
        int h = (n0 + wn * 64 - 2048) >> 6;
#pragma unroll
        for (int i = 0; i < MIa; i++) {
#pragma unroll
            for (int j = 0; j < MIb; j++) {
#pragma unroll
                for (int r = 0; r < 4; r++) {
                    int d   = j * 16 + (l & 15);
                    int tl2 = ((l >> 4) << 2) + r;
                    st[d * 24 + tl2] = f2bf(acc[i][j][r]);
                }
            }
            // in-order DS per wave: reads see writes above. lane = d.
            int grow = m0 + wm * (BM / WM) + i * 16;
            int bb = grow / T_;
            int t0 = grow % T_;
            us8 v0 = *(const us8*)(st + l * 24);
            us8 v1 = *(const us8*)(st + l * 24 + 8);
            ushort_t* dstp = vt + ((size_t)(bb * H_ + h) * HS_ + l) * T_ + t0;
            *(us8*)dstp       = v0;
            *(us8*)(dstp + 8) = v1;
        }
    } else if (OUT_BF16 && RES_MODE == 0) {
        // LDS-staged vectorized epilogue (wave-private 16x64 bf16 scratch in As)
        ushort_t* scratch = As + w * 1024;          // 2KB/wave
#pragma unroll
        for (int i = 0; i < MIa; i++) {
#pragma unroll
            for (int j = 0; j < MIb; j++) {
                int colo = wn * 64 + j * 16 + (l & 15);       // block-local col
                float bval = BIAS ? bias[n0 + colo] : 0.f;
#pragma unroll
                for (int r = 0; r < 4; r++) {
                    float v = acc[i][j][r] + bval;
                    if (RELU) v = fmaxf(v, 0.f);
                    scratch[(((l >> 4) << 2) + r) * 64 + j * 16 + (l & 15)] = f2bf(v);
                }
            }
            // in-order DS per wave: reads below see the writes above
#pragma unroll
            for (int rr = 0; rr < 2; rr++) {
                int lrow = rr * 8 + (l >> 3);
                us8 vv = *(const us8*)(scratch + lrow * 64 + (l & 7) * 8);
                int grow = m0 + wm * (BM / WM) + i * 16 + lrow;
                *(us8*)((ushort_t*)out + (size_t)grow * N + n0 + wn * 64 + (l & 7) * 8) = vv;
            }
        }
    } else if (!OUT_BF16 && RES_MODE == 1) {
        // fp32 LDS-staged epilogue with coalesced float4 residual+store (Wo/W2)
        float* scratch = (float*)As + w * 1024;     // 4KB/wave (8 waves = 32KB = As)
#pragma unroll
        for (int i = 0; i < MIa; i++) {
#pragma unroll
            for (int j = 0; j < MIb; j++) {
                int colo = wn * 64 + j * 16 + (l & 15);
                float bval = BIAS ? bias[n0 + colo] : 0.f;
#pragma unroll
                for (int r = 0; r < 4; r++) {
                    float v = acc[i][j][r] + bval;
                    if (RELU) v = fmaxf(v, 0.f);
                    scratch[(((l >> 4) << 2) + r) * 64 + j * 16 + (l & 15)] = v;
                }
            }
            // 4 rounds: lanes 0-15 cover one full 256B row -> coalesced float4
#pragma unroll
            for (int rr = 0; rr < 4; rr++) {
                int lrow = rr * 4 + (l >> 4);
                f32x4 v4 = *(const f32x4*)(scratch + lrow * 64 + (l & 15) * 4);
                int grow = m0 + wm * (BM / WM) + i * 16 + lrow;
                size_t base = (size_t)grow * N + n0 + wn * 64 + (l & 15) * 4;
                f32x4 r4 = *(const f32x4*)((const float*)res + base);
                v4 += r4;
                *(f32x4*)((float*)out + base) = v4;
            }
        }
    } else {
        int colb = n0 + wn * (BN / WN) + (l & 15);
        int rowb = m0 + wm * (BM / WM) + ((l >> 4) << 2);
#pragma unroll
        for (int j = 0; j < MIb; j++) {
            int col = colb + j * 16;
            float bval = BIAS ? bias[col] : 0.f;
#pragma unroll
            for (int i = 0; i < MIa; i++) {
#pragma unroll
                for (int r = 0; r < 4; r++) {
                    int row = rowb + i * 16 + r;
                    float v = acc[i][j][r] + bval;
                    if (RELU) v = fmaxf(v, 0.f);
                    size_t idx = (size_t)row * N + col;
                    if (RES_MODE == 1) v += ((const float*)res)[idx];
                    else if (RES_MODE == 2) v += bf2f(((const ushort_t*)res)[idx]);
                    if (OUT_BF16) ((ushort_t*)out)[idx] = f2bf(v);
                    else          ((float*)out)[idx]    = v;
                }
            }
        }
    }
}

// ---------- MFMA flash attention, v8 (best measured: 82 us) ----------
// QK-early pipeline: S(kt+1) MFMA overlaps softmax(kt) VALU; K 3-buf staged 2
// ahead, V 2-buf; Qs/Ps union (QPs); __expf (v_exp_f32); diag-specialized mask.
__global__ __launch_bounds__(256) void fattn_k(
    ushort_t* __restrict__ QKV, const ushort_t* __restrict__ Vt)
{
    __shared__ ushort_t QPs[64 * 64];     // Q staging (prologue) / P tile (loop)
    __shared__ ushort_t Ks[3][64 * 64];
    __shared__ ushort_t Vs[2][64 * 64];
    int lin = blockIdx.x;
    int nwg = gridDim.x;                       // 1024, %8 == 0
    int bid = (lin & 7) * (nwg >> 3) + (lin >> 3);   // bijective XCD remap
    int pr = bid & 15;
    int bh = bid >> 4;
    int b  = bh >> 4;
    int h  = bh & 15;
    int tid = threadIdx.x;
    int lid = tid & 63, w = tid >> 6;

    int srow = w * 16 + (lid >> 3);
    int sseg0 = (lid & 7) ^ (srow & 7);
    int sseg1 = (lid & 7) ^ ((srow + 8) & 7);
    const ushort_t* Kg = QKV + (size_t)(b * T_) * N3_ + C_ + h * HS_;
    const ushort_t* Vg = Vt + (size_t)(b * H_ + h) * HS_ * T_;

    int mrow = w * 16 + (lid & 15);
    int fseg = lid >> 4;
    int qlocb = w * 16 + ((lid >> 4) << 2);

    const __bf16 oneb = (__bf16)1.0f;
    bf16x8 ones = {oneb, oneb, oneb, oneb, oneb, oneb, oneb, oneb};

    auto stageK = [&](int kt) {
        ushort_t* d = Ks[kt % 3];
        gload16(Kg + (size_t)(kt * 64 + srow) * N3_ + sseg0 * 8,     d + w * 1024);
        gload16(Kg + (size_t)(kt * 64 + srow + 8) * N3_ + sseg1 * 8, d + w * 1024 + 512);
    };
    auto stageV = [&](int kt) {
        ushort_t* d = Vs[kt & 1];
        gload16(Vg + (size_t)srow * T_ + kt * 64 + sseg0 * 8,       d + w * 1024);
        gload16(Vg + (size_t)(srow + 8) * T_ + kt * 64 + sseg1 * 8, d + w * 1024 + 512);
    };

    for (int half = 0; half < 2; ++half) {
        int qt = half ? (31 - pr) : pr;
        const ushort_t* Qg = QKV + (size_t)(b * T_ + qt * 64) * N3_ + h * HS_;

        // prologue: stage Q, K0, V0, K1 (all dests wave-private rows)
        gload16(Qg + (size_t)srow * N3_ + sseg0 * 8,       QPs + w * 1024);
        gload16(Qg + (size_t)(srow + 8) * N3_ + sseg1 * 8, QPs + w * 1024 + 512);
        stageK(0);
        stageV(0);
        if (qt >= 1) stageK(1);
        __syncthreads();   // drains all staging + syncs waves

        // Q fragments loop-invariant -> registers; QPs becomes the P tile.
        bf16x8 aqr[2];
        aqr[0] = *(const bf16x8*)(QPs + mrow * 64 + (((0 + fseg) ^ (mrow & 7)) * 8));
        aqr[1] = *(const bf16x8*)(QPs + mrow * 64 + (((4 + fseg) ^ (mrow & 7)) * 8));

        f32x4 accO[4];
#pragma unroll
        for (int j = 0; j < 4; j++) accO[j] = (f32x4){0.f, 0.f, 0.f, 0.f};
        f32x4 accL = (f32x4){0.f, 0.f, 0.f, 0.f};

        auto qk_into = [&](const ushort_t* Kc, f32x4* s) {
#pragma unroll
            for (int j = 0; j < 4; j++) s[j] = (f32x4){0.f, 0.f, 0.f, 0.f};
            __builtin_amdgcn_s_setprio(1);
#pragma unroll
            for (int ks = 0; ks < 2; ks++) {
#pragma unroll
                for (int j = 0; j < 4; j++) {
                    int krow = j * 16 + (lid & 15);
                    bf16x8 bk = *(const bf16x8*)(Kc + krow * 64 + (((ks * 4 + fseg) ^ (krow & 7)) * 8));
                    s[j] = __builtin_amdgcn_mfma_f32_16x16x32_bf16(aqr[ks], bk, s[j], 0, 0, 0);
                }
            }
            __builtin_amdgcn_s_setprio(0);
        };
        auto smax_pv = [&](auto diag_c, f32x4* s, const ushort_t* Vc) {
            constexpr bool DIAG = decltype(diag_c)::value;
#pragma unroll
            for (int r = 0; r < 4; r++) {
                int qloc = qlocb + r;
#pragma unroll
                for (int j = 0; j < 4; j++) {
                    int col = j * 16 + (lid & 15);
                    float p = __expf(s[j][r] * 0.125f);
                    if (DIAG) { if (col > qloc) p = 0.f; }
                    QPs[qloc * 64 + (((col >> 3) ^ (qloc & 7)) * 8) + (col & 7)] = f2bf(p);
                }
            }
            __builtin_amdgcn_s_setprio(1);
#pragma unroll
            for (int ks = 0; ks < 2; ks++) {
                bf16x8 ap = *(const bf16x8*)(QPs + mrow * 64 + (((ks * 4 + fseg) ^ (mrow & 7)) * 8));
                accL = __builtin_amdgcn_mfma_f32_16x16x32_bf16(ap, ones, accL, 0, 0, 0);
#pragma unroll
                for (int j = 0; j < 4; j++) {
                    int drow = j * 16 + (lid & 15);
                    bf16x8 bv = *(const bf16x8*)(Vc + drow * 64 + (((ks * 4 + fseg) ^ (drow & 7)) * 8));
                    accO[j] = __builtin_amdgcn_mfma_f32_16x16x32_bf16(ap, bv, accO[j], 0, 0, 0);
                }
            }
            __builtin_amdgcn_s_setprio(0);
        };

        // sP = S(0)
        f32x4 sP[4], sN[4];
        qk_into(Ks[0], sP);

        for (int kt = 0; kt < qt; ++kt) {
            // early-issue staging: K two ahead, V one ahead
            if (kt + 2 <= qt) stageK(kt + 2);
            stageV(kt + 1);
            // QK(kt+1) — independent of softmax(kt); overlaps its VALU work
            qk_into(Ks[(kt + 1) % 3], sN);
            // softmax(kt) (never diag in-loop) + PV(kt)
            smax_pv(bool_c<false>{}, sP, Vs[kt & 1]);
            __syncthreads();   // staged loads drained; all waves done with K/V[cur]
#pragma unroll
            for (int j = 0; j < 4; j++) sP[j] = sN[j];
        }
        // final tile kt = qt: diag mask
        smax_pv(bool_c<true>{}, sP, Vs[qt & 1]);
        __syncthreads();   // all reads done before next half restages

#pragma unroll
        for (int r = 0; r < 4; r++) {
            float inv = 1.0f / accL[r];
            int qabs = qt * 64 + qlocb + r;
            ushort_t* orow = QKV + (size_t)(b * T_ + qabs) * N3_ + h * HS_;
#pragma unroll
            for (int j = 0; j < 4; j++)
                orow[j * 16 + (lid & 15)] = f2bf(accO[j][r] * inv);
        }
    }
}

extern "C" void kernel_launch(void* const* d_in, const int* in_sizes, int n_in,
                              void* d_out, int out_size, void* d_ws, size_t ws_size,
                              hipStream_t stream)
{
    const float* x   = (const float*)d_in[0];
    const float* g1  = (const float*)d_in[1];
    const float* be1 = (const float*)d_in[2];
    const float* Wq  = (const float*)d_in[3];
    const float* Wk  = (const float*)d_in[4];
    const float* Wv  = (const float*)d_in[5];
    const float* Wo  = (const float*)d_in[6];
    const float* bo  = (const float*)d_in[7];
    const float* g2  = (const float*)d_in[8];
    const float* be2 = (const float*)d_in[9];
    const float* W1  = (const float*)d_in[10];
    const float* b1  = (const float*)d_in[11];
    const float* W2  = (const float*)d_in[12];
    const float* b2  = (const float*)d_in[13];

    // ws (bytes): hB 16M | big region 64M (qkv 48M + Vt tail 16M during attn;
    // ff1 64M later, time-disjoint) | WtB 6M | WoB 2M | W1B 8M | W2B 8M = 104 MiB.
    // x2 lives as fp32 in d_out. Vt = wsb+4*UB2 (big-region tail).
    const size_t UB2 = (size_t)BT_ * C_ * 2;
    const size_t WT_B = (size_t)N3_ * C_ * 2;
    const size_t WO_B = (size_t)C_ * C_ * 2;
    const size_t W1_B = (size_t)C_ * F_ * 2;
    const size_t REQ = 5 * UB2 + WT_B + WO_B + 2 * W1_B;
    if (ws_size < REQ) {
        hipMemsetAsync(d_out, 0, (size_t)out_size * 4, stream);
        return;
    }
    char* wsb = (char*)d_ws;
    ushort_t* hB   = (ushort_t*)(wsb);                 // LN1 out; h2 after LN2
    ushort_t* qkvB = (ushort_t*)(wsb + UB2);           // big region
    ushort_t* ff1B = qkvB;
    ushort_t* VtB  = (ushort_t*)(wsb + 4 * UB2);       // big-region tail
    ushort_t* WtB  = (ushort_t*)(wsb + 5 * UB2);
    ushort_t* WoB  = (ushort_t*)(wsb + 5 * UB2 + WT_B);
    ushort_t* W1B  = (ushort_t*)(wsb + 5 * UB2 + WT_B + WO_B);
    ushort_t* W2B  = (ushort_t*)(wsb + 5 * UB2 + WT_B + WO_B + W1_B);
    float* x2F = (float*)d_out;

    // fused prologue: 2-row LN1 + QKV-weight repack + 3 weight transposes
    prep_ln1_k<<<BT_ / 2 + 768 + 256 + 1024 + 1024, 256, 0, stream>>>(
        x, g1, be1, hB, Wq, Wk, Wv, WtB, Wo, WoB, W1, W1B, W2, W2B);
    // qkv = h @ Wt^T  [8192 x 3072]; V-region blocks write transposed into VtB
    mgemm8_k<128,256,2,4,0,0,0,1><<<(N3_ / 256) * (BT_ / 128), 512, 0, stream>>>(
        hB, WtB, nullptr, nullptr, qkvB, BT_, N3_, C_, C_, N3_ / 256, VtB);
    // attention (paired q-tiles, XCD-swizzled; O -> Q slots of qkv)
    fattn_k<<<B_ * H_ * 16, 256, 0, stream>>>(qkvB, VtB);
    // x2 = x + O @ Wo + bo -> fp32 in d_out   [8192 x 1024], 128x256, grid 256
    mgemm8_k<128,256,2,4,0,1,1,0><<<(C_ / 256) * (BT_ / 128), 512, 0, stream>>>(
        qkvB, WoB, bo, x, x2F, BT_, C_, C_, N3_, C_ / 256, nullptr);
    // h2 = LN2(x2), 2-row blocks
    ln_k<<<BT_ / 2, 256, 0, stream>>>(x2F, g2, be2, hB);
    // ff1 = relu(h2 @ W1 + b1)   [8192 x 4096], 256x256 tiles, grid 512
    mgemm8_k<256,256,2,4,1,1,0,1><<<(F_ / 256) * (BT_ / 256), 512, 0, stream>>>(
        hB, W1B, b1, nullptr, ff1B, BT_, F_, C_, C_, F_ / 256, nullptr);
    // out = x2 + ff1 @ W2 + b2   [8192 x 1024], 128x256, grid 256
    mgemm8_k<128,256,2,4,0,1,1,0><<<(C_ / 256) * (BT_ / 128), 512, 0, stream>>>(
        ff1B, W2B, b2, x2F, (float*)d_out, BT_, C_, F_, F_, C_ / 256, nullptr);
}